// Round 1
// baseline (642.367 us; speedup 1.0000x reference)
//
#include <hip/hip_runtime.h>
#include <hip/hip_bf16.h>
#include <hip/hip_fp16.h>
#include <cstdint>

#define N_NODES 100000
#define N_EDGES 1600000
#define N_GRAPHS 64
#define F_IN 64
#define F_MID 128
#define F_OUT 64

typedef unsigned int uint32;

// ---- dtype-agnostic accessors (flags[0]=1 → floats are fp32; flags[1]=1 → ints are int64)
__device__ __forceinline__ float ldF(const void* p, size_t i, int f32) {
    return f32 ? ((const float*)p)[i]
               : __bfloat162float(((const __hip_bfloat16*)p)[i]);
}
__device__ __forceinline__ int ldI(const void* p, size_t i, int i64) {
    return i64 ? (int)((const long long*)p)[i] : ((const int*)p)[i];
}
__device__ __forceinline__ void stF(void* p, size_t i, float v, int f32) {
    if (f32) ((float*)p)[i] = v;
    else     ((__hip_bfloat16*)p)[i] = __float2bfloat16(v);
}

// ---- fp16x2 pack/unpack (SCALAR unions only — arrays of unions spill to scratch!) ----
union H2U { uint32 u; __half2 h; };
__device__ __forceinline__ float2 up16(uint32 u) {
    H2U c; c.u = u;
    return __half22float2(c.h);
}
__device__ __forceinline__ __half2 u2h(uint32 u) {
    H2U c; c.u = u;
    return c.h;
}
__device__ __forceinline__ uint32 pk16(float a, float b) {
    H2U c; c.h = __floats2half2_rn(a, b);
    return c.u;
}
__device__ __forceinline__ unsigned short bfbits(float f) {
    __hip_bfloat16 b = __float2bfloat16(f);
    return *(unsigned short*)&b;
}

// ---- 32-edge-slot predicated gather batch -----------------------------------------
// One wave, one node. Slot k (k<32) valid iff k<rem (rem is wave-uniform → scalar
// select). Invalid slots read the all-zero pad row at index N_NODES (L1-resident).
// 16 row-loads per lane in flight → ONE memory latency per batch, no serial tail.
__device__ __forceinline__ void gath32(const int* __restrict__ sp, const int rem,
                                       const uint32* __restrict__ rows,
                                       const int h, const int fp,
                                       float2& A0, float2& A1, float2& A2, float2& A3) {
#define T_(k) const int t##k = sp[k];
    T_(0) T_(1) T_(2) T_(3) T_(4) T_(5) T_(6) T_(7)
    T_(8) T_(9) T_(10) T_(11) T_(12) T_(13) T_(14) T_(15)
    T_(16) T_(17) T_(18) T_(19) T_(20) T_(21) T_(22) T_(23)
    T_(24) T_(25) T_(26) T_(27) T_(28) T_(29) T_(30) T_(31)
#undef T_
#define P_(k) const int p##k = (k < rem) ? t##k : N_NODES;
    P_(0) P_(1) P_(2) P_(3) P_(4) P_(5) P_(6) P_(7)
    P_(8) P_(9) P_(10) P_(11) P_(12) P_(13) P_(14) P_(15)
    P_(16) P_(17) P_(18) P_(19) P_(20) P_(21) P_(22) P_(23)
    P_(24) P_(25) P_(26) P_(27) P_(28) P_(29) P_(30) P_(31)
#undef P_
#define V_(m, pe, po) \
    const float2 v##m = up16(rows[(uint32)(h ? po : pe) * 32u + (uint32)fp]);
    V_(0, p0, p1)   V_(1, p2, p3)   V_(2, p4, p5)   V_(3, p6, p7)
    V_(4, p8, p9)   V_(5, p10, p11) V_(6, p12, p13) V_(7, p14, p15)
    V_(8, p16, p17) V_(9, p18, p19) V_(10, p20, p21) V_(11, p22, p23)
    V_(12, p24, p25) V_(13, p26, p27) V_(14, p28, p29) V_(15, p30, p31)
#undef V_
    A0.x += (v0.x + v4.x) + (v8.x + v12.x);
    A0.y += (v0.y + v4.y) + (v8.y + v12.y);
    A1.x += (v1.x + v5.x) + (v9.x + v13.x);
    A1.y += (v1.y + v5.y) + (v9.y + v13.y);
    A2.x += (v2.x + v6.x) + (v10.x + v14.x);
    A2.y += (v2.y + v6.y) + (v10.y + v14.y);
    A3.x += (v3.x + v7.x) + (v11.x + v15.x);
    A3.y += (v3.y + v7.y) + (v11.y + v15.y);
}

// ---------------- dtype sniffer ----------------------------------------------------
__global__ void GCNEncoder_77214922048129_kernel(const void* x, const void* ei,
                                                 int* flags) {
    __shared__ int cnt_weird, cnt_zero;
    if (threadIdx.x == 0) { cnt_weird = 0; cnt_zero = 0; }
    __syncthreads();
    const unsigned short* u = (const unsigned short*)x;
    int w = 0;
    for (int i = threadIdx.x; i < 2048; i += 256) {
        int e = (u[i] >> 7) & 0xFF;
        if (e == 0xFF || e >= 159 || (e > 0 && e <= 95)) w++;
    }
    atomicAdd(&cnt_weird, w);
    const int* ii = (const int*)ei;
    int z = 0;
    for (int i = threadIdx.x; i < 128; i += 256) {
        if (ii[2 * i + 1] == 0) z++;
    }
    atomicAdd(&cnt_zero, z);
    __syncthreads();
    if (threadIdx.x == 0) {
        flags[0] = (cnt_weird > 64) ? 1 : 0;  // fp32 floats
        flags[1] = (cnt_zero > 64) ? 1 : 0;   // int64 indices
    }
}

// ---------------- degree over col (self-loop added analytically) -------------------
__global__ void k_deg(const void* __restrict__ ei, int* __restrict__ deg,
                      const int* __restrict__ flags) {
    const int i64 = flags[1];
    int e = blockIdx.x * blockDim.x + threadIdx.x;
    if (e < N_EDGES) atomicAdd(&deg[ldI(ei, (size_t)N_EDGES + e, i64)], 1);
}

// ---------------- CSR build: 3-stage parallel exclusive scan of deg ----------------
#define NB_SCAN ((N_NODES + 255) / 256)  // 391

// fused: block-sum for scan + dinv computation
__global__ __launch_bounds__(256) void k_bsum(const int* __restrict__ deg,
                                              int* __restrict__ bsum,
                                              float* __restrict__ dinv) {
    __shared__ int sh[256];
    int idx = blockIdx.x * 256 + threadIdx.x;
    int d = 0;
    if (idx < N_NODES) {
        d = deg[idx];
        dinv[idx] = rsqrtf((float)d + 1.0f);  // +1 = self-loop
    }
    sh[threadIdx.x] = d;
    __syncthreads();
#pragma unroll
    for (int off = 128; off > 0; off >>= 1) {
        if (threadIdx.x < off) sh[threadIdx.x] += sh[threadIdx.x + off];
        __syncthreads();
    }
    if (threadIdx.x == 0) bsum[blockIdx.x] = sh[0];
}

__global__ __launch_bounds__(512) void k_bscan(const int* __restrict__ bsum,
                                               int* __restrict__ bbase) {
    __shared__ int sh[512];
    const int t = threadIdx.x;
    sh[t] = (t < NB_SCAN) ? bsum[t] : 0;
    __syncthreads();
    for (int off = 1; off < 512; off <<= 1) {
        int v = (t >= off) ? sh[t - off] : 0;
        __syncthreads();
        sh[t] += v;
        __syncthreads();
    }
    if (t < NB_SCAN) bbase[t] = (t == 0) ? 0 : sh[t - 1];
}

__global__ __launch_bounds__(256) void k_rowptr(const int* __restrict__ deg,
                                                const int* __restrict__ bbase,
                                                int* __restrict__ rowptr,
                                                int* __restrict__ cursor) {
    __shared__ int sh[256];
    const int t = threadIdx.x;
    const int idx = blockIdx.x * 256 + t;
    const int d = (idx < N_NODES) ? deg[idx] : 0;
    sh[t] = d;
    __syncthreads();
    for (int off = 1; off < 256; off <<= 1) {
        int v = (t >= off) ? sh[t - off] : 0;
        __syncthreads();
        sh[t] += v;
        __syncthreads();
    }
    if (idx < N_NODES) {
        int r = bbase[blockIdx.x] + sh[t] - d;  // exclusive
        rowptr[idx] = r;
        cursor[idx] = r;
    }
    if (idx == 0) rowptr[N_NODES] = N_EDGES;
}

// ---------------- CSR scatter: src[pos(c)] = r -------------------------------------
__global__ __launch_bounds__(256) void k_csr(const void* __restrict__ ei,
                                             int* __restrict__ cursor,
                                             int* __restrict__ src,
                                             const int* __restrict__ flags) {
    const int i64 = flags[1];
    int e = blockIdx.x * blockDim.x + threadIdx.x;
    if (e < N_EDGES) {
        int r = ldI(ei, e, i64);
        int c = ldI(ei, (size_t)N_EDGES + e, i64);
        int pos = atomicAdd(&cursor[c], 1);
        src[pos] = r;
    }
}

// ---------------- xs16[n] = fp16( x[n] * dinv[n] ), packed pairs -------------------
// Also zeroes the pad row (index N_NODES) of BOTH xs16 and a2u for predicated gather.
__global__ __launch_bounds__(256) void k_scale(const void* __restrict__ x,
                                               const float* __restrict__ dinv,
                                               uint32* __restrict__ xs16,
                                               uint32* __restrict__ a2u,
                                               const int* __restrict__ flags) {
    const int F32 = flags[0];
    int idx = blockIdx.x * blockDim.x + threadIdx.x;  // feature-pair index
    if (idx < N_NODES * 32) {
        int n = idx >> 5;
        float dv = dinv[n];
        float a = ldF(x, (size_t)idx * 2, F32) * dv;
        float b = ldF(x, (size_t)idx * 2 + 1, F32) * dv;
        xs16[idx] = pk16(a, b);
    } else if (idx < (N_NODES + 1) * 32) {
        xs16[idx] = 0u;  // zero pad row: dummy gather target contributes 0
        a2u[idx] = 0u;
    }
}

// ------ fused layer1: predicated gather + GEMM1 + LN + ReLU + GEMM2 (hfma2) --------
// ONE node per wave. Gather is a single 32-edge-slot predicated batch (gath32):
// 16 concurrent row-loads per lane, ONE latency round-trip per node (avg deg 17).
#define G1W 8
__global__ __launch_bounds__(64 * G1W, 4) void k_gather1(
    const int* __restrict__ rowptr, const int* __restrict__ src,
    const uint32* __restrict__ xsu, const float* __restrict__ dinv,
    const void* __restrict__ b1, const void* __restrict__ lnw,
    const void* __restrict__ lnb, const void* __restrict__ W1,
    const void* __restrict__ W2, uint32* __restrict__ a2u,
    const int* __restrict__ flags) {
    const int F32 = flags[0];
    __shared__ uint2  w1d[32 * 64];   // [k2][f]: .x=(W1[2k2][f],W1[2k2+1][f]) .y=@f+64 ; 16 KB
    __shared__ uint2  w2q[32 * 64];   // [k4][f]: 4 k-values of W2 per entry ; 16 KB
    __shared__ float b1s[F_MID], lnws[F_MID], lnbs[F_MID];
    __shared__ uint32 aggp[G1W][32];  // packed agg k-pairs per wave
    __shared__ uint32 usp[G1W][64];   // packed u k-pairs per wave
    for (int i = threadIdx.x; i < 32 * 64; i += 64 * G1W) {
        const int k2 = i >> 6, f = i & 63;
        uint2 w;
        w.x = pk16(ldF(W1, (size_t)(2 * k2) * F_MID + f, F32),
                   ldF(W1, (size_t)(2 * k2 + 1) * F_MID + f, F32));
        w.y = pk16(ldF(W1, (size_t)(2 * k2) * F_MID + f + 64, F32),
                   ldF(W1, (size_t)(2 * k2 + 1) * F_MID + f + 64, F32));
        w1d[i] = w;
    }
    for (int i = threadIdx.x; i < 32 * 64; i += 64 * G1W) {
        const int k4 = i >> 6, f = i & 63;
        uint2 w;
        w.x = pk16(ldF(W2, (size_t)(4 * k4) * F_OUT + f, F32),
                   ldF(W2, (size_t)(4 * k4 + 1) * F_OUT + f, F32));
        w.y = pk16(ldF(W2, (size_t)(4 * k4 + 2) * F_OUT + f, F32),
                   ldF(W2, (size_t)(4 * k4 + 3) * F_OUT + f, F32));
        w2q[i] = w;
    }
    if (threadIdx.x < F_MID) {
        b1s[threadIdx.x] = ldF(b1, threadIdx.x, F32);
        lnws[threadIdx.x] = ldF(lnw, threadIdx.x, F32);
        lnbs[threadIdx.x] = ldF(lnb, threadIdx.x, F32);
    }
    __syncthreads();
    const int wid = threadIdx.x >> 6;
    const int lane = threadIdx.x & 63;
    const int h = lane >> 5;    // which edge of the pair
    const int fp = lane & 31;   // feature-pair index
    const __half2 hz = __float2half2_rn(0.f);
    for (int n0 = blockIdx.x * G1W + wid; n0 < N_NODES; n0 += gridDim.x * G1W) {
        const int n = __builtin_amdgcn_readfirstlane(n0);
        const int beg = __builtin_amdgcn_readfirstlane(rowptr[n]);
        const int end = __builtin_amdgcn_readfirstlane(rowptr[n + 1]);
        float2 A0 = {0.f, 0.f}, A1 = {0.f, 0.f}, A2 = {0.f, 0.f}, A3 = {0.f, 0.f};
        for (int jj = beg; jj < end; jj += 32)
            gath32(src + jj, end - jj, xsu, h, fp, A0, A1, A2, A3);
        float sx = (A0.x + A1.x) + (A2.x + A3.x);
        float sy = (A0.y + A1.y) + (A2.y + A3.y);
        sx += __shfl_xor(sx, 32, 64);
        sy += __shfl_xor(sy, 32, 64);
        const float2 sv = up16(xsu[(uint32)n * 32u + (uint32)fp]);  // self (already * dinv)
        sx += sv.x; sy += sv.y;
        if (h == 0) aggp[wid][fp] = pk16(sx, sy);  // within-wave RAW (lgkmcnt wait)
        const float dv = dinv[n];
        // ---- GEMM1: lane f handles f and f+64; hfma2, promote every 16 k ----
        __half2 hc0 = hz, hc1 = hz;
        float g0 = 0.f, g1 = 0.f;
#pragma unroll
        for (int q = 0; q < 8; ++q) {
            const uint4 aq = ((const uint4*)aggp[wid])[q];  // b128 broadcast
#pragma unroll
            for (int j = 0; j < 4; ++j) {
                const uint32 av = (j == 0) ? aq.x : (j == 1) ? aq.y : (j == 2) ? aq.z : aq.w;
                const uint2 wv = w1d[(q * 4 + j) * 64 + lane];
                hc0 = __hfma2(u2h(av), u2h(wv.x), hc0);
                hc1 = __hfma2(u2h(av), u2h(wv.y), hc1);
            }
            if (q & 1) {
                float2 p;
                p = __half22float2(hc0); g0 += p.x + p.y; hc0 = hz;
                p = __half22float2(hc1); g1 += p.x + p.y; hc1 = hz;
            }
        }
        const float t0 = g0 * dv + b1s[lane];
        const float t1 = g1 * dv + b1s[lane + 64];
        // ---- LayerNorm over 128 ----
        float s = t0 + t1;
#pragma unroll
        for (int off = 32; off > 0; off >>= 1) s += __shfl_xor(s, off, 64);
        const float mu = s * (1.f / 128.f);
        const float d0 = t0 - mu, d1 = t1 - mu;
        float v = d0 * d0 + d1 * d1;
#pragma unroll
        for (int off = 32; off > 0; off >>= 1) v += __shfl_xor(v, off, 64);
        const float rstd = rsqrtf(v * (1.f / 128.f) + 1e-5f);
        const float u0 = fmaxf(d0 * rstd * lnws[lane] + lnbs[lane], 0.f);
        const float u1 = fmaxf(d1 * rstd * lnws[lane + 64] + lnbs[lane + 64], 0.f);
        // repack u into k-pair layout: usp[k2] = (u[2k2], u[2k2+1])
        const int praw = (int)pk16(u0, u1);  // lane m: (u[m], u[m+64])
        const int ia = __shfl(praw, (2 * lane) & 63, 64);
        const int ib = __shfl(praw, (2 * lane + 1) & 63, 64);
        const float2 fa = up16((uint32)ia), fb = up16((uint32)ib);
        const float ux = (lane < 32) ? fa.x : fa.y;  // u[2*lane]
        const float uy = (lane < 32) ? fb.x : fb.y;  // u[2*lane+1]
        usp[wid][lane] = pk16(ux, uy);
        // ---- GEMM2: a2[lane] = (u @ W2)[lane] * dv ; b64 weights, promote /32k ----
        __half2 hc = hz;
        float facc = 0.f;
#pragma unroll
        for (int q = 0; q < 16; ++q) {
            const uint4 uq = ((const uint4*)usp[wid])[q];  // b128 broadcast
            const uint2 wv0 = w2q[(2 * q) * 64 + lane];    // k 8q..8q+3
            const uint2 wv1 = w2q[(2 * q + 1) * 64 + lane];// k 8q+4..8q+7
            hc = __hfma2(u2h(uq.x), u2h(wv0.x), hc);
            hc = __hfma2(u2h(uq.y), u2h(wv0.y), hc);
            hc = __hfma2(u2h(uq.z), u2h(wv1.x), hc);
            hc = __hfma2(u2h(uq.w), u2h(wv1.y), hc);
            if ((q & 3) == 3) {
                const float2 p = __half22float2(hc);
                facc += p.x + p.y;
                hc = hz;
            }
        }
        const float a2 = facc * dv;
        // ---- store packed fp16 pairs ----
        const float e  = __shfl(a2, (2 * lane) & 63, 64);
        const float f2 = __shfl(a2, (2 * lane + 1) & 63, 64);
        if (lane < 32) a2u[(size_t)n * 32 + lane] = pk16(e, f2);
    }
}

// ------ fused layer2: predicated fp16 gather + self + dinv + b2 → out --------------
__global__ __launch_bounds__(256) void k_gather2(
    const int* __restrict__ rowptr, const int* __restrict__ src,
    const uint32* __restrict__ a2u, const float* __restrict__ dinv,
    const void* __restrict__ b2, void* __restrict__ out,
    const int* __restrict__ flags) {
    const int F32 = flags[0];
    __shared__ float b2s[F_OUT];
    if (threadIdx.x < F_OUT) b2s[threadIdx.x] = ldF(b2, threadIdx.x, F32);
    __syncthreads();
    const int wid = threadIdx.x >> 6;
    const int lane = threadIdx.x & 63;
    const int h = lane >> 5;
    const int fp = lane & 31;
    for (int n0 = blockIdx.x * 4 + wid; n0 < N_NODES; n0 += gridDim.x * 4) {
        const int n = __builtin_amdgcn_readfirstlane(n0);
        const int beg = __builtin_amdgcn_readfirstlane(rowptr[n]);
        const int end = __builtin_amdgcn_readfirstlane(rowptr[n + 1]);
        float2 A0 = {0.f, 0.f}, A1 = {0.f, 0.f}, A2 = {0.f, 0.f}, A3 = {0.f, 0.f};
        for (int jj = beg; jj < end; jj += 32)
            gath32(src + jj, end - jj, a2u, h, fp, A0, A1, A2, A3);
        float sx = (A0.x + A1.x) + (A2.x + A3.x);
        float sy = (A0.y + A1.y) + (A2.y + A3.y);
        sx += __shfl_xor(sx, 32, 64);
        sy += __shfl_xor(sy, 32, 64);
        const float2 sv = up16(a2u[(uint32)n * 32u + (uint32)fp]);  // self term
        const float dv = dinv[n];
        const float2 b2v = ((const float2*)b2s)[fp];
        float2 r;
        r.x = (sx + sv.x) * dv + b2v.x;
        r.y = (sy + sv.y) * dv + b2v.y;
        if (h == 0) {
            if (F32) {
                ((float2*)out)[(size_t)n * 32 + fp] = r;
            } else {
                uint32 ub = ((uint32)bfbits(r.y) << 16) | (uint32)bfbits(r.x);
                ((uint32*)out)[(size_t)n * 32 + fp] = ub;
            }
        }
    }
}

// ---------------- pooling: segmented per-wave reduction (reads d_out h) ------------
__global__ __launch_bounds__(256) void k_pool(const void* __restrict__ hout,
                                              const void* __restrict__ batch,
                                              float* __restrict__ gsum,
                                              const int* __restrict__ flags) {
    const int F32 = flags[0];
    const int i64 = flags[1];
    const int wid = (blockIdx.x * blockDim.x + threadIdx.x) >> 6;
    const int lane = threadIdx.x & 63;
    const int nwaves = (gridDim.x * blockDim.x) >> 6;
    const int per = (N_NODES + nwaves - 1) / nwaves;
    const int start = wid * per;
    const int end = min(start + per, N_NODES);
    if (start >= end) return;
    float acc = 0.f;
    int gcur = ldI(batch, start, i64);
    for (int n = start; n < end; ++n) {
        int g = ldI(batch, n, i64);
        if (g != gcur) {
            atomicAdd(&gsum[gcur * 64 + lane], acc);
            acc = 0.f;
            gcur = g;
        }
        acc += ldF(hout, (size_t)n * 64 + lane, F32);
    }
    atomicAdd(&gsum[gcur * 64 + lane], acc);
}

// ---------------- g-output with inline per-graph count (binary search) -------------
__global__ void k_gout(const float* __restrict__ gsum, const void* __restrict__ batch,
                       void* __restrict__ out, const int* __restrict__ flags) {
    const int F32 = flags[0];
    const int i64 = flags[1];
    int idx = blockIdx.x * blockDim.x + threadIdx.x;
    if (idx < N_GRAPHS * 64) {
        int g = idx >> 6;  // wave-uniform within 64-thread groups
        int lo = 0, hi = N_NODES;
        while (lo < hi) { int m = (lo + hi) >> 1; if (ldI(batch, m, i64) < g) lo = m + 1; else hi = m; }
        int lb = lo;
        lo = 0; hi = N_NODES;
        while (lo < hi) { int m = (lo + hi) >> 1; if (ldI(batch, m, i64) <= g) lo = m + 1; else hi = m; }
        float c = (float)max(lo - lb, 1);
        stF(out, (size_t)N_NODES * F_OUT + idx, gsum[idx] / c, F32);
    }
}

extern "C" void kernel_launch(void* const* d_in, const int* in_sizes, int n_in,
                              void* d_out, int out_size, void* d_ws, size_t ws_size,
                              hipStream_t stream) {
    const void* x   = d_in[0];
    const void* ei  = d_in[1];
    const void* bat = d_in[2];
    const void* W1  = d_in[3];
    const void* b1  = d_in[4];
    const void* lnw = d_in[5];
    const void* lnb = d_in[6];
    const void* W2  = d_in[7];
    const void* b2  = d_in[8];

    char* ws = (char*)d_ws;
    size_t o = 0;
    auto alloc = [&](size_t bytes) { size_t r = o; o += (bytes + 255) & ~(size_t)255; return r; };
    int*    flags  = (int*)   (ws + alloc(2 * 4));
    float*  dinv   = (float*) (ws + alloc((size_t)N_NODES * 4));
    int*    deg    = (int*)   (ws + alloc((size_t)N_NODES * 4));
    int*    rowptr = (int*)   (ws + alloc((size_t)(N_NODES + 1) * 4));
    int*    cursor = (int*)   (ws + alloc((size_t)N_NODES * 4));
    int*    bsum   = (int*)   (ws + alloc((size_t)NB_SCAN * 4));
    int*    bbase  = (int*)   (ws + alloc((size_t)NB_SCAN * 4));
    int*    srcidx = (int*)   (ws + alloc((size_t)(N_EDGES + 64) * 4));      // +64 pad for predicated s_loads
    uint32* xs16   = (uint32*)(ws + alloc((size_t)(N_NODES + 1) * 32 * 4));  // +1 zero pad row
    uint32* a2u    = (uint32*)(ws + alloc((size_t)(N_NODES + 1) * 32 * 4));  // +1 zero pad row
    float*  gsum   = (float*) (ws + alloc((size_t)N_GRAPHS * 64 * 4));

    hipMemsetAsync(deg, 0, (size_t)N_NODES * 4, stream);
    hipMemsetAsync(gsum, 0, (size_t)N_GRAPHS * 64 * 4, stream);

    GCNEncoder_77214922048129_kernel<<<1, 256, 0, stream>>>(x, ei, flags);
    k_deg<<<(N_EDGES + 255) / 256, 256, 0, stream>>>(ei, deg, flags);
    k_bsum<<<NB_SCAN, 256, 0, stream>>>(deg, bsum, dinv);
    k_bscan<<<1, 512, 0, stream>>>(bsum, bbase);
    k_rowptr<<<NB_SCAN, 256, 0, stream>>>(deg, bbase, rowptr, cursor);
    k_csr<<<(N_EDGES + 255) / 256, 256, 0, stream>>>(ei, cursor, srcidx, flags);
    k_scale<<<((N_NODES + 1) * 32 + 255) / 256, 256, 0, stream>>>(x, dinv, xs16, a2u, flags);
    k_gather1<<<1024, 64 * G1W, 0, stream>>>(rowptr, srcidx, xs16, dinv, b1, lnw, lnb,
                                             W1, W2, a2u, flags);
    k_gather2<<<4096, 256, 0, stream>>>(rowptr, srcidx, a2u, dinv, b2, d_out, flags);
    k_pool<<<512, 256, 0, stream>>>(d_out, bat, gsum, flags);
    k_gout<<<(N_GRAPHS * 64 + 255) / 256, 256, 0, stream>>>(gsum, bat, d_out, flags);
}

// Round 2
// 512.028 us; speedup vs baseline: 1.2546x; 1.2546x over previous
//
#include <hip/hip_runtime.h>
#include <hip/hip_bf16.h>
#include <hip/hip_fp16.h>
#include <cstdint>

#define N_NODES 100000
#define N_EDGES 1600000
#define N_GRAPHS 64
#define F_IN 64
#define F_MID 128
#define F_OUT 64

typedef unsigned int uint32;

// ---- dtype-agnostic accessors (flags[0]=1 → floats are fp32; flags[1]=1 → ints are int64)
__device__ __forceinline__ float ldF(const void* p, size_t i, int f32) {
    return f32 ? ((const float*)p)[i]
               : __bfloat162float(((const __hip_bfloat16*)p)[i]);
}
__device__ __forceinline__ int ldI(const void* p, size_t i, int i64) {
    return i64 ? (int)((const long long*)p)[i] : ((const int*)p)[i];
}
__device__ __forceinline__ void stF(void* p, size_t i, float v, int f32) {
    if (f32) ((float*)p)[i] = v;
    else     ((__hip_bfloat16*)p)[i] = __float2bfloat16(v);
}

// ---- fp16x2 pack/unpack (SCALAR unions only — arrays of unions spill to scratch!) ----
union H2U { uint32 u; __half2 h; };
__device__ __forceinline__ float2 up16(uint32 u) {
    H2U c; c.u = u;
    return __half22float2(c.h);
}
__device__ __forceinline__ __half2 u2h(uint32 u) {
    H2U c; c.u = u;
    return c.h;
}
__device__ __forceinline__ uint32 pk16(float a, float b) {
    H2U c; c.h = __floats2half2_rn(a, b);
    return c.u;
}
__device__ __forceinline__ unsigned short bfbits(float f) {
    __hip_bfloat16 b = __float2bfloat16(f);
    return *(unsigned short*)&b;
}

// ---- 16-edge-slot PREDICATED gather batch -----------------------------------------
// One wave, one node. Slot k valid iff k<rem (rem wave-uniform → scalar cselect);
// invalid slots read the all-zero pad row at index N_NODES (L1-resident, adds 0).
// 8 concurrent row-loads per lane-half → ONE latency round-trip per batch, NO serial
// tail loop. Register footprint identical to the proven 16-batch (VGPR ~84, no spill).
__device__ __forceinline__ void gath16(const int* __restrict__ sp, const int rem,
                                       const uint32* __restrict__ rows,
                                       const int h, const int fp,
                                       float2& a0, float2& a1) {
    const int t0 = sp[0],  t1 = sp[1],  t2 = sp[2],  t3 = sp[3];
    const int t4 = sp[4],  t5 = sp[5],  t6 = sp[6],  t7 = sp[7];
    const int t8 = sp[8],  t9 = sp[9],  ta = sp[10], tb = sp[11];
    const int tc = sp[12], td = sp[13], te = sp[14], tf = sp[15];
    const int p0 = (0 < rem) ? t0 : N_NODES,  p1 = (1 < rem) ? t1 : N_NODES;
    const int p2 = (2 < rem) ? t2 : N_NODES,  p3 = (3 < rem) ? t3 : N_NODES;
    const int p4 = (4 < rem) ? t4 : N_NODES,  p5 = (5 < rem) ? t5 : N_NODES;
    const int p6 = (6 < rem) ? t6 : N_NODES,  p7 = (7 < rem) ? t7 : N_NODES;
    const int p8 = (8 < rem) ? t8 : N_NODES,  p9 = (9 < rem) ? t9 : N_NODES;
    const int pa = (10 < rem) ? ta : N_NODES, pb = (11 < rem) ? tb : N_NODES;
    const int pc = (12 < rem) ? tc : N_NODES, pd = (13 < rem) ? td : N_NODES;
    const int pe = (14 < rem) ? te : N_NODES, pf = (15 < rem) ? tf : N_NODES;
    const int iA = h ? p1 : p0, iB = h ? p3 : p2, iC = h ? p5 : p4, iD = h ? p7 : p6;
    const int iE = h ? p9 : p8, iF = h ? pb : pa, iG = h ? pd : pc, iH = h ? pf : pe;
    const float2 vA = up16(rows[(uint32)iA * 32u + (uint32)fp]);
    const float2 vB = up16(rows[(uint32)iB * 32u + (uint32)fp]);
    const float2 vC = up16(rows[(uint32)iC * 32u + (uint32)fp]);
    const float2 vD = up16(rows[(uint32)iD * 32u + (uint32)fp]);
    const float2 vE = up16(rows[(uint32)iE * 32u + (uint32)fp]);
    const float2 vF = up16(rows[(uint32)iF * 32u + (uint32)fp]);
    const float2 vG = up16(rows[(uint32)iG * 32u + (uint32)fp]);
    const float2 vH = up16(rows[(uint32)iH * 32u + (uint32)fp]);
    a0.x += (vA.x + vC.x) + (vE.x + vG.x);
    a0.y += (vA.y + vC.y) + (vE.y + vG.y);
    a1.x += (vB.x + vD.x) + (vF.x + vH.x);
    a1.y += (vB.y + vD.y) + (vF.y + vH.y);
}

// ---------------- dtype sniffer ----------------------------------------------------
__global__ void GCNEncoder_77214922048129_kernel(const void* x, const void* ei,
                                                 int* flags) {
    __shared__ int cnt_weird, cnt_zero;
    if (threadIdx.x == 0) { cnt_weird = 0; cnt_zero = 0; }
    __syncthreads();
    const unsigned short* u = (const unsigned short*)x;
    int w = 0;
    for (int i = threadIdx.x; i < 2048; i += 256) {
        int e = (u[i] >> 7) & 0xFF;
        if (e == 0xFF || e >= 159 || (e > 0 && e <= 95)) w++;
    }
    atomicAdd(&cnt_weird, w);
    const int* ii = (const int*)ei;
    int z = 0;
    for (int i = threadIdx.x; i < 128; i += 256) {
        if (ii[2 * i + 1] == 0) z++;
    }
    atomicAdd(&cnt_zero, z);
    __syncthreads();
    if (threadIdx.x == 0) {
        flags[0] = (cnt_weird > 64) ? 1 : 0;  // fp32 floats
        flags[1] = (cnt_zero > 64) ? 1 : 0;   // int64 indices
    }
}

// ---------------- degree over col (self-loop added analytically) -------------------
__global__ void k_deg(const void* __restrict__ ei, int* __restrict__ deg,
                      const int* __restrict__ flags) {
    const int i64 = flags[1];
    int e = blockIdx.x * blockDim.x + threadIdx.x;
    if (e < N_EDGES) atomicAdd(&deg[ldI(ei, (size_t)N_EDGES + e, i64)], 1);
}

// ---------------- CSR build: 3-stage parallel exclusive scan of deg ----------------
#define NB_SCAN ((N_NODES + 255) / 256)  // 391

// fused: block-sum for scan + dinv computation
__global__ __launch_bounds__(256) void k_bsum(const int* __restrict__ deg,
                                              int* __restrict__ bsum,
                                              float* __restrict__ dinv) {
    __shared__ int sh[256];
    int idx = blockIdx.x * 256 + threadIdx.x;
    int d = 0;
    if (idx < N_NODES) {
        d = deg[idx];
        dinv[idx] = rsqrtf((float)d + 1.0f);  // +1 = self-loop
    }
    sh[threadIdx.x] = d;
    __syncthreads();
#pragma unroll
    for (int off = 128; off > 0; off >>= 1) {
        if (threadIdx.x < off) sh[threadIdx.x] += sh[threadIdx.x + off];
        __syncthreads();
    }
    if (threadIdx.x == 0) bsum[blockIdx.x] = sh[0];
}

__global__ __launch_bounds__(512) void k_bscan(const int* __restrict__ bsum,
                                               int* __restrict__ bbase) {
    __shared__ int sh[512];
    const int t = threadIdx.x;
    sh[t] = (t < NB_SCAN) ? bsum[t] : 0;
    __syncthreads();
    for (int off = 1; off < 512; off <<= 1) {
        int v = (t >= off) ? sh[t - off] : 0;
        __syncthreads();
        sh[t] += v;
        __syncthreads();
    }
    if (t < NB_SCAN) bbase[t] = (t == 0) ? 0 : sh[t - 1];
}

__global__ __launch_bounds__(256) void k_rowptr(const int* __restrict__ deg,
                                                const int* __restrict__ bbase,
                                                int* __restrict__ rowptr,
                                                int* __restrict__ cursor) {
    __shared__ int sh[256];
    const int t = threadIdx.x;
    const int idx = blockIdx.x * 256 + t;
    const int d = (idx < N_NODES) ? deg[idx] : 0;
    sh[t] = d;
    __syncthreads();
    for (int off = 1; off < 256; off <<= 1) {
        int v = (t >= off) ? sh[t - off] : 0;
        __syncthreads();
        sh[t] += v;
        __syncthreads();
    }
    if (idx < N_NODES) {
        int r = bbase[blockIdx.x] + sh[t] - d;  // exclusive
        rowptr[idx] = r;
        cursor[idx] = r;
    }
    if (idx == 0) rowptr[N_NODES] = N_EDGES;
}

// ---------------- CSR scatter: src[pos(c)] = r -------------------------------------
__global__ __launch_bounds__(256) void k_csr(const void* __restrict__ ei,
                                             int* __restrict__ cursor,
                                             int* __restrict__ src,
                                             const int* __restrict__ flags) {
    const int i64 = flags[1];
    int e = blockIdx.x * blockDim.x + threadIdx.x;
    if (e < N_EDGES) {
        int r = ldI(ei, e, i64);
        int c = ldI(ei, (size_t)N_EDGES + e, i64);
        int pos = atomicAdd(&cursor[c], 1);
        src[pos] = r;
    }
}

// ---------------- xs16[n] = fp16( x[n] * dinv[n] ), packed pairs -------------------
// Also zeroes the pad row (index N_NODES) of BOTH xs16 and a2u for predicated gather.
__global__ __launch_bounds__(256) void k_scale(const void* __restrict__ x,
                                               const float* __restrict__ dinv,
                                               uint32* __restrict__ xs16,
                                               uint32* __restrict__ a2u,
                                               const int* __restrict__ flags) {
    const int F32 = flags[0];
    int idx = blockIdx.x * blockDim.x + threadIdx.x;  // feature-pair index
    if (idx < N_NODES * 32) {
        int n = idx >> 5;
        float dv = dinv[n];
        float a = ldF(x, (size_t)idx * 2, F32) * dv;
        float b = ldF(x, (size_t)idx * 2 + 1, F32) * dv;
        xs16[idx] = pk16(a, b);
    } else if (idx < (N_NODES + 1) * 32) {
        xs16[idx] = 0u;  // zero pad row: dummy gather target contributes 0
        a2u[idx] = 0u;
    }
}

// ------ fused layer1: predicated gather + GEMM1 + LN + ReLU + GEMM2 (hfma2) --------
// ONE node per wave (r8 structure, low VGPR). Every batch is a predicated 16-slot
// gath16 → exactly ceil(deg/16) memory round-trips per node, zero serial tail.
#define G1W 8
__global__ __launch_bounds__(64 * G1W) void k_gather1(
    const int* __restrict__ rowptr, const int* __restrict__ src,
    const uint32* __restrict__ xsu, const float* __restrict__ dinv,
    const void* __restrict__ b1, const void* __restrict__ lnw,
    const void* __restrict__ lnb, const void* __restrict__ W1,
    const void* __restrict__ W2, uint32* __restrict__ a2u,
    const int* __restrict__ flags) {
    const int F32 = flags[0];
    __shared__ uint2  w1d[32 * 64];   // [k2][f]: .x=(W1[2k2][f],W1[2k2+1][f]) .y=@f+64 ; 16 KB
    __shared__ uint2  w2q[32 * 64];   // [k4][f]: 4 k-values of W2 per entry ; 16 KB
    __shared__ float b1s[F_MID], lnws[F_MID], lnbs[F_MID];
    __shared__ uint32 aggp[G1W][32];  // packed agg k-pairs per wave
    __shared__ uint32 usp[G1W][64];   // packed u k-pairs per wave
    for (int i = threadIdx.x; i < 32 * 64; i += 64 * G1W) {
        const int k2 = i >> 6, f = i & 63;
        uint2 w;
        w.x = pk16(ldF(W1, (size_t)(2 * k2) * F_MID + f, F32),
                   ldF(W1, (size_t)(2 * k2 + 1) * F_MID + f, F32));
        w.y = pk16(ldF(W1, (size_t)(2 * k2) * F_MID + f + 64, F32),
                   ldF(W1, (size_t)(2 * k2 + 1) * F_MID + f + 64, F32));
        w1d[i] = w;
    }
    for (int i = threadIdx.x; i < 32 * 64; i += 64 * G1W) {
        const int k4 = i >> 6, f = i & 63;
        uint2 w;
        w.x = pk16(ldF(W2, (size_t)(4 * k4) * F_OUT + f, F32),
                   ldF(W2, (size_t)(4 * k4 + 1) * F_OUT + f, F32));
        w.y = pk16(ldF(W2, (size_t)(4 * k4 + 2) * F_OUT + f, F32),
                   ldF(W2, (size_t)(4 * k4 + 3) * F_OUT + f, F32));
        w2q[i] = w;
    }
    if (threadIdx.x < F_MID) {
        b1s[threadIdx.x] = ldF(b1, threadIdx.x, F32);
        lnws[threadIdx.x] = ldF(lnw, threadIdx.x, F32);
        lnbs[threadIdx.x] = ldF(lnb, threadIdx.x, F32);
    }
    __syncthreads();
    const int wid = threadIdx.x >> 6;
    const int lane = threadIdx.x & 63;
    const int h = lane >> 5;    // which edge of the pair
    const int fp = lane & 31;   // feature-pair index
    const __half2 hz = __float2half2_rn(0.f);
    for (int n0 = blockIdx.x * G1W + wid; n0 < N_NODES; n0 += gridDim.x * G1W) {
        const int n = __builtin_amdgcn_readfirstlane(n0);
        const int beg = __builtin_amdgcn_readfirstlane(rowptr[n]);
        const int end = __builtin_amdgcn_readfirstlane(rowptr[n + 1]);
        // issue self-row + dinv loads BEFORE the gather so they share the latency window
        const float2 sv = up16(xsu[(uint32)n * 32u + (uint32)fp]);  // self (already * dinv)
        const float dv = dinv[n];
        float2 a0 = {0.f, 0.f}, a1 = {0.f, 0.f};
        for (int jj = beg; jj < end; jj += 16)
            gath16(src + jj, end - jj, xsu, h, fp, a0, a1);
        float sx = a0.x + a1.x, sy = a0.y + a1.y;
        sx += __shfl_xor(sx, 32, 64);
        sy += __shfl_xor(sy, 32, 64);
        sx += sv.x; sy += sv.y;
        if (h == 0) aggp[wid][fp] = pk16(sx, sy);  // within-wave RAW (lgkmcnt wait)
        // ---- GEMM1: lane f handles f and f+64; hfma2, promote every 16 k ----
        __half2 hc0 = hz, hc1 = hz;
        float g0 = 0.f, g1 = 0.f;
#pragma unroll
        for (int q = 0; q < 8; ++q) {
            const uint4 aq = ((const uint4*)aggp[wid])[q];  // b128 broadcast
#pragma unroll
            for (int j = 0; j < 4; ++j) {
                const uint32 av = (j == 0) ? aq.x : (j == 1) ? aq.y : (j == 2) ? aq.z : aq.w;
                const uint2 wv = w1d[(q * 4 + j) * 64 + lane];
                hc0 = __hfma2(u2h(av), u2h(wv.x), hc0);
                hc1 = __hfma2(u2h(av), u2h(wv.y), hc1);
            }
            if (q & 1) {
                float2 p;
                p = __half22float2(hc0); g0 += p.x + p.y; hc0 = hz;
                p = __half22float2(hc1); g1 += p.x + p.y; hc1 = hz;
            }
        }
        const float t0 = g0 * dv + b1s[lane];
        const float t1 = g1 * dv + b1s[lane + 64];
        // ---- LayerNorm over 128 ----
        float s = t0 + t1;
#pragma unroll
        for (int off = 32; off > 0; off >>= 1) s += __shfl_xor(s, off, 64);
        const float mu = s * (1.f / 128.f);
        const float d0 = t0 - mu, d1 = t1 - mu;
        float v = d0 * d0 + d1 * d1;
#pragma unroll
        for (int off = 32; off > 0; off >>= 1) v += __shfl_xor(v, off, 64);
        const float rstd = rsqrtf(v * (1.f / 128.f) + 1e-5f);
        const float u0 = fmaxf(d0 * rstd * lnws[lane] + lnbs[lane], 0.f);
        const float u1 = fmaxf(d1 * rstd * lnws[lane + 64] + lnbs[lane + 64], 0.f);
        // repack u into k-pair layout: usp[k2] = (u[2k2], u[2k2+1])
        const int praw = (int)pk16(u0, u1);  // lane m: (u[m], u[m+64])
        const int ia = __shfl(praw, (2 * lane) & 63, 64);
        const int ib = __shfl(praw, (2 * lane + 1) & 63, 64);
        const float2 fa = up16((uint32)ia), fb = up16((uint32)ib);
        const float ux = (lane < 32) ? fa.x : fa.y;  // u[2*lane]
        const float uy = (lane < 32) ? fb.x : fb.y;  // u[2*lane+1]
        usp[wid][lane] = pk16(ux, uy);
        // ---- GEMM2: a2[lane] = (u @ W2)[lane] * dv ; b64 weights, promote /32k ----
        __half2 hc = hz;
        float facc = 0.f;
#pragma unroll
        for (int q = 0; q < 16; ++q) {
            const uint4 uq = ((const uint4*)usp[wid])[q];  // b128 broadcast
            const uint2 wv0 = w2q[(2 * q) * 64 + lane];    // k 8q..8q+3
            const uint2 wv1 = w2q[(2 * q + 1) * 64 + lane];// k 8q+4..8q+7
            hc = __hfma2(u2h(uq.x), u2h(wv0.x), hc);
            hc = __hfma2(u2h(uq.y), u2h(wv0.y), hc);
            hc = __hfma2(u2h(uq.z), u2h(wv1.x), hc);
            hc = __hfma2(u2h(uq.w), u2h(wv1.y), hc);
            if ((q & 3) == 3) {
                const float2 p = __half22float2(hc);
                facc += p.x + p.y;
                hc = hz;
            }
        }
        const float a2 = facc * dv;
        // ---- store packed fp16 pairs ----
        const float e  = __shfl(a2, (2 * lane) & 63, 64);
        const float f2 = __shfl(a2, (2 * lane + 1) & 63, 64);
        if (lane < 32) a2u[(size_t)n * 32 + lane] = pk16(e, f2);
    }
}

// ------ fused layer2: predicated fp16 gather + self + dinv + b2 → out --------------
__global__ __launch_bounds__(256) void k_gather2(
    const int* __restrict__ rowptr, const int* __restrict__ src,
    const uint32* __restrict__ a2u, const float* __restrict__ dinv,
    const void* __restrict__ b2, void* __restrict__ out,
    const int* __restrict__ flags) {
    const int F32 = flags[0];
    __shared__ float b2s[F_OUT];
    if (threadIdx.x < F_OUT) b2s[threadIdx.x] = ldF(b2, threadIdx.x, F32);
    __syncthreads();
    const int wid = threadIdx.x >> 6;
    const int lane = threadIdx.x & 63;
    const int h = lane >> 5;
    const int fp = lane & 31;
    for (int n0 = blockIdx.x * 4 + wid; n0 < N_NODES; n0 += gridDim.x * 4) {
        const int n = __builtin_amdgcn_readfirstlane(n0);
        const int beg = __builtin_amdgcn_readfirstlane(rowptr[n]);
        const int end = __builtin_amdgcn_readfirstlane(rowptr[n + 1]);
        const float2 sv = up16(a2u[(uint32)n * 32u + (uint32)fp]);  // self term (early issue)
        const float dv = dinv[n];
        float2 a0 = {0.f, 0.f}, a1 = {0.f, 0.f};
        for (int jj = beg; jj < end; jj += 16)
            gath16(src + jj, end - jj, a2u, h, fp, a0, a1);
        float sx = a0.x + a1.x, sy = a0.y + a1.y;
        sx += __shfl_xor(sx, 32, 64);
        sy += __shfl_xor(sy, 32, 64);
        const float2 b2v = ((const float2*)b2s)[fp];
        float2 r;
        r.x = (sx + sv.x) * dv + b2v.x;
        r.y = (sy + sv.y) * dv + b2v.y;
        if (h == 0) {
            if (F32) {
                ((float2*)out)[(size_t)n * 32 + fp] = r;
            } else {
                uint32 ub = ((uint32)bfbits(r.y) << 16) | (uint32)bfbits(r.x);
                ((uint32*)out)[(size_t)n * 32 + fp] = ub;
            }
        }
    }
}

// ---------------- pooling: segmented per-wave reduction (reads d_out h) ------------
__global__ __launch_bounds__(256) void k_pool(const void* __restrict__ hout,
                                              const void* __restrict__ batch,
                                              float* __restrict__ gsum,
                                              const int* __restrict__ flags) {
    const int F32 = flags[0];
    const int i64 = flags[1];
    const int wid = (blockIdx.x * blockDim.x + threadIdx.x) >> 6;
    const int lane = threadIdx.x & 63;
    const int nwaves = (gridDim.x * blockDim.x) >> 6;
    const int per = (N_NODES + nwaves - 1) / nwaves;
    const int start = wid * per;
    const int end = min(start + per, N_NODES);
    if (start >= end) return;
    float acc = 0.f;
    int gcur = ldI(batch, start, i64);
    for (int n = start; n < end; ++n) {
        int g = ldI(batch, n, i64);
        if (g != gcur) {
            atomicAdd(&gsum[gcur * 64 + lane], acc);
            acc = 0.f;
            gcur = g;
        }
        acc += ldF(hout, (size_t)n * 64 + lane, F32);
    }
    atomicAdd(&gsum[gcur * 64 + lane], acc);
}

// ---------------- g-output with inline per-graph count (binary search) -------------
__global__ void k_gout(const float* __restrict__ gsum, const void* __restrict__ batch,
                       void* __restrict__ out, const int* __restrict__ flags) {
    const int F32 = flags[0];
    const int i64 = flags[1];
    int idx = blockIdx.x * blockDim.x + threadIdx.x;
    if (idx < N_GRAPHS * 64) {
        int g = idx >> 6;  // wave-uniform within 64-thread groups
        int lo = 0, hi = N_NODES;
        while (lo < hi) { int m = (lo + hi) >> 1; if (ldI(batch, m, i64) < g) lo = m + 1; else hi = m; }
        int lb = lo;
        lo = 0; hi = N_NODES;
        while (lo < hi) { int m = (lo + hi) >> 1; if (ldI(batch, m, i64) <= g) lo = m + 1; else hi = m; }
        float c = (float)max(lo - lb, 1);
        stF(out, (size_t)N_NODES * F_OUT + idx, gsum[idx] / c, F32);
    }
}

extern "C" void kernel_launch(void* const* d_in, const int* in_sizes, int n_in,
                              void* d_out, int out_size, void* d_ws, size_t ws_size,
                              hipStream_t stream) {
    const void* x   = d_in[0];
    const void* ei  = d_in[1];
    const void* bat = d_in[2];
    const void* W1  = d_in[3];
    const void* b1  = d_in[4];
    const void* lnw = d_in[5];
    const void* lnb = d_in[6];
    const void* W2  = d_in[7];
    const void* b2  = d_in[8];

    char* ws = (char*)d_ws;
    size_t o = 0;
    auto alloc = [&](size_t bytes) { size_t r = o; o += (bytes + 255) & ~(size_t)255; return r; };
    int*    flags  = (int*)   (ws + alloc(2 * 4));
    float*  dinv   = (float*) (ws + alloc((size_t)N_NODES * 4));
    int*    deg    = (int*)   (ws + alloc((size_t)N_NODES * 4));
    int*    rowptr = (int*)   (ws + alloc((size_t)(N_NODES + 1) * 4));
    int*    cursor = (int*)   (ws + alloc((size_t)N_NODES * 4));
    int*    bsum   = (int*)   (ws + alloc((size_t)NB_SCAN * 4));
    int*    bbase  = (int*)   (ws + alloc((size_t)NB_SCAN * 4));
    int*    srcidx = (int*)   (ws + alloc((size_t)(N_EDGES + 64) * 4));      // +64 pad for predicated idx loads
    uint32* xs16   = (uint32*)(ws + alloc((size_t)(N_NODES + 1) * 32 * 4));  // +1 zero pad row
    uint32* a2u    = (uint32*)(ws + alloc((size_t)(N_NODES + 1) * 32 * 4));  // +1 zero pad row
    float*  gsum   = (float*) (ws + alloc((size_t)N_GRAPHS * 64 * 4));

    hipMemsetAsync(deg, 0, (size_t)N_NODES * 4, stream);
    hipMemsetAsync(gsum, 0, (size_t)N_GRAPHS * 64 * 4, stream);

    GCNEncoder_77214922048129_kernel<<<1, 256, 0, stream>>>(x, ei, flags);
    k_deg<<<(N_EDGES + 255) / 256, 256, 0, stream>>>(ei, deg, flags);
    k_bsum<<<NB_SCAN, 256, 0, stream>>>(deg, bsum, dinv);
    k_bscan<<<1, 512, 0, stream>>>(bsum, bbase);
    k_rowptr<<<NB_SCAN, 256, 0, stream>>>(deg, bbase, rowptr, cursor);
    k_csr<<<(N_EDGES + 255) / 256, 256, 0, stream>>>(ei, cursor, srcidx, flags);
    k_scale<<<((N_NODES + 1) * 32 + 255) / 256, 256, 0, stream>>>(x, dinv, xs16, a2u, flags);
    k_gather1<<<1024, 64 * G1W, 0, stream>>>(rowptr, srcidx, xs16, dinv, b1, lnw, lnb,
                                             W1, W2, a2u, flags);
    k_gather2<<<4096, 256, 0, stream>>>(rowptr, srcidx, a2u, dinv, b2, d_out, flags);
    k_pool<<<512, 256, 0, stream>>>(d_out, bat, gsum, flags);
    k_gout<<<(N_GRAPHS * 64 + 255) / 256, 256, 0, stream>>>(gsum, bat, d_out, flags);
}

// Round 3
// 489.531 us; speedup vs baseline: 1.3122x; 1.0460x over previous
//
#include <hip/hip_runtime.h>
#include <hip/hip_bf16.h>
#include <hip/hip_fp16.h>
#include <cstdint>

#define N_NODES 100000
#define N_EDGES 1600000
#define N_GRAPHS 64
#define F_IN 64
#define F_MID 128
#define F_OUT 64

typedef unsigned int uint32;

// ---- dtype-agnostic accessors (flags[0]=1 → floats are fp32; flags[1]=1 → ints are int64)
__device__ __forceinline__ float ldF(const void* p, size_t i, int f32) {
    return f32 ? ((const float*)p)[i]
               : __bfloat162float(((const __hip_bfloat16*)p)[i]);
}
__device__ __forceinline__ int ldI(const void* p, size_t i, int i64) {
    return i64 ? (int)((const long long*)p)[i] : ((const int*)p)[i];
}
__device__ __forceinline__ void stF(void* p, size_t i, float v, int f32) {
    if (f32) ((float*)p)[i] = v;
    else     ((__hip_bfloat16*)p)[i] = __float2bfloat16(v);
}

// ---- fp16x2 pack/unpack (SCALAR unions only — arrays of unions spill to scratch!) ----
union H2U { uint32 u; __half2 h; };
__device__ __forceinline__ float2 up16(uint32 u) {
    H2U c; c.u = u;
    return __half22float2(c.h);
}
__device__ __forceinline__ __half2 u2h(uint32 u) {
    H2U c; c.u = u;
    return c.h;
}
__device__ __forceinline__ uint32 pk16(float a, float b) {
    H2U c; c.h = __floats2half2_rn(a, b);
    return c.u;
}
__device__ __forceinline__ unsigned short bfbits(float f) {
    __hip_bfloat16 b = __float2bfloat16(f);
    return *(unsigned short*)&b;
}

// ---- OCTET gather: 8 lanes own one node; lane q owns features 8q..8q+7 (16B) -----
// Wave covers 8 nodes × 8 edges = 64 edges per batch (4× the old wave-per-node),
// each lane with 8 × b128 loads in flight. Indices: 1 coalesced load/lane + 8
// intra-octet shfl, predicated to zero pad row (index N_NODES). Next-batch index
// load is prefetched. NO cross-lane reduce needed — aggregation is feature-parallel.
struct Acc8 { float2 p0, p1, p2, p3; };

__device__ __forceinline__ void accum(Acc8& A, const uint4 d) {
    const float2 f0 = up16(d.x), f1 = up16(d.y), f2 = up16(d.z), f3 = up16(d.w);
    A.p0.x += f0.x; A.p0.y += f0.y;
    A.p1.x += f1.x; A.p1.y += f1.y;
    A.p2.x += f2.x; A.p2.y += f2.y;
    A.p3.x += f3.x; A.p3.y += f3.y;
}

__device__ __forceinline__ void oct_gather(const int* __restrict__ sp,
                                           const uint32* __restrict__ rows,
                                           const int beg, const int end,
                                           const int q, const int obase,
                                           Acc8& A) {
    int pre = sp[beg + q];                       // pad-safe (src has +64 pad)
    int myidx = (beg + q < end) ? pre : N_NODES;
    for (int jj = beg; jj < end; jj += 8) {
        const int cur = myidx;
        const int nx = jj + 8 + q;
        pre = sp[nx];                            // prefetch next batch (pad-safe)
        myidx = (nx < end) ? pre : N_NODES;
        const int i0 = __shfl(cur, obase | 0, 64);
        const int i1 = __shfl(cur, obase | 1, 64);
        const int i2 = __shfl(cur, obase | 2, 64);
        const int i3 = __shfl(cur, obase | 3, 64);
        const int i4 = __shfl(cur, obase | 4, 64);
        const int i5 = __shfl(cur, obase | 5, 64);
        const int i6 = __shfl(cur, obase | 6, 64);
        const int i7 = __shfl(cur, obase | 7, 64);
        const uint32 qo = (uint32)(q << 2);
        const uint4 d0 = *(const uint4*)(rows + ((uint32)i0 * 32u + qo));
        const uint4 d1 = *(const uint4*)(rows + ((uint32)i1 * 32u + qo));
        const uint4 d2 = *(const uint4*)(rows + ((uint32)i2 * 32u + qo));
        const uint4 d3 = *(const uint4*)(rows + ((uint32)i3 * 32u + qo));
        const uint4 d4 = *(const uint4*)(rows + ((uint32)i4 * 32u + qo));
        const uint4 d5 = *(const uint4*)(rows + ((uint32)i5 * 32u + qo));
        const uint4 d6 = *(const uint4*)(rows + ((uint32)i6 * 32u + qo));
        const uint4 d7 = *(const uint4*)(rows + ((uint32)i7 * 32u + qo));
        accum(A, d0); accum(A, d1); accum(A, d2); accum(A, d3);
        accum(A, d4); accum(A, d5); accum(A, d6); accum(A, d7);
    }
}

// ---------------- dtype sniffer ----------------------------------------------------
__global__ void GCNEncoder_77214922048129_kernel(const void* x, const void* ei,
                                                 int* flags) {
    __shared__ int cnt_weird, cnt_zero;
    if (threadIdx.x == 0) { cnt_weird = 0; cnt_zero = 0; }
    __syncthreads();
    const unsigned short* u = (const unsigned short*)x;
    int w = 0;
    for (int i = threadIdx.x; i < 2048; i += 256) {
        int e = (u[i] >> 7) & 0xFF;
        if (e == 0xFF || e >= 159 || (e > 0 && e <= 95)) w++;
    }
    atomicAdd(&cnt_weird, w);
    const int* ii = (const int*)ei;
    int z = 0;
    for (int i = threadIdx.x; i < 128; i += 256) {
        if (ii[2 * i + 1] == 0) z++;
    }
    atomicAdd(&cnt_zero, z);
    __syncthreads();
    if (threadIdx.x == 0) {
        flags[0] = (cnt_weird > 64) ? 1 : 0;  // fp32 floats
        flags[1] = (cnt_zero > 64) ? 1 : 0;   // int64 indices
    }
}

// ---------------- degree over col (self-loop added analytically) -------------------
__global__ void k_deg(const void* __restrict__ ei, int* __restrict__ deg,
                      const int* __restrict__ flags) {
    const int i64 = flags[1];
    int e = blockIdx.x * blockDim.x + threadIdx.x;
    if (e < N_EDGES) atomicAdd(&deg[ldI(ei, (size_t)N_EDGES + e, i64)], 1);
}

// ---------------- CSR build: 3-stage parallel exclusive scan of deg ----------------
#define NB_SCAN ((N_NODES + 255) / 256)  // 391

// fused: block-sum for scan + dinv computation
__global__ __launch_bounds__(256) void k_bsum(const int* __restrict__ deg,
                                              int* __restrict__ bsum,
                                              float* __restrict__ dinv) {
    __shared__ int sh[256];
    int idx = blockIdx.x * 256 + threadIdx.x;
    int d = 0;
    if (idx < N_NODES) {
        d = deg[idx];
        dinv[idx] = rsqrtf((float)d + 1.0f);  // +1 = self-loop
    }
    sh[threadIdx.x] = d;
    __syncthreads();
#pragma unroll
    for (int off = 128; off > 0; off >>= 1) {
        if (threadIdx.x < off) sh[threadIdx.x] += sh[threadIdx.x + off];
        __syncthreads();
    }
    if (threadIdx.x == 0) bsum[blockIdx.x] = sh[0];
}

__global__ __launch_bounds__(512) void k_bscan(const int* __restrict__ bsum,
                                               int* __restrict__ bbase) {
    __shared__ int sh[512];
    const int t = threadIdx.x;
    sh[t] = (t < NB_SCAN) ? bsum[t] : 0;
    __syncthreads();
    for (int off = 1; off < 512; off <<= 1) {
        int v = (t >= off) ? sh[t - off] : 0;
        __syncthreads();
        sh[t] += v;
        __syncthreads();
    }
    if (t < NB_SCAN) bbase[t] = (t == 0) ? 0 : sh[t - 1];
}

__global__ __launch_bounds__(256) void k_rowptr(const int* __restrict__ deg,
                                                const int* __restrict__ bbase,
                                                int* __restrict__ rowptr,
                                                int* __restrict__ cursor) {
    __shared__ int sh[256];
    const int t = threadIdx.x;
    const int idx = blockIdx.x * 256 + t;
    const int d = (idx < N_NODES) ? deg[idx] : 0;
    sh[t] = d;
    __syncthreads();
    for (int off = 1; off < 256; off <<= 1) {
        int v = (t >= off) ? sh[t - off] : 0;
        __syncthreads();
        sh[t] += v;
        __syncthreads();
    }
    if (idx < N_NODES) {
        int r = bbase[blockIdx.x] + sh[t] - d;  // exclusive
        rowptr[idx] = r;
        cursor[idx] = r;
    }
    if (idx == 0) rowptr[N_NODES] = N_EDGES;
}

// ---------------- CSR scatter: src[pos(c)] = r -------------------------------------
__global__ __launch_bounds__(256) void k_csr(const void* __restrict__ ei,
                                             int* __restrict__ cursor,
                                             int* __restrict__ src,
                                             const int* __restrict__ flags) {
    const int i64 = flags[1];
    int e = blockIdx.x * blockDim.x + threadIdx.x;
    if (e < N_EDGES) {
        int r = ldI(ei, e, i64);
        int c = ldI(ei, (size_t)N_EDGES + e, i64);
        int pos = atomicAdd(&cursor[c], 1);
        src[pos] = r;
    }
}

// ---------------- xs16[n] = fp16( x[n] * dinv[n] ), packed pairs -------------------
// Also zeroes the pad row (index N_NODES) of BOTH xs16 and a2u for predicated gather.
__global__ __launch_bounds__(256) void k_scale(const void* __restrict__ x,
                                               const float* __restrict__ dinv,
                                               uint32* __restrict__ xs16,
                                               uint32* __restrict__ a2u,
                                               const int* __restrict__ flags) {
    const int F32 = flags[0];
    int idx = blockIdx.x * blockDim.x + threadIdx.x;  // feature-pair index
    if (idx < N_NODES * 32) {
        int n = idx >> 5;
        float dv = dinv[n];
        float a = ldF(x, (size_t)idx * 2, F32) * dv;
        float b = ldF(x, (size_t)idx * 2 + 1, F32) * dv;
        xs16[idx] = pk16(a, b);
    } else if (idx < (N_NODES + 1) * 32) {
        xs16[idx] = 0u;  // zero pad row: dummy gather target contributes 0
        a2u[idx] = 0u;
    }
}

// ------ fused layer1: OCTET gather + per-node GEMM1 + LN + ReLU + GEMM2 ------------
// Gather: 8 nodes per wave (octet each), 64 edges per latency window. Compute: wave
// processes its 8 nodes sequentially with the proven hfma2 GEMM/LN pipeline.
#define G1W 8
__global__ __launch_bounds__(64 * G1W) void k_gather1(
    const int* __restrict__ rowptr, const int* __restrict__ src,
    const uint32* __restrict__ xsu, const float* __restrict__ dinv,
    const void* __restrict__ b1, const void* __restrict__ lnw,
    const void* __restrict__ lnb, const void* __restrict__ W1,
    const void* __restrict__ W2, uint32* __restrict__ a2u,
    const int* __restrict__ flags) {
    const int F32 = flags[0];
    __shared__ uint2  w1d[32 * 64];    // 16 KB
    __shared__ uint2  w2q[32 * 64];    // 16 KB
    __shared__ float b1s[F_MID], lnws[F_MID], lnbs[F_MID];
    __shared__ uint32 aggp[G1W][8][32];  // per-wave, per-octet agg k-pairs ; 8 KB
    __shared__ uint32 usp[G1W][64];      // packed u k-pairs per wave ; 2 KB
    for (int i = threadIdx.x; i < 32 * 64; i += 64 * G1W) {
        const int k2 = i >> 6, f = i & 63;
        uint2 w;
        w.x = pk16(ldF(W1, (size_t)(2 * k2) * F_MID + f, F32),
                   ldF(W1, (size_t)(2 * k2 + 1) * F_MID + f, F32));
        w.y = pk16(ldF(W1, (size_t)(2 * k2) * F_MID + f + 64, F32),
                   ldF(W1, (size_t)(2 * k2 + 1) * F_MID + f + 64, F32));
        w1d[i] = w;
    }
    for (int i = threadIdx.x; i < 32 * 64; i += 64 * G1W) {
        const int k4 = i >> 6, f = i & 63;
        uint2 w;
        w.x = pk16(ldF(W2, (size_t)(4 * k4) * F_OUT + f, F32),
                   ldF(W2, (size_t)(4 * k4 + 1) * F_OUT + f, F32));
        w.y = pk16(ldF(W2, (size_t)(4 * k4 + 2) * F_OUT + f, F32),
                   ldF(W2, (size_t)(4 * k4 + 3) * F_OUT + f, F32));
        w2q[i] = w;
    }
    if (threadIdx.x < F_MID) {
        b1s[threadIdx.x] = ldF(b1, threadIdx.x, F32);
        lnws[threadIdx.x] = ldF(lnw, threadIdx.x, F32);
        lnbs[threadIdx.x] = ldF(lnb, threadIdx.x, F32);
    }
    __syncthreads();
    const int wid = threadIdx.x >> 6;
    const int lane = threadIdx.x & 63;
    const int q = lane & 7;       // feature-slice within octet (16B)
    const int oct = lane >> 3;    // node slot within wave
    const int obase = lane & 56;  // octet base lane
    const int gw = (blockIdx.x * (64 * G1W) + threadIdx.x) >> 6;
    const int totw = (gridDim.x * (64 * G1W)) >> 6;
    const __half2 hz = __float2half2_rn(0.f);
    for (int nb = gw * 8; nb < N_NODES; nb += totw * 8) {
        // ---- OCTET gather phase: 8 nodes in parallel ----
        const int n = nb + oct;
        const int nc = (n < N_NODES) ? n : (N_NODES - 1);
        int beg = rowptr[nc], end = rowptr[nc + 1];
        if (n >= N_NODES) { beg = 0; end = 0; }
        const uint32 nself = (n < N_NODES) ? (uint32)n : (uint32)N_NODES;
        const uint4 sd = *(const uint4*)(xsu + (nself * 32u + (uint32)(q << 2)));
        Acc8 A = {{0.f, 0.f}, {0.f, 0.f}, {0.f, 0.f}, {0.f, 0.f}};
        oct_gather(src, xsu, beg, end, q, obase, A);
        accum(A, sd);  // self (already * dinv)
        uint4 pkd;
        pkd.x = pk16(A.p0.x, A.p0.y);
        pkd.y = pk16(A.p1.x, A.p1.y);
        pkd.z = pk16(A.p2.x, A.p2.y);
        pkd.w = pk16(A.p3.x, A.p3.y);
        *(uint4*)&aggp[wid][oct][q * 4] = pkd;  // within-wave RAW (lgkmcnt wait)
        // ---- compute phase: 8 nodes sequentially ----
        for (int c = 0; c < 8; ++c) {
            const int node = nb + c;
            if (node >= N_NODES) break;  // wave-uniform
            const float dv = dinv[node];
            // ---- GEMM1: lane f handles f and f+64; hfma2, promote every 16 k ----
            __half2 hc0 = hz, hc1 = hz;
            float g0 = 0.f, g1 = 0.f;
#pragma unroll
            for (int qq = 0; qq < 8; ++qq) {
                const uint4 aq = ((const uint4*)aggp[wid][c])[qq];  // b128 broadcast
#pragma unroll
                for (int j = 0; j < 4; ++j) {
                    const uint32 av = (j == 0) ? aq.x : (j == 1) ? aq.y : (j == 2) ? aq.z : aq.w;
                    const uint2 wv = w1d[(qq * 4 + j) * 64 + lane];
                    hc0 = __hfma2(u2h(av), u2h(wv.x), hc0);
                    hc1 = __hfma2(u2h(av), u2h(wv.y), hc1);
                }
                if (qq & 1) {
                    float2 p;
                    p = __half22float2(hc0); g0 += p.x + p.y; hc0 = hz;
                    p = __half22float2(hc1); g1 += p.x + p.y; hc1 = hz;
                }
            }
            const float t0 = g0 * dv + b1s[lane];
            const float t1 = g1 * dv + b1s[lane + 64];
            // ---- LayerNorm over 128 ----
            float s = t0 + t1;
#pragma unroll
            for (int off = 32; off > 0; off >>= 1) s += __shfl_xor(s, off, 64);
            const float mu = s * (1.f / 128.f);
            const float d0 = t0 - mu, d1 = t1 - mu;
            float v = d0 * d0 + d1 * d1;
#pragma unroll
            for (int off = 32; off > 0; off >>= 1) v += __shfl_xor(v, off, 64);
            const float rstd = rsqrtf(v * (1.f / 128.f) + 1e-5f);
            const float u0 = fmaxf(d0 * rstd * lnws[lane] + lnbs[lane], 0.f);
            const float u1 = fmaxf(d1 * rstd * lnws[lane + 64] + lnbs[lane + 64], 0.f);
            // repack u into k-pair layout: usp[k2] = (u[2k2], u[2k2+1])
            const int praw = (int)pk16(u0, u1);  // lane m: (u[m], u[m+64])
            const int ia = __shfl(praw, (2 * lane) & 63, 64);
            const int ib = __shfl(praw, (2 * lane + 1) & 63, 64);
            const float2 fa = up16((uint32)ia), fb = up16((uint32)ib);
            const float ux = (lane < 32) ? fa.x : fa.y;  // u[2*lane]
            const float uy = (lane < 32) ? fb.x : fb.y;  // u[2*lane+1]
            usp[wid][lane] = pk16(ux, uy);
            // ---- GEMM2: a2[lane] = (u @ W2)[lane] * dv ----
            __half2 hc = hz;
            float facc = 0.f;
#pragma unroll
            for (int qq = 0; qq < 16; ++qq) {
                const uint4 uq = ((const uint4*)usp[wid])[qq];  // b128 broadcast
                const uint2 wv0 = w2q[(2 * qq) * 64 + lane];
                const uint2 wv1 = w2q[(2 * qq + 1) * 64 + lane];
                hc = __hfma2(u2h(uq.x), u2h(wv0.x), hc);
                hc = __hfma2(u2h(uq.y), u2h(wv0.y), hc);
                hc = __hfma2(u2h(uq.z), u2h(wv1.x), hc);
                hc = __hfma2(u2h(uq.w), u2h(wv1.y), hc);
                if ((qq & 3) == 3) {
                    const float2 p = __half22float2(hc);
                    facc += p.x + p.y;
                    hc = hz;
                }
            }
            const float a2 = facc * dv;
            // ---- store packed fp16 pairs ----
            const float e  = __shfl(a2, (2 * lane) & 63, 64);
            const float f2 = __shfl(a2, (2 * lane + 1) & 63, 64);
            if (lane < 32) a2u[(size_t)node * 32 + lane] = pk16(e, f2);
        }
    }
}

// ------ fused layer2: OCTET gather + self + dinv + b2 → out ------------------------
// Feature-parallel: no cross-lane reduce at all. Lane q of each octet produces the
// 16B output slice of its node directly.
__global__ __launch_bounds__(256) void k_gather2(
    const int* __restrict__ rowptr, const int* __restrict__ src,
    const uint32* __restrict__ a2u, const float* __restrict__ dinv,
    const void* __restrict__ b2, void* __restrict__ out,
    const int* __restrict__ flags) {
    const int F32 = flags[0];
    const int lane = threadIdx.x & 63;
    const int q = lane & 7;
    const int oct = lane >> 3;
    const int obase = lane & 56;
    // b2 slice into registers (fixed per lane)
    const float bb0 = ldF(b2, q * 8 + 0, F32), bb1 = ldF(b2, q * 8 + 1, F32);
    const float bb2 = ldF(b2, q * 8 + 2, F32), bb3 = ldF(b2, q * 8 + 3, F32);
    const float bb4 = ldF(b2, q * 8 + 4, F32), bb5 = ldF(b2, q * 8 + 5, F32);
    const float bb6 = ldF(b2, q * 8 + 6, F32), bb7 = ldF(b2, q * 8 + 7, F32);
    const int gw = (blockIdx.x * 256 + threadIdx.x) >> 6;
    const int totw = (gridDim.x * 256) >> 6;
    for (int nb = gw * 8; nb < N_NODES; nb += totw * 8) {
        const int n = nb + oct;
        const int nc = (n < N_NODES) ? n : (N_NODES - 1);
        int beg = rowptr[nc], end = rowptr[nc + 1];
        if (n >= N_NODES) { beg = 0; end = 0; }
        const uint32 nself = (n < N_NODES) ? (uint32)n : (uint32)N_NODES;
        const uint4 sd = *(const uint4*)(a2u + (nself * 32u + (uint32)(q << 2)));
        const float dv = dinv[nc];
        Acc8 A = {{0.f, 0.f}, {0.f, 0.f}, {0.f, 0.f}, {0.f, 0.f}};
        oct_gather(src, a2u, beg, end, q, obase, A);
        accum(A, sd);  // self term
        const float r0 = A.p0.x * dv + bb0, r1 = A.p0.y * dv + bb1;
        const float r2 = A.p1.x * dv + bb2, r3 = A.p1.y * dv + bb3;
        const float r4 = A.p2.x * dv + bb4, r5 = A.p2.y * dv + bb5;
        const float r6 = A.p3.x * dv + bb6, r7 = A.p3.y * dv + bb7;
        if (n < N_NODES) {
            if (F32) {
                float4 o0; o0.x = r0; o0.y = r1; o0.z = r2; o0.w = r3;
                float4 o1; o1.x = r4; o1.y = r5; o1.z = r6; o1.w = r7;
                ((float4*)out)[(size_t)n * 16 + (q << 1)]     = o0;
                ((float4*)out)[(size_t)n * 16 + (q << 1) + 1] = o1;
            } else {
                uint4 ub;
                ub.x = ((uint32)bfbits(r1) << 16) | (uint32)bfbits(r0);
                ub.y = ((uint32)bfbits(r3) << 16) | (uint32)bfbits(r2);
                ub.z = ((uint32)bfbits(r5) << 16) | (uint32)bfbits(r4);
                ub.w = ((uint32)bfbits(r7) << 16) | (uint32)bfbits(r6);
                ((uint4*)out)[(size_t)n * 8 + q] = ub;
            }
        }
    }
}

// ---------------- pooling: segmented per-wave reduction (reads d_out h) ------------
__global__ __launch_bounds__(256) void k_pool(const void* __restrict__ hout,
                                              const void* __restrict__ batch,
                                              float* __restrict__ gsum,
                                              const int* __restrict__ flags) {
    const int F32 = flags[0];
    const int i64 = flags[1];
    const int wid = (blockIdx.x * blockDim.x + threadIdx.x) >> 6;
    const int lane = threadIdx.x & 63;
    const int nwaves = (gridDim.x * blockDim.x) >> 6;
    const int per = (N_NODES + nwaves - 1) / nwaves;
    const int start = wid * per;
    const int end = min(start + per, N_NODES);
    if (start >= end) return;
    float acc = 0.f;
    int gcur = ldI(batch, start, i64);
    for (int n = start; n < end; ++n) {
        int g = ldI(batch, n, i64);
        if (g != gcur) {
            atomicAdd(&gsum[gcur * 64 + lane], acc);
            acc = 0.f;
            gcur = g;
        }
        acc += ldF(hout, (size_t)n * 64 + lane, F32);
    }
    atomicAdd(&gsum[gcur * 64 + lane], acc);
}

// ---------------- g-output with inline per-graph count (binary search) -------------
__global__ void k_gout(const float* __restrict__ gsum, const void* __restrict__ batch,
                       void* __restrict__ out, const int* __restrict__ flags) {
    const int F32 = flags[0];
    const int i64 = flags[1];
    int idx = blockIdx.x * blockDim.x + threadIdx.x;
    if (idx < N_GRAPHS * 64) {
        int g = idx >> 6;  // wave-uniform within 64-thread groups
        int lo = 0, hi = N_NODES;
        while (lo < hi) { int m = (lo + hi) >> 1; if (ldI(batch, m, i64) < g) lo = m + 1; else hi = m; }
        int lb = lo;
        lo = 0; hi = N_NODES;
        while (lo < hi) { int m = (lo + hi) >> 1; if (ldI(batch, m, i64) <= g) lo = m + 1; else hi = m; }
        float c = (float)max(lo - lb, 1);
        stF(out, (size_t)N_NODES * F_OUT + idx, gsum[idx] / c, F32);
    }
}

extern "C" void kernel_launch(void* const* d_in, const int* in_sizes, int n_in,
                              void* d_out, int out_size, void* d_ws, size_t ws_size,
                              hipStream_t stream) {
    const void* x   = d_in[0];
    const void* ei  = d_in[1];
    const void* bat = d_in[2];
    const void* W1  = d_in[3];
    const void* b1  = d_in[4];
    const void* lnw = d_in[5];
    const void* lnb = d_in[6];
    const void* W2  = d_in[7];
    const void* b2  = d_in[8];

    char* ws = (char*)d_ws;
    size_t o = 0;
    auto alloc = [&](size_t bytes) { size_t r = o; o += (bytes + 255) & ~(size_t)255; return r; };
    int*    flags  = (int*)   (ws + alloc(2 * 4));
    float*  dinv   = (float*) (ws + alloc((size_t)N_NODES * 4));
    int*    deg    = (int*)   (ws + alloc((size_t)N_NODES * 4));
    int*    rowptr = (int*)   (ws + alloc((size_t)(N_NODES + 1) * 4));
    int*    cursor = (int*)   (ws + alloc((size_t)N_NODES * 4));
    int*    bsum   = (int*)   (ws + alloc((size_t)NB_SCAN * 4));
    int*    bbase  = (int*)   (ws + alloc((size_t)NB_SCAN * 4));
    int*    srcidx = (int*)   (ws + alloc((size_t)(N_EDGES + 64) * 4));      // +64 pad for predicated idx loads
    uint32* xs16   = (uint32*)(ws + alloc((size_t)(N_NODES + 1) * 32 * 4));  // +1 zero pad row
    uint32* a2u    = (uint32*)(ws + alloc((size_t)(N_NODES + 1) * 32 * 4));  // +1 zero pad row
    float*  gsum   = (float*) (ws + alloc((size_t)N_GRAPHS * 64 * 4));

    hipMemsetAsync(deg, 0, (size_t)N_NODES * 4, stream);
    hipMemsetAsync(gsum, 0, (size_t)N_GRAPHS * 64 * 4, stream);

    GCNEncoder_77214922048129_kernel<<<1, 256, 0, stream>>>(x, ei, flags);
    k_deg<<<(N_EDGES + 255) / 256, 256, 0, stream>>>(ei, deg, flags);
    k_bsum<<<NB_SCAN, 256, 0, stream>>>(deg, bsum, dinv);
    k_bscan<<<1, 512, 0, stream>>>(bsum, bbase);
    k_rowptr<<<NB_SCAN, 256, 0, stream>>>(deg, bbase, rowptr, cursor);
    k_csr<<<(N_EDGES + 255) / 256, 256, 0, stream>>>(ei, cursor, srcidx, flags);
    k_scale<<<((N_NODES + 1) * 32 + 255) / 256, 256, 0, stream>>>(x, dinv, xs16, a2u, flags);
    // one 8-node group per wave: 1563 blocks * 8 waves = 12504 waves >= 12500 groups
    k_gather1<<<1563, 64 * G1W, 0, stream>>>(rowptr, srcidx, xs16, dinv, b1, lnw, lnb,
                                             W1, W2, a2u, flags);
    // 3125 blocks * 4 waves = 12500 waves = 12500 groups (exact)
    k_gather2<<<3125, 256, 0, stream>>>(rowptr, srcidx, a2u, dinv, b2, d_out, flags);
    k_pool<<<512, 256, 0, stream>>>(d_out, bat, gsum, flags);
    k_gout<<<(N_GRAPHS * 64 + 255) / 256, 256, 0, stream>>>(gsum, bat, d_out, flags);
}

// Round 4
// 364.827 us; speedup vs baseline: 1.7607x; 1.3418x over previous
//
#include <hip/hip_runtime.h>
#include <hip/hip_bf16.h>
#include <hip/hip_fp16.h>
#include <cstdint>

#define N_NODES 100000
#define N_EDGES 1600000
#define N_GRAPHS 64
#define F_IN 64
#define F_MID 128
#define F_OUT 64

typedef unsigned int uint32;

// ---- bucket partition parameters --------------------------------------------------
#define BK_SHIFT 10
#define BK_COLS (1 << BK_SHIFT)                      // 1024 cols per bucket
#define NBUK ((N_NODES + BK_COLS - 1) >> BK_SHIFT)   // 98 buckets
#define BK_CAP 17408                                 // mean 16384 + ~8 sigma margin
#define EPB 4096                                     // edges per partition block
#define NPB ((N_EDGES + EPB - 1) / EPB)              // 391 blocks

// ---- dtype-agnostic accessors (flags[0]=1 → floats are fp32; flags[1]=1 → ints are int64)
__device__ __forceinline__ float ldF(const void* p, size_t i, int f32) {
    return f32 ? ((const float*)p)[i]
               : __bfloat162float(((const __hip_bfloat16*)p)[i]);
}
__device__ __forceinline__ int ldI(const void* p, size_t i, int i64) {
    return i64 ? (int)((const long long*)p)[i] : ((const int*)p)[i];
}
__device__ __forceinline__ void stF(void* p, size_t i, float v, int f32) {
    if (f32) ((float*)p)[i] = v;
    else     ((__hip_bfloat16*)p)[i] = __float2bfloat16(v);
}

// ---- fp16x2 pack/unpack (SCALAR unions only — arrays of unions spill to scratch!) ----
union H2U { uint32 u; __half2 h; };
__device__ __forceinline__ float2 up16(uint32 u) {
    H2U c; c.u = u;
    return __half22float2(c.h);
}
__device__ __forceinline__ __half2 u2h(uint32 u) {
    H2U c; c.u = u;
    return c.h;
}
__device__ __forceinline__ uint32 pk16(float a, float b) {
    H2U c; c.h = __floats2half2_rn(a, b);
    return c.u;
}
__device__ __forceinline__ unsigned short bfbits(float f) {
    __hip_bfloat16 b = __float2bfloat16(f);
    return *(unsigned short*)&b;
}

// ---- OCTET gather: 8 lanes own one node; lane q owns features 8q..8q+7 (16B) -----
struct Acc8 { float2 p0, p1, p2, p3; };

__device__ __forceinline__ void accum(Acc8& A, const uint4 d) {
    const float2 f0 = up16(d.x), f1 = up16(d.y), f2 = up16(d.z), f3 = up16(d.w);
    A.p0.x += f0.x; A.p0.y += f0.y;
    A.p1.x += f1.x; A.p1.y += f1.y;
    A.p2.x += f2.x; A.p2.y += f2.y;
    A.p3.x += f3.x; A.p3.y += f3.y;
}

__device__ __forceinline__ void oct_gather(const int* __restrict__ sp,
                                           const uint32* __restrict__ rows,
                                           const int beg, const int end,
                                           const int q, const int obase,
                                           Acc8& A) {
    int pre = sp[beg + q];                       // pad-safe (src has +64 pad)
    int myidx = (beg + q < end) ? pre : N_NODES;
    for (int jj = beg; jj < end; jj += 8) {
        const int cur = myidx;
        const int nx = jj + 8 + q;
        pre = sp[nx];                            // prefetch next batch (pad-safe)
        myidx = (nx < end) ? pre : N_NODES;
        const int i0 = __shfl(cur, obase | 0, 64);
        const int i1 = __shfl(cur, obase | 1, 64);
        const int i2 = __shfl(cur, obase | 2, 64);
        const int i3 = __shfl(cur, obase | 3, 64);
        const int i4 = __shfl(cur, obase | 4, 64);
        const int i5 = __shfl(cur, obase | 5, 64);
        const int i6 = __shfl(cur, obase | 6, 64);
        const int i7 = __shfl(cur, obase | 7, 64);
        const uint32 qo = (uint32)(q << 2);
        const uint4 d0 = *(const uint4*)(rows + ((uint32)i0 * 32u + qo));
        const uint4 d1 = *(const uint4*)(rows + ((uint32)i1 * 32u + qo));
        const uint4 d2 = *(const uint4*)(rows + ((uint32)i2 * 32u + qo));
        const uint4 d3 = *(const uint4*)(rows + ((uint32)i3 * 32u + qo));
        const uint4 d4 = *(const uint4*)(rows + ((uint32)i4 * 32u + qo));
        const uint4 d5 = *(const uint4*)(rows + ((uint32)i5 * 32u + qo));
        const uint4 d6 = *(const uint4*)(rows + ((uint32)i6 * 32u + qo));
        const uint4 d7 = *(const uint4*)(rows + ((uint32)i7 * 32u + qo));
        accum(A, d0); accum(A, d1); accum(A, d2); accum(A, d3);
        accum(A, d4); accum(A, d5); accum(A, d6); accum(A, d7);
    }
}

// ---------------- dtype sniffer + gcur init ----------------------------------------
__global__ void GCNEncoder_77214922048129_kernel(const void* x, const void* ei,
                                                 int* flags, int* gcur) {
    __shared__ int cnt_weird, cnt_zero;
    if (threadIdx.x == 0) { cnt_weird = 0; cnt_zero = 0; }
    if (threadIdx.x < NBUK) gcur[threadIdx.x] = threadIdx.x * BK_CAP;
    __syncthreads();
    const unsigned short* u = (const unsigned short*)x;
    int w = 0;
    for (int i = threadIdx.x; i < 2048; i += 256) {
        int e = (u[i] >> 7) & 0xFF;
        if (e == 0xFF || e >= 159 || (e > 0 && e <= 95)) w++;
    }
    atomicAdd(&cnt_weird, w);
    const int* ii = (const int*)ei;
    int z = 0;
    for (int i = threadIdx.x; i < 128; i += 256) {
        if (ii[2 * i + 1] == 0) z++;
    }
    atomicAdd(&cnt_zero, z);
    __syncthreads();
    if (threadIdx.x == 0) {
        flags[0] = (cnt_weird > 64) ? 1 : 0;  // fp32 floats
        flags[1] = (cnt_zero > 64) ? 1 : 0;   // int64 indices
    }
}

// ---------------- bucket partition: edges → part[bucket regions] -------------------
// LDS-staged: per-block per-bucket counts, ONE global atomic per bucket per block,
// then contiguous slice writes (~42 edges × 8B per slice). Replaces the 1.6M-atomic
// random scatter (was 16× write-amplified).
__global__ __launch_bounds__(256) void k_part(const void* __restrict__ ei,
                                              uint2* __restrict__ part,
                                              int* __restrict__ gcur,
                                              const int* __restrict__ flags) {
    const int i64 = flags[1];
    __shared__ uint2 est[EPB];                 // 32 KB edge stage
    __shared__ int cnt[NBUK], base_[NBUK], cur[NBUK];
    const int t = threadIdx.x;
    const int e0 = blockIdx.x * EPB;
    const int ne = min(EPB, N_EDGES - e0);
    for (int i = t; i < NBUK; i += 256) { cnt[i] = 0; cur[i] = 0; }
    __syncthreads();
    for (int i = t; i < ne; i += 256) {
        const int e = e0 + i;
        const int r = ldI(ei, e, i64);
        const int c = ldI(ei, (size_t)N_EDGES + e, i64);
        est[i] = make_uint2((uint32)r, (uint32)c);
        atomicAdd(&cnt[c >> BK_SHIFT], 1);
    }
    __syncthreads();
    for (int b = t; b < NBUK; b += 256)
        base_[b] = (cnt[b] > 0) ? atomicAdd(&gcur[b], cnt[b]) : 0;
    __syncthreads();
    for (int i = t; i < ne; i += 256) {
        const uint2 rc = est[i];
        const int b = (int)(rc.y >> BK_SHIFT);
        const int off = atomicAdd(&cur[b], 1);
        const int pos = base_[b] + off;
        if (pos < (b + 1) * BK_CAP) part[pos] = rc;  // overflow guard (statistically never)
    }
}

// ---------------- per-bucket degree histogram → sequential deg writes --------------
__global__ __launch_bounds__(256) void k_bdeg(const uint2* __restrict__ part,
                                              const int* __restrict__ gcur,
                                              int* __restrict__ deg) {
    __shared__ int h[BK_COLS];
    const int b = blockIdx.x;
    const int t = threadIdx.x;
    for (int i = t; i < BK_COLS; i += 256) h[i] = 0;
    __syncthreads();
    const int beg = b * BK_CAP;
    const int cnt = min(gcur[b] - beg, BK_CAP);
    for (int i = t; i < cnt; i += 256)
        atomicAdd(&h[part[beg + i].y & (BK_COLS - 1)], 1);
    __syncthreads();
    const int cbase = b << BK_SHIFT;
    for (int i = t; i < BK_COLS; i += 256)
        if (cbase + i < N_NODES) deg[cbase + i] = h[i];
}

// ---------------- per-bucket CSR fill: scatter confined to ~65KB L2 window ---------
__global__ __launch_bounds__(256) void k_fill(const uint2* __restrict__ part,
                                              const int* __restrict__ gcur,
                                              const int* __restrict__ rowptr,
                                              int* __restrict__ src) {
    __shared__ int cur[BK_COLS];
    const int b = blockIdx.x;
    const int t = threadIdx.x;
    const int cbase = b << BK_SHIFT;
    for (int i = t; i < BK_COLS; i += 256)
        cur[i] = (cbase + i < N_NODES) ? rowptr[cbase + i] : 0;
    __syncthreads();
    const int beg = b * BK_CAP;
    const int cnt = min(gcur[b] - beg, BK_CAP);
    for (int i = t; i < cnt; i += 256) {
        const uint2 rc = part[beg + i];
        const int pos = atomicAdd(&cur[rc.y & (BK_COLS - 1)], 1);
        src[pos] = (int)rc.x;
    }
}

// ---------------- CSR scan: 3-stage parallel exclusive scan of deg -----------------
#define NB_SCAN ((N_NODES + 255) / 256)  // 391

// fused: block-sum for scan + dinv computation
__global__ __launch_bounds__(256) void k_bsum(const int* __restrict__ deg,
                                              int* __restrict__ bsum,
                                              float* __restrict__ dinv) {
    __shared__ int sh[256];
    int idx = blockIdx.x * 256 + threadIdx.x;
    int d = 0;
    if (idx < N_NODES) {
        d = deg[idx];
        dinv[idx] = rsqrtf((float)d + 1.0f);  // +1 = self-loop
    }
    sh[threadIdx.x] = d;
    __syncthreads();
#pragma unroll
    for (int off = 128; off > 0; off >>= 1) {
        if (threadIdx.x < off) sh[threadIdx.x] += sh[threadIdx.x + off];
        __syncthreads();
    }
    if (threadIdx.x == 0) bsum[blockIdx.x] = sh[0];
}

__global__ __launch_bounds__(512) void k_bscan(const int* __restrict__ bsum,
                                               int* __restrict__ bbase) {
    __shared__ int sh[512];
    const int t = threadIdx.x;
    sh[t] = (t < NB_SCAN) ? bsum[t] : 0;
    __syncthreads();
    for (int off = 1; off < 512; off <<= 1) {
        int v = (t >= off) ? sh[t - off] : 0;
        __syncthreads();
        sh[t] += v;
        __syncthreads();
    }
    if (t < NB_SCAN) bbase[t] = (t == 0) ? 0 : sh[t - 1];
}

__global__ __launch_bounds__(256) void k_rowptr(const int* __restrict__ deg,
                                                const int* __restrict__ bbase,
                                                int* __restrict__ rowptr) {
    __shared__ int sh[256];
    const int t = threadIdx.x;
    const int idx = blockIdx.x * 256 + t;
    const int d = (idx < N_NODES) ? deg[idx] : 0;
    sh[t] = d;
    __syncthreads();
    for (int off = 1; off < 256; off <<= 1) {
        int v = (t >= off) ? sh[t - off] : 0;
        __syncthreads();
        sh[t] += v;
        __syncthreads();
    }
    if (idx < N_NODES) rowptr[idx] = bbase[blockIdx.x] + sh[t] - d;  // exclusive
    if (idx == 0) rowptr[N_NODES] = N_EDGES;
}

// ---------------- xs16[n] = fp16( x[n] * dinv[n] ), packed pairs -------------------
// Also zeroes the pad row (index N_NODES) of BOTH xs16 and a2u for predicated gather.
__global__ __launch_bounds__(256) void k_scale(const void* __restrict__ x,
                                               const float* __restrict__ dinv,
                                               uint32* __restrict__ xs16,
                                               uint32* __restrict__ a2u,
                                               const int* __restrict__ flags) {
    const int F32 = flags[0];
    int idx = blockIdx.x * blockDim.x + threadIdx.x;  // feature-pair index
    if (idx < N_NODES * 32) {
        int n = idx >> 5;
        float dv = dinv[n];
        float a = ldF(x, (size_t)idx * 2, F32) * dv;
        float b = ldF(x, (size_t)idx * 2 + 1, F32) * dv;
        xs16[idx] = pk16(a, b);
    } else if (idx < (N_NODES + 1) * 32) {
        xs16[idx] = 0u;  // zero pad row: dummy gather target contributes 0
        a2u[idx] = 0u;
    }
}

// ------ fused layer1: OCTET gather + per-node GEMM1 + LN + ReLU + GEMM2 ------------
#define G1W 8
__global__ __launch_bounds__(64 * G1W) void k_gather1(
    const int* __restrict__ rowptr, const int* __restrict__ src,
    const uint32* __restrict__ xsu, const float* __restrict__ dinv,
    const void* __restrict__ b1, const void* __restrict__ lnw,
    const void* __restrict__ lnb, const void* __restrict__ W1,
    const void* __restrict__ W2, uint32* __restrict__ a2u,
    const int* __restrict__ flags) {
    const int F32 = flags[0];
    __shared__ uint2  w1d[32 * 64];    // 16 KB
    __shared__ uint2  w2q[32 * 64];    // 16 KB
    __shared__ float b1s[F_MID], lnws[F_MID], lnbs[F_MID];
    __shared__ uint32 aggp[G1W][8][32];  // per-wave, per-octet agg k-pairs ; 8 KB
    __shared__ uint32 usp[G1W][64];      // packed u k-pairs per wave ; 2 KB
    for (int i = threadIdx.x; i < 32 * 64; i += 64 * G1W) {
        const int k2 = i >> 6, f = i & 63;
        uint2 w;
        w.x = pk16(ldF(W1, (size_t)(2 * k2) * F_MID + f, F32),
                   ldF(W1, (size_t)(2 * k2 + 1) * F_MID + f, F32));
        w.y = pk16(ldF(W1, (size_t)(2 * k2) * F_MID + f + 64, F32),
                   ldF(W1, (size_t)(2 * k2 + 1) * F_MID + f + 64, F32));
        w1d[i] = w;
    }
    for (int i = threadIdx.x; i < 32 * 64; i += 64 * G1W) {
        const int k4 = i >> 6, f = i & 63;
        uint2 w;
        w.x = pk16(ldF(W2, (size_t)(4 * k4) * F_OUT + f, F32),
                   ldF(W2, (size_t)(4 * k4 + 1) * F_OUT + f, F32));
        w.y = pk16(ldF(W2, (size_t)(4 * k4 + 2) * F_OUT + f, F32),
                   ldF(W2, (size_t)(4 * k4 + 3) * F_OUT + f, F32));
        w2q[i] = w;
    }
    if (threadIdx.x < F_MID) {
        b1s[threadIdx.x] = ldF(b1, threadIdx.x, F32);
        lnws[threadIdx.x] = ldF(lnw, threadIdx.x, F32);
        lnbs[threadIdx.x] = ldF(lnb, threadIdx.x, F32);
    }
    __syncthreads();
    const int wid = threadIdx.x >> 6;
    const int lane = threadIdx.x & 63;
    const int q = lane & 7;       // feature-slice within octet (16B)
    const int oct = lane >> 3;    // node slot within wave
    const int obase = lane & 56;  // octet base lane
    const int gw = (blockIdx.x * (64 * G1W) + threadIdx.x) >> 6;
    const int totw = (gridDim.x * (64 * G1W)) >> 6;
    const __half2 hz = __float2half2_rn(0.f);
    for (int nb = gw * 8; nb < N_NODES; nb += totw * 8) {
        // ---- OCTET gather phase: 8 nodes in parallel ----
        const int n = nb + oct;
        const int nc = (n < N_NODES) ? n : (N_NODES - 1);
        int beg = rowptr[nc], end = rowptr[nc + 1];
        if (n >= N_NODES) { beg = 0; end = 0; }
        const uint32 nself = (n < N_NODES) ? (uint32)n : (uint32)N_NODES;
        const uint4 sd = *(const uint4*)(xsu + (nself * 32u + (uint32)(q << 2)));
        Acc8 A = {{0.f, 0.f}, {0.f, 0.f}, {0.f, 0.f}, {0.f, 0.f}};
        oct_gather(src, xsu, beg, end, q, obase, A);
        accum(A, sd);  // self (already * dinv)
        uint4 pkd;
        pkd.x = pk16(A.p0.x, A.p0.y);
        pkd.y = pk16(A.p1.x, A.p1.y);
        pkd.z = pk16(A.p2.x, A.p2.y);
        pkd.w = pk16(A.p3.x, A.p3.y);
        *(uint4*)&aggp[wid][oct][q * 4] = pkd;  // within-wave RAW (lgkmcnt wait)
        // ---- compute phase: 8 nodes sequentially ----
        for (int c = 0; c < 8; ++c) {
            const int node = nb + c;
            if (node >= N_NODES) break;  // wave-uniform
            const float dv = dinv[node];
            // ---- GEMM1: lane f handles f and f+64; hfma2, promote every 16 k ----
            __half2 hc0 = hz, hc1 = hz;
            float g0 = 0.f, g1 = 0.f;
#pragma unroll
            for (int qq = 0; qq < 8; ++qq) {
                const uint4 aq = ((const uint4*)aggp[wid][c])[qq];  // b128 broadcast
#pragma unroll
                for (int j = 0; j < 4; ++j) {
                    const uint32 av = (j == 0) ? aq.x : (j == 1) ? aq.y : (j == 2) ? aq.z : aq.w;
                    const uint2 wv = w1d[(qq * 4 + j) * 64 + lane];
                    hc0 = __hfma2(u2h(av), u2h(wv.x), hc0);
                    hc1 = __hfma2(u2h(av), u2h(wv.y), hc1);
                }
                if (qq & 1) {
                    float2 p;
                    p = __half22float2(hc0); g0 += p.x + p.y; hc0 = hz;
                    p = __half22float2(hc1); g1 += p.x + p.y; hc1 = hz;
                }
            }
            const float t0 = g0 * dv + b1s[lane];
            const float t1 = g1 * dv + b1s[lane + 64];
            // ---- LayerNorm over 128 ----
            float s = t0 + t1;
#pragma unroll
            for (int off = 32; off > 0; off >>= 1) s += __shfl_xor(s, off, 64);
            const float mu = s * (1.f / 128.f);
            const float d0 = t0 - mu, d1 = t1 - mu;
            float v = d0 * d0 + d1 * d1;
#pragma unroll
            for (int off = 32; off > 0; off >>= 1) v += __shfl_xor(v, off, 64);
            const float rstd = rsqrtf(v * (1.f / 128.f) + 1e-5f);
            const float u0 = fmaxf(d0 * rstd * lnws[lane] + lnbs[lane], 0.f);
            const float u1 = fmaxf(d1 * rstd * lnws[lane + 64] + lnbs[lane + 64], 0.f);
            // repack u into k-pair layout: usp[k2] = (u[2k2], u[2k2+1])
            const int praw = (int)pk16(u0, u1);  // lane m: (u[m], u[m+64])
            const int ia = __shfl(praw, (2 * lane) & 63, 64);
            const int ib = __shfl(praw, (2 * lane + 1) & 63, 64);
            const float2 fa = up16((uint32)ia), fb = up16((uint32)ib);
            const float ux = (lane < 32) ? fa.x : fa.y;  // u[2*lane]
            const float uy = (lane < 32) ? fb.x : fb.y;  // u[2*lane+1]
            usp[wid][lane] = pk16(ux, uy);
            // ---- GEMM2: a2[lane] = (u @ W2)[lane] * dv ----
            __half2 hc = hz;
            float facc = 0.f;
#pragma unroll
            for (int qq = 0; qq < 16; ++qq) {
                const uint4 uq = ((const uint4*)usp[wid])[qq];  // b128 broadcast
                const uint2 wv0 = w2q[(2 * qq) * 64 + lane];
                const uint2 wv1 = w2q[(2 * qq + 1) * 64 + lane];
                hc = __hfma2(u2h(uq.x), u2h(wv0.x), hc);
                hc = __hfma2(u2h(uq.y), u2h(wv0.y), hc);
                hc = __hfma2(u2h(uq.z), u2h(wv1.x), hc);
                hc = __hfma2(u2h(uq.w), u2h(wv1.y), hc);
                if ((qq & 3) == 3) {
                    const float2 p = __half22float2(hc);
                    facc += p.x + p.y;
                    hc = hz;
                }
            }
            const float a2 = facc * dv;
            // ---- store packed fp16 pairs ----
            const float e  = __shfl(a2, (2 * lane) & 63, 64);
            const float f2 = __shfl(a2, (2 * lane + 1) & 63, 64);
            if (lane < 32) a2u[(size_t)node * 32 + lane] = pk16(e, f2);
        }
    }
}

// ------ fused layer2: OCTET gather + self + dinv + b2 → out ------------------------
__global__ __launch_bounds__(256) void k_gather2(
    const int* __restrict__ rowptr, const int* __restrict__ src,
    const uint32* __restrict__ a2u, const float* __restrict__ dinv,
    const void* __restrict__ b2, void* __restrict__ out,
    const int* __restrict__ flags) {
    const int F32 = flags[0];
    const int lane = threadIdx.x & 63;
    const int q = lane & 7;
    const int oct = lane >> 3;
    const int obase = lane & 56;
    // b2 slice into registers (fixed per lane)
    const float bb0 = ldF(b2, q * 8 + 0, F32), bb1 = ldF(b2, q * 8 + 1, F32);
    const float bb2 = ldF(b2, q * 8 + 2, F32), bb3 = ldF(b2, q * 8 + 3, F32);
    const float bb4 = ldF(b2, q * 8 + 4, F32), bb5 = ldF(b2, q * 8 + 5, F32);
    const float bb6 = ldF(b2, q * 8 + 6, F32), bb7 = ldF(b2, q * 8 + 7, F32);
    const int gw = (blockIdx.x * 256 + threadIdx.x) >> 6;
    const int totw = (gridDim.x * 256) >> 6;
    for (int nb = gw * 8; nb < N_NODES; nb += totw * 8) {
        const int n = nb + oct;
        const int nc = (n < N_NODES) ? n : (N_NODES - 1);
        int beg = rowptr[nc], end = rowptr[nc + 1];
        if (n >= N_NODES) { beg = 0; end = 0; }
        const uint32 nself = (n < N_NODES) ? (uint32)n : (uint32)N_NODES;
        const uint4 sd = *(const uint4*)(a2u + (nself * 32u + (uint32)(q << 2)));
        const float dv = dinv[nc];
        Acc8 A = {{0.f, 0.f}, {0.f, 0.f}, {0.f, 0.f}, {0.f, 0.f}};
        oct_gather(src, a2u, beg, end, q, obase, A);
        accum(A, sd);  // self term
        const float r0 = A.p0.x * dv + bb0, r1 = A.p0.y * dv + bb1;
        const float r2 = A.p1.x * dv + bb2, r3 = A.p1.y * dv + bb3;
        const float r4 = A.p2.x * dv + bb4, r5 = A.p2.y * dv + bb5;
        const float r6 = A.p3.x * dv + bb6, r7 = A.p3.y * dv + bb7;
        if (n < N_NODES) {
            if (F32) {
                float4 o0; o0.x = r0; o0.y = r1; o0.z = r2; o0.w = r3;
                float4 o1; o1.x = r4; o1.y = r5; o1.z = r6; o1.w = r7;
                ((float4*)out)[(size_t)n * 16 + (q << 1)]     = o0;
                ((float4*)out)[(size_t)n * 16 + (q << 1) + 1] = o1;
            } else {
                uint4 ub;
                ub.x = ((uint32)bfbits(r1) << 16) | (uint32)bfbits(r0);
                ub.y = ((uint32)bfbits(r3) << 16) | (uint32)bfbits(r2);
                ub.z = ((uint32)bfbits(r5) << 16) | (uint32)bfbits(r4);
                ub.w = ((uint32)bfbits(r7) << 16) | (uint32)bfbits(r6);
                ((uint4*)out)[(size_t)n * 8 + q] = ub;
            }
        }
    }
}

// ---------------- pooling: segmented per-wave reduction (reads d_out h) ------------
__global__ __launch_bounds__(256) void k_pool(const void* __restrict__ hout,
                                              const void* __restrict__ batch,
                                              float* __restrict__ gsum,
                                              const int* __restrict__ flags) {
    const int F32 = flags[0];
    const int i64 = flags[1];
    const int wid = (blockIdx.x * blockDim.x + threadIdx.x) >> 6;
    const int lane = threadIdx.x & 63;
    const int nwaves = (gridDim.x * blockDim.x) >> 6;
    const int per = (N_NODES + nwaves - 1) / nwaves;
    const int start = wid * per;
    const int end = min(start + per, N_NODES);
    if (start >= end) return;
    float acc = 0.f;
    int gcur = ldI(batch, start, i64);
    for (int n = start; n < end; ++n) {
        int g = ldI(batch, n, i64);
        if (g != gcur) {
            atomicAdd(&gsum[gcur * 64 + lane], acc);
            acc = 0.f;
            gcur = g;
        }
        acc += ldF(hout, (size_t)n * 64 + lane, F32);
    }
    atomicAdd(&gsum[gcur * 64 + lane], acc);
}

// ---------------- g-output with inline per-graph count (binary search) -------------
__global__ void k_gout(const float* __restrict__ gsum, const void* __restrict__ batch,
                       void* __restrict__ out, const int* __restrict__ flags) {
    const int F32 = flags[0];
    const int i64 = flags[1];
    int idx = blockIdx.x * blockDim.x + threadIdx.x;
    if (idx < N_GRAPHS * 64) {
        int g = idx >> 6;  // wave-uniform within 64-thread groups
        int lo = 0, hi = N_NODES;
        while (lo < hi) { int m = (lo + hi) >> 1; if (ldI(batch, m, i64) < g) lo = m + 1; else hi = m; }
        int lb = lo;
        lo = 0; hi = N_NODES;
        while (lo < hi) { int m = (lo + hi) >> 1; if (ldI(batch, m, i64) <= g) lo = m + 1; else hi = m; }
        float c = (float)max(lo - lb, 1);
        stF(out, (size_t)N_NODES * F_OUT + idx, gsum[idx] / c, F32);
    }
}

extern "C" void kernel_launch(void* const* d_in, const int* in_sizes, int n_in,
                              void* d_out, int out_size, void* d_ws, size_t ws_size,
                              hipStream_t stream) {
    const void* x   = d_in[0];
    const void* ei  = d_in[1];
    const void* bat = d_in[2];
    const void* W1  = d_in[3];
    const void* b1  = d_in[4];
    const void* lnw = d_in[5];
    const void* lnb = d_in[6];
    const void* W2  = d_in[7];
    const void* b2  = d_in[8];

    char* ws = (char*)d_ws;
    size_t o = 0;
    auto alloc = [&](size_t bytes) { size_t r = o; o += (bytes + 255) & ~(size_t)255; return r; };
    int*    flags  = (int*)   (ws + alloc(2 * 4));
    float*  dinv   = (float*) (ws + alloc((size_t)N_NODES * 4));
    int*    deg    = (int*)   (ws + alloc((size_t)N_NODES * 4));
    int*    rowptr = (int*)   (ws + alloc((size_t)(N_NODES + 1) * 4));
    int*    bsum   = (int*)   (ws + alloc((size_t)NB_SCAN * 4));
    int*    bbase  = (int*)   (ws + alloc((size_t)NB_SCAN * 4));
    int*    srcidx = (int*)   (ws + alloc((size_t)(N_EDGES + 64) * 4));      // +64 pad for predicated idx loads
    uint32* xs16   = (uint32*)(ws + alloc((size_t)(N_NODES + 1) * 32 * 4));  // +1 zero pad row
    uint32* a2u    = (uint32*)(ws + alloc((size_t)(N_NODES + 1) * 32 * 4));  // +1 zero pad row
    float*  gsum   = (float*) (ws + alloc((size_t)N_GRAPHS * 64 * 4));
    uint2*  part   = (uint2*) (ws + alloc((size_t)NBUK * BK_CAP * 8));       // 13.7 MB bucket regions
    int*    gcur   = (int*)   (ws + alloc((size_t)NBUK * 4));

    hipMemsetAsync(gsum, 0, (size_t)N_GRAPHS * 64 * 4, stream);

    GCNEncoder_77214922048129_kernel<<<1, 256, 0, stream>>>(x, ei, flags, gcur);
    k_part<<<NPB, 256, 0, stream>>>(ei, part, gcur, flags);
    k_bdeg<<<NBUK, 256, 0, stream>>>(part, gcur, deg);
    k_bsum<<<NB_SCAN, 256, 0, stream>>>(deg, bsum, dinv);
    k_bscan<<<1, 512, 0, stream>>>(bsum, bbase);
    k_rowptr<<<NB_SCAN, 256, 0, stream>>>(deg, bbase, rowptr);
    k_fill<<<NBUK, 256, 0, stream>>>(part, gcur, rowptr, srcidx);
    k_scale<<<((N_NODES + 1) * 32 + 255) / 256, 256, 0, stream>>>(x, dinv, xs16, a2u, flags);
    // one 8-node group per wave: 1563 blocks * 8 waves = 12504 waves >= 12500 groups
    k_gather1<<<1563, 64 * G1W, 0, stream>>>(rowptr, srcidx, xs16, dinv, b1, lnw, lnb,
                                             W1, W2, a2u, flags);
    // 3125 blocks * 4 waves = 12500 waves = 12500 groups (exact)
    k_gather2<<<3125, 256, 0, stream>>>(rowptr, srcidx, a2u, dinv, b2, d_out, flags);
    k_pool<<<512, 256, 0, stream>>>(d_out, bat, gsum, flags);
    k_gout<<<(N_GRAPHS * 64 + 255) / 256, 256, 0, stream>>>(gsum, bat, d_out, flags);
}

// Round 5
// 361.631 us; speedup vs baseline: 1.7763x; 1.0088x over previous
//
#include <hip/hip_runtime.h>
#include <hip/hip_bf16.h>
#include <hip/hip_fp16.h>
#include <cstdint>

#define N_NODES 100000
#define N_EDGES 1600000
#define N_GRAPHS 64
#define F_IN 64
#define F_MID 128
#define F_OUT 64
#define NSEG 8

typedef unsigned int uint32;

// ---- bucket partition parameters --------------------------------------------------
#define BK_SHIFT 9
#define BK_COLS (1 << BK_SHIFT)                      // 512 cols per bucket
#define NBUK ((N_NODES + BK_COLS - 1) >> BK_SHIFT)   // 196 buckets
#define BK_CAP 9216                                  // mean 8163 + >10 sigma margin
#define EPB 4096                                     // edges per partition block
#define NPB ((N_EDGES + EPB - 1) / EPB)              // 391 blocks

// ---- dtype-agnostic accessors (flags[0]=1 → floats are fp32; flags[1]=1 → ints are int64)
__device__ __forceinline__ float ldF(const void* p, size_t i, int f32) {
    return f32 ? ((const float*)p)[i]
               : __bfloat162float(((const __hip_bfloat16*)p)[i]);
}
__device__ __forceinline__ int ldI(const void* p, size_t i, int i64) {
    return i64 ? (int)((const long long*)p)[i] : ((const int*)p)[i];
}
__device__ __forceinline__ void stF(void* p, size_t i, float v, int f32) {
    if (f32) ((float*)p)[i] = v;
    else     ((__hip_bfloat16*)p)[i] = __float2bfloat16(v);
}

// source-node → segment (8 segments of 12500 nodes; compiler emits magic-mul)
__device__ __forceinline__ int segof(uint32 r) {
    return (int)((r * (uint32)NSEG) / (uint32)N_NODES);
}

// ---- fp16x2 pack/unpack (SCALAR unions only — arrays of unions spill to scratch!) ----
union H2U { uint32 u; __half2 h; };
__device__ __forceinline__ float2 up16(uint32 u) {
    H2U c; c.u = u;
    return __half22float2(c.h);
}
__device__ __forceinline__ __half2 u2h(uint32 u) {
    H2U c; c.u = u;
    return c.h;
}
__device__ __forceinline__ uint32 pk16(float a, float b) {
    H2U c; c.h = __floats2half2_rn(a, b);
    return c.u;
}
__device__ __forceinline__ unsigned short bfbits(float f) {
    __hip_bfloat16 b = __float2bfloat16(f);
    return *(unsigned short*)&b;
}

// ---- OCTET gather: 8 lanes own one node; lane q owns features 8q..8q+7 (16B) -----
struct Acc8 { float2 p0, p1, p2, p3; };

__device__ __forceinline__ void accum(Acc8& A, const uint4 d) {
    const float2 f0 = up16(d.x), f1 = up16(d.y), f2 = up16(d.z), f3 = up16(d.w);
    A.p0.x += f0.x; A.p0.y += f0.y;
    A.p1.x += f1.x; A.p1.y += f1.y;
    A.p2.x += f2.x; A.p2.y += f2.y;
    A.p3.x += f3.x; A.p3.y += f3.y;
}

__device__ __forceinline__ void oct_batch(const uint32* __restrict__ rows,
                                          const int cur, const int obase,
                                          const uint32 qo, Acc8& A) {
    const int i0 = __shfl(cur, obase | 0, 64);
    const int i1 = __shfl(cur, obase | 1, 64);
    const int i2 = __shfl(cur, obase | 2, 64);
    const int i3 = __shfl(cur, obase | 3, 64);
    const int i4 = __shfl(cur, obase | 4, 64);
    const int i5 = __shfl(cur, obase | 5, 64);
    const int i6 = __shfl(cur, obase | 6, 64);
    const int i7 = __shfl(cur, obase | 7, 64);
    const uint4 d0 = *(const uint4*)(rows + ((uint32)i0 * 32u + qo));
    const uint4 d1 = *(const uint4*)(rows + ((uint32)i1 * 32u + qo));
    const uint4 d2 = *(const uint4*)(rows + ((uint32)i2 * 32u + qo));
    const uint4 d3 = *(const uint4*)(rows + ((uint32)i3 * 32u + qo));
    const uint4 d4 = *(const uint4*)(rows + ((uint32)i4 * 32u + qo));
    const uint4 d5 = *(const uint4*)(rows + ((uint32)i5 * 32u + qo));
    const uint4 d6 = *(const uint4*)(rows + ((uint32)i6 * 32u + qo));
    const uint4 d7 = *(const uint4*)(rows + ((uint32)i7 * 32u + qo));
    accum(A, d0); accum(A, d1); accum(A, d2); accum(A, d3);
    accum(A, d4); accum(A, d5); accum(A, d6); accum(A, d7);
}

// Segment-phased gather: edges are seg-sorted per node (k_fill). Every wave walks
// segs 0..7 in order → instantaneous read window ≈ 1-2 segs (1.6-3.2 MB), which is
// L2-resident on every XCD. Index loads pipelined one batch ahead. Invalid slots
// read the L1-resident zero pad row (adds 0). Per-octet divergence is safe: shfl
// sources are within the same octet (active together), and each lane's pipelined
// `t` stays consistent with its own octet's cursor.
__device__ __forceinline__ void oct_gather_seg(const int* __restrict__ sp,
                                               const uint32* __restrict__ rows,
                                               int curb, const uint2 sc,
                                               const int q, const int obase,
                                               Acc8& A) {
    const uint32 qo = (uint32)(q << 2);
    int t = sp[curb + q];   // prefetch first batch indices (pad-safe)
#pragma unroll
    for (int s = 0; s < NSEG; ++s) {
        const uint32 w = (s < 4) ? sc.x : sc.y;
        const int cnt = (int)((w >> ((s & 3) * 8)) & 0xFFu);
        for (int o = 0; o < cnt; o += 8) {
            const int rem = cnt - o;
            const int nxt = (rem > 8) ? (curb + o + 8) : (curb + cnt);
            const int tn = sp[nxt + q];              // prefetch next batch / next seg
            const int cur = (q < rem) ? t : N_NODES;
            oct_batch(rows, cur, obase, qo, A);
            t = tn;
        }
        curb += cnt;
    }
}

// ---------------- dtype sniffer + gcur init ----------------------------------------
__global__ void GCNEncoder_77214922048129_kernel(const void* x, const void* ei,
                                                 int* flags, int* gcur) {
    __shared__ int cnt_weird, cnt_zero;
    if (threadIdx.x == 0) { cnt_weird = 0; cnt_zero = 0; }
    if (threadIdx.x < NBUK) gcur[threadIdx.x] = threadIdx.x * BK_CAP;
    __syncthreads();
    const unsigned short* u = (const unsigned short*)x;
    int w = 0;
    for (int i = threadIdx.x; i < 2048; i += 256) {
        int e = (u[i] >> 7) & 0xFF;
        if (e == 0xFF || e >= 159 || (e > 0 && e <= 95)) w++;
    }
    atomicAdd(&cnt_weird, w);
    const int* ii = (const int*)ei;
    int z = 0;
    for (int i = threadIdx.x; i < 128; i += 256) {
        if (ii[2 * i + 1] == 0) z++;
    }
    atomicAdd(&cnt_zero, z);
    __syncthreads();
    if (threadIdx.x == 0) {
        flags[0] = (cnt_weird > 64) ? 1 : 0;  // fp32 floats
        flags[1] = (cnt_zero > 64) ? 1 : 0;   // int64 indices
    }
}

// ---------------- bucket partition: edges → part[bucket regions] -------------------
__global__ __launch_bounds__(256) void k_part(const void* __restrict__ ei,
                                              uint2* __restrict__ part,
                                              int* __restrict__ gcur,
                                              const int* __restrict__ flags) {
    const int i64 = flags[1];
    __shared__ uint2 est[EPB];                 // 32 KB edge stage
    __shared__ int cnt[NBUK], base_[NBUK], cur[NBUK];
    const int t = threadIdx.x;
    const int e0 = blockIdx.x * EPB;
    const int ne = min(EPB, N_EDGES - e0);
    for (int i = t; i < NBUK; i += 256) { cnt[i] = 0; cur[i] = 0; }
    __syncthreads();
    for (int i = t; i < ne; i += 256) {
        const int e = e0 + i;
        const int r = ldI(ei, e, i64);
        const int c = ldI(ei, (size_t)N_EDGES + e, i64);
        est[i] = make_uint2((uint32)r, (uint32)c);
        atomicAdd(&cnt[c >> BK_SHIFT], 1);
    }
    __syncthreads();
    for (int b = t; b < NBUK; b += 256)
        base_[b] = (cnt[b] > 0) ? atomicAdd(&gcur[b], cnt[b]) : 0;
    __syncthreads();
    for (int i = t; i < ne; i += 256) {
        const uint2 rc = est[i];
        const int b = (int)(rc.y >> BK_SHIFT);
        const int off = atomicAdd(&cur[b], 1);
        const int pos = base_[b] + off;
        if (pos < (b + 1) * BK_CAP) part[pos] = rc;  // overflow guard (statistically never)
    }
}

// ------ per-bucket (col, seg) histogram → deg + packed per-node seg counts ---------
__global__ __launch_bounds__(256) void k_bdeg(const uint2* __restrict__ part,
                                              const int* __restrict__ gcur,
                                              int* __restrict__ deg,
                                              uint2* __restrict__ seg8) {
    __shared__ uint32 hs[BK_COLS * NSEG];  // 16 KB
    const int b = blockIdx.x;
    const int t = threadIdx.x;
    for (int i = t; i < BK_COLS * NSEG; i += 256) hs[i] = 0u;
    __syncthreads();
    const int beg = b * BK_CAP;
    const int cnt = min(gcur[b] - beg, BK_CAP);
    for (int i = t; i < cnt; i += 256) {
        const uint2 rc = part[beg + i];
        atomicAdd(&hs[(int)(rc.y & (BK_COLS - 1)) * NSEG + segof(rc.x)], 1u);
    }
    __syncthreads();
    const int cbase = b << BK_SHIFT;
    for (int c = t; c < BK_COLS; c += 256) {
        const int col = cbase + c;
        if (col < N_NODES) {
            const uint32 h0 = hs[c * 8 + 0], h1 = hs[c * 8 + 1];
            const uint32 h2 = hs[c * 8 + 2], h3 = hs[c * 8 + 3];
            const uint32 h4 = hs[c * 8 + 4], h5 = hs[c * 8 + 5];
            const uint32 h6 = hs[c * 8 + 6], h7 = hs[c * 8 + 7];
            deg[col] = (int)(h0 + h1 + h2 + h3 + h4 + h5 + h6 + h7);
            uint2 pk;
            pk.x = h0 | (h1 << 8) | (h2 << 16) | (h3 << 24);
            pk.y = h4 | (h5 << 8) | (h6 << 16) | (h7 << 24);
            seg8[col] = pk;
        }
    }
}

// ------ per-bucket CSR fill with (col, seg) cursors → seg-sorted adjacency ---------
__global__ __launch_bounds__(256) void k_fill(const uint2* __restrict__ part,
                                              const int* __restrict__ gcur,
                                              const int* __restrict__ rowptr,
                                              const uint2* __restrict__ seg8,
                                              int* __restrict__ src) {
    __shared__ int cur[BK_COLS * NSEG];  // 16 KB
    const int b = blockIdx.x;
    const int t = threadIdx.x;
    const int cbase = b << BK_SHIFT;
    for (int c = t; c < BK_COLS; c += 256) {
        const int col = cbase + c;
        int base = 0;
        uint2 sc = make_uint2(0u, 0u);
        if (col < N_NODES) { base = rowptr[col]; sc = seg8[col]; }
        cur[c * 8 + 0] = base; base += (int)(sc.x & 0xFF);
        cur[c * 8 + 1] = base; base += (int)((sc.x >> 8) & 0xFF);
        cur[c * 8 + 2] = base; base += (int)((sc.x >> 16) & 0xFF);
        cur[c * 8 + 3] = base; base += (int)((sc.x >> 24) & 0xFF);
        cur[c * 8 + 4] = base; base += (int)(sc.y & 0xFF);
        cur[c * 8 + 5] = base; base += (int)((sc.y >> 8) & 0xFF);
        cur[c * 8 + 6] = base; base += (int)((sc.y >> 16) & 0xFF);
        cur[c * 8 + 7] = base;
    }
    __syncthreads();
    const int beg = b * BK_CAP;
    const int cnt = min(gcur[b] - beg, BK_CAP);
    for (int i = t; i < cnt; i += 256) {
        const uint2 rc = part[beg + i];
        const int pos = atomicAdd(&cur[(int)(rc.y & (BK_COLS - 1)) * NSEG + segof(rc.x)], 1);
        src[pos] = (int)rc.x;
    }
}

// ---------------- CSR scan: 3-stage parallel exclusive scan of deg -----------------
#define NB_SCAN ((N_NODES + 255) / 256)  // 391

__global__ __launch_bounds__(256) void k_bsum(const int* __restrict__ deg,
                                              int* __restrict__ bsum,
                                              float* __restrict__ dinv) {
    __shared__ int sh[256];
    int idx = blockIdx.x * 256 + threadIdx.x;
    int d = 0;
    if (idx < N_NODES) {
        d = deg[idx];
        dinv[idx] = rsqrtf((float)d + 1.0f);  // +1 = self-loop
    }
    sh[threadIdx.x] = d;
    __syncthreads();
#pragma unroll
    for (int off = 128; off > 0; off >>= 1) {
        if (threadIdx.x < off) sh[threadIdx.x] += sh[threadIdx.x + off];
        __syncthreads();
    }
    if (threadIdx.x == 0) bsum[blockIdx.x] = sh[0];
}

__global__ __launch_bounds__(512) void k_bscan(const int* __restrict__ bsum,
                                               int* __restrict__ bbase) {
    __shared__ int sh[512];
    const int t = threadIdx.x;
    sh[t] = (t < NB_SCAN) ? bsum[t] : 0;
    __syncthreads();
    for (int off = 1; off < 512; off <<= 1) {
        int v = (t >= off) ? sh[t - off] : 0;
        __syncthreads();
        sh[t] += v;
        __syncthreads();
    }
    if (t < NB_SCAN) bbase[t] = (t == 0) ? 0 : sh[t - 1];
}

__global__ __launch_bounds__(256) void k_rowptr(const int* __restrict__ deg,
                                                const int* __restrict__ bbase,
                                                int* __restrict__ rowptr) {
    __shared__ int sh[256];
    const int t = threadIdx.x;
    const int idx = blockIdx.x * 256 + t;
    const int d = (idx < N_NODES) ? deg[idx] : 0;
    sh[t] = d;
    __syncthreads();
    for (int off = 1; off < 256; off <<= 1) {
        int v = (t >= off) ? sh[t - off] : 0;
        __syncthreads();
        sh[t] += v;
        __syncthreads();
    }
    if (idx < N_NODES) rowptr[idx] = bbase[blockIdx.x] + sh[t] - d;  // exclusive
    if (idx == 0) rowptr[N_NODES] = N_EDGES;
}

// ---------------- xs16[n] = fp16( x[n] * dinv[n] ), packed pairs -------------------
__global__ __launch_bounds__(256) void k_scale(const void* __restrict__ x,
                                               const float* __restrict__ dinv,
                                               uint32* __restrict__ xs16,
                                               uint32* __restrict__ a2u,
                                               const int* __restrict__ flags) {
    const int F32 = flags[0];
    int idx = blockIdx.x * blockDim.x + threadIdx.x;  // feature-pair index
    if (idx < N_NODES * 32) {
        int n = idx >> 5;
        float dv = dinv[n];
        float a = ldF(x, (size_t)idx * 2, F32) * dv;
        float b = ldF(x, (size_t)idx * 2 + 1, F32) * dv;
        xs16[idx] = pk16(a, b);
    } else if (idx < (N_NODES + 1) * 32) {
        xs16[idx] = 0u;  // zero pad row: dummy gather target contributes 0
        a2u[idx] = 0u;
    }
}

// ------ fused layer1: seg-phased OCTET gather + per-node GEMM1 + LN + ReLU + GEMM2 --
#define G1W 8
__global__ __launch_bounds__(64 * G1W) void k_gather1(
    const int* __restrict__ rowptr, const int* __restrict__ src,
    const uint2* __restrict__ seg8,
    const uint32* __restrict__ xsu, const float* __restrict__ dinv,
    const void* __restrict__ b1, const void* __restrict__ lnw,
    const void* __restrict__ lnb, const void* __restrict__ W1,
    const void* __restrict__ W2, uint32* __restrict__ a2u,
    const int* __restrict__ flags) {
    const int F32 = flags[0];
    __shared__ uint2  w1d[32 * 64];    // 16 KB
    __shared__ uint2  w2q[32 * 64];    // 16 KB
    __shared__ float b1s[F_MID], lnws[F_MID], lnbs[F_MID];
    __shared__ uint32 aggp[G1W][8][32];  // per-wave, per-octet agg k-pairs ; 8 KB
    __shared__ uint32 usp[G1W][64];      // packed u k-pairs per wave ; 2 KB
    for (int i = threadIdx.x; i < 32 * 64; i += 64 * G1W) {
        const int k2 = i >> 6, f = i & 63;
        uint2 w;
        w.x = pk16(ldF(W1, (size_t)(2 * k2) * F_MID + f, F32),
                   ldF(W1, (size_t)(2 * k2 + 1) * F_MID + f, F32));
        w.y = pk16(ldF(W1, (size_t)(2 * k2) * F_MID + f + 64, F32),
                   ldF(W1, (size_t)(2 * k2 + 1) * F_MID + f + 64, F32));
        w1d[i] = w;
    }
    for (int i = threadIdx.x; i < 32 * 64; i += 64 * G1W) {
        const int k4 = i >> 6, f = i & 63;
        uint2 w;
        w.x = pk16(ldF(W2, (size_t)(4 * k4) * F_OUT + f, F32),
                   ldF(W2, (size_t)(4 * k4 + 1) * F_OUT + f, F32));
        w.y = pk16(ldF(W2, (size_t)(4 * k4 + 2) * F_OUT + f, F32),
                   ldF(W2, (size_t)(4 * k4 + 3) * F_OUT + f, F32));
        w2q[i] = w;
    }
    if (threadIdx.x < F_MID) {
        b1s[threadIdx.x] = ldF(b1, threadIdx.x, F32);
        lnws[threadIdx.x] = ldF(lnw, threadIdx.x, F32);
        lnbs[threadIdx.x] = ldF(lnb, threadIdx.x, F32);
    }
    __syncthreads();
    const int wid = threadIdx.x >> 6;
    const int lane = threadIdx.x & 63;
    const int q = lane & 7;       // feature-slice within octet (16B)
    const int oct = lane >> 3;    // node slot within wave
    const int obase = lane & 56;  // octet base lane
    const int gw = (blockIdx.x * (64 * G1W) + threadIdx.x) >> 6;
    const int totw = (gridDim.x * (64 * G1W)) >> 6;
    const __half2 hz = __float2half2_rn(0.f);
    for (int nb = gw * 8; nb < N_NODES; nb += totw * 8) {
        // ---- OCTET gather phase: 8 nodes in parallel, seg-phased ----
        const int n = nb + oct;
        const int nc = (n < N_NODES) ? n : (N_NODES - 1);
        const int curb = rowptr[nc];
        uint2 sc = make_uint2(0u, 0u);
        if (n < N_NODES) sc = seg8[n];
        const uint32 nself = (n < N_NODES) ? (uint32)n : (uint32)N_NODES;
        const uint4 sd = *(const uint4*)(xsu + (nself * 32u + (uint32)(q << 2)));
        Acc8 A = {{0.f, 0.f}, {0.f, 0.f}, {0.f, 0.f}, {0.f, 0.f}};
        oct_gather_seg(src, xsu, curb, sc, q, obase, A);
        accum(A, sd);  // self (already * dinv)
        uint4 pkd;
        pkd.x = pk16(A.p0.x, A.p0.y);
        pkd.y = pk16(A.p1.x, A.p1.y);
        pkd.z = pk16(A.p2.x, A.p2.y);
        pkd.w = pk16(A.p3.x, A.p3.y);
        *(uint4*)&aggp[wid][oct][q * 4] = pkd;  // within-wave RAW (lgkmcnt wait)
        // ---- compute phase: 8 nodes sequentially ----
        for (int c = 0; c < 8; ++c) {
            const int node = nb + c;
            if (node >= N_NODES) break;  // wave-uniform
            const float dv = dinv[node];
            // ---- GEMM1: lane f handles f and f+64; hfma2, promote every 16 k ----
            __half2 hc0 = hz, hc1 = hz;
            float g0 = 0.f, g1 = 0.f;
#pragma unroll
            for (int qq = 0; qq < 8; ++qq) {
                const uint4 aq = ((const uint4*)aggp[wid][c])[qq];  // b128 broadcast
#pragma unroll
                for (int j = 0; j < 4; ++j) {
                    const uint32 av = (j == 0) ? aq.x : (j == 1) ? aq.y : (j == 2) ? aq.z : aq.w;
                    const uint2 wv = w1d[(qq * 4 + j) * 64 + lane];
                    hc0 = __hfma2(u2h(av), u2h(wv.x), hc0);
                    hc1 = __hfma2(u2h(av), u2h(wv.y), hc1);
                }
                if (qq & 1) {
                    float2 p;
                    p = __half22float2(hc0); g0 += p.x + p.y; hc0 = hz;
                    p = __half22float2(hc1); g1 += p.x + p.y; hc1 = hz;
                }
            }
            const float t0 = g0 * dv + b1s[lane];
            const float t1 = g1 * dv + b1s[lane + 64];
            // ---- LayerNorm over 128 ----
            float s = t0 + t1;
#pragma unroll
            for (int off = 32; off > 0; off >>= 1) s += __shfl_xor(s, off, 64);
            const float mu = s * (1.f / 128.f);
            const float d0 = t0 - mu, d1 = t1 - mu;
            float v = d0 * d0 + d1 * d1;
#pragma unroll
            for (int off = 32; off > 0; off >>= 1) v += __shfl_xor(v, off, 64);
            const float rstd = rsqrtf(v * (1.f / 128.f) + 1e-5f);
            const float u0 = fmaxf(d0 * rstd * lnws[lane] + lnbs[lane], 0.f);
            const float u1 = fmaxf(d1 * rstd * lnws[lane + 64] + lnbs[lane + 64], 0.f);
            // repack u into k-pair layout: usp[k2] = (u[2k2], u[2k2+1])
            const int praw = (int)pk16(u0, u1);  // lane m: (u[m], u[m+64])
            const int ia = __shfl(praw, (2 * lane) & 63, 64);
            const int ib = __shfl(praw, (2 * lane + 1) & 63, 64);
            const float2 fa = up16((uint32)ia), fb = up16((uint32)ib);
            const float ux = (lane < 32) ? fa.x : fa.y;  // u[2*lane]
            const float uy = (lane < 32) ? fb.x : fb.y;  // u[2*lane+1]
            usp[wid][lane] = pk16(ux, uy);
            // ---- GEMM2: a2[lane] = (u @ W2)[lane] * dv ----
            __half2 hc = hz;
            float facc = 0.f;
#pragma unroll
            for (int qq = 0; qq < 16; ++qq) {
                const uint4 uq = ((const uint4*)usp[wid])[qq];  // b128 broadcast
                const uint2 wv0 = w2q[(2 * qq) * 64 + lane];
                const uint2 wv1 = w2q[(2 * qq + 1) * 64 + lane];
                hc = __hfma2(u2h(uq.x), u2h(wv0.x), hc);
                hc = __hfma2(u2h(uq.y), u2h(wv0.y), hc);
                hc = __hfma2(u2h(uq.z), u2h(wv1.x), hc);
                hc = __hfma2(u2h(uq.w), u2h(wv1.y), hc);
                if ((qq & 3) == 3) {
                    const float2 p = __half22float2(hc);
                    facc += p.x + p.y;
                    hc = hz;
                }
            }
            const float a2 = facc * dv;
            // ---- store packed fp16 pairs ----
            const float e  = __shfl(a2, (2 * lane) & 63, 64);
            const float f2 = __shfl(a2, (2 * lane + 1) & 63, 64);
            if (lane < 32) a2u[(size_t)node * 32 + lane] = pk16(e, f2);
        }
    }
}

// ------ fused layer2: seg-phased OCTET gather + self + dinv + b2 → out -------------
__global__ __launch_bounds__(256) void k_gather2(
    const int* __restrict__ rowptr, const int* __restrict__ src,
    const uint2* __restrict__ seg8,
    const uint32* __restrict__ a2u, const float* __restrict__ dinv,
    const void* __restrict__ b2, void* __restrict__ out,
    const int* __restrict__ flags) {
    const int F32 = flags[0];
    const int lane = threadIdx.x & 63;
    const int q = lane & 7;
    const int oct = lane >> 3;
    const int obase = lane & 56;
    // b2 slice into registers (fixed per lane)
    const float bb0 = ldF(b2, q * 8 + 0, F32), bb1 = ldF(b2, q * 8 + 1, F32);
    const float bb2 = ldF(b2, q * 8 + 2, F32), bb3 = ldF(b2, q * 8 + 3, F32);
    const float bb4 = ldF(b2, q * 8 + 4, F32), bb5 = ldF(b2, q * 8 + 5, F32);
    const float bb6 = ldF(b2, q * 8 + 6, F32), bb7 = ldF(b2, q * 8 + 7, F32);
    const int gw = (blockIdx.x * 256 + threadIdx.x) >> 6;
    const int totw = (gridDim.x * 256) >> 6;
    for (int nb = gw * 8; nb < N_NODES; nb += totw * 8) {
        const int n = nb + oct;
        const int nc = (n < N_NODES) ? n : (N_NODES - 1);
        const int curb = rowptr[nc];
        uint2 sc = make_uint2(0u, 0u);
        if (n < N_NODES) sc = seg8[n];
        const uint32 nself = (n < N_NODES) ? (uint32)n : (uint32)N_NODES;
        const uint4 sd = *(const uint4*)(a2u + (nself * 32u + (uint32)(q << 2)));
        const float dv = dinv[nc];
        Acc8 A = {{0.f, 0.f}, {0.f, 0.f}, {0.f, 0.f}, {0.f, 0.f}};
        oct_gather_seg(src, a2u, curb, sc, q, obase, A);
        accum(A, sd);  // self term
        const float r0 = A.p0.x * dv + bb0, r1 = A.p0.y * dv + bb1;
        const float r2 = A.p1.x * dv + bb2, r3 = A.p1.y * dv + bb3;
        const float r4 = A.p2.x * dv + bb4, r5 = A.p2.y * dv + bb5;
        const float r6 = A.p3.x * dv + bb6, r7 = A.p3.y * dv + bb7;
        if (n < N_NODES) {
            if (F32) {
                float4 o0; o0.x = r0; o0.y = r1; o0.z = r2; o0.w = r3;
                float4 o1; o1.x = r4; o1.y = r5; o1.z = r6; o1.w = r7;
                ((float4*)out)[(size_t)n * 16 + (q << 1)]     = o0;
                ((float4*)out)[(size_t)n * 16 + (q << 1) + 1] = o1;
            } else {
                uint4 ub;
                ub.x = ((uint32)bfbits(r1) << 16) | (uint32)bfbits(r0);
                ub.y = ((uint32)bfbits(r3) << 16) | (uint32)bfbits(r2);
                ub.z = ((uint32)bfbits(r5) << 16) | (uint32)bfbits(r4);
                ub.w = ((uint32)bfbits(r7) << 16) | (uint32)bfbits(r6);
                ((uint4*)out)[(size_t)n * 8 + q] = ub;
            }
        }
    }
}

// ---------------- pooling: segmented per-wave reduction (reads d_out h) ------------
__global__ __launch_bounds__(256) void k_pool(const void* __restrict__ hout,
                                              const void* __restrict__ batch,
                                              float* __restrict__ gsum,
                                              const int* __restrict__ flags) {
    const int F32 = flags[0];
    const int i64 = flags[1];
    const int wid = (blockIdx.x * blockDim.x + threadIdx.x) >> 6;
    const int lane = threadIdx.x & 63;
    const int nwaves = (gridDim.x * blockDim.x) >> 6;
    const int per = (N_NODES + nwaves - 1) / nwaves;
    const int start = wid * per;
    const int end = min(start + per, N_NODES);
    if (start >= end) return;
    float acc = 0.f;
    int gcur = ldI(batch, start, i64);
    for (int n = start; n < end; ++n) {
        int g = ldI(batch, n, i64);
        if (g != gcur) {
            atomicAdd(&gsum[gcur * 64 + lane], acc);
            acc = 0.f;
            gcur = g;
        }
        acc += ldF(hout, (size_t)n * 64 + lane, F32);
    }
    atomicAdd(&gsum[gcur * 64 + lane], acc);
}

// ---------------- g-output with inline per-graph count (binary search) -------------
__global__ void k_gout(const float* __restrict__ gsum, const void* __restrict__ batch,
                       void* __restrict__ out, const int* __restrict__ flags) {
    const int F32 = flags[0];
    const int i64 = flags[1];
    int idx = blockIdx.x * blockDim.x + threadIdx.x;
    if (idx < N_GRAPHS * 64) {
        int g = idx >> 6;  // wave-uniform within 64-thread groups
        int lo = 0, hi = N_NODES;
        while (lo < hi) { int m = (lo + hi) >> 1; if (ldI(batch, m, i64) < g) lo = m + 1; else hi = m; }
        int lb = lo;
        lo = 0; hi = N_NODES;
        while (lo < hi) { int m = (lo + hi) >> 1; if (ldI(batch, m, i64) <= g) lo = m + 1; else hi = m; }
        float c = (float)max(lo - lb, 1);
        stF(out, (size_t)N_NODES * F_OUT + idx, gsum[idx] / c, F32);
    }
}

extern "C" void kernel_launch(void* const* d_in, const int* in_sizes, int n_in,
                              void* d_out, int out_size, void* d_ws, size_t ws_size,
                              hipStream_t stream) {
    const void* x   = d_in[0];
    const void* ei  = d_in[1];
    const void* bat = d_in[2];
    const void* W1  = d_in[3];
    const void* b1  = d_in[4];
    const void* lnw = d_in[5];
    const void* lnb = d_in[6];
    const void* W2  = d_in[7];
    const void* b2  = d_in[8];

    char* ws = (char*)d_ws;
    size_t o = 0;
    auto alloc = [&](size_t bytes) { size_t r = o; o += (bytes + 255) & ~(size_t)255; return r; };
    int*    flags  = (int*)   (ws + alloc(2 * 4));
    float*  dinv   = (float*) (ws + alloc((size_t)N_NODES * 4));
    int*    deg    = (int*)   (ws + alloc((size_t)N_NODES * 4));
    int*    rowptr = (int*)   (ws + alloc((size_t)(N_NODES + 1) * 4));
    int*    bsum   = (int*)   (ws + alloc((size_t)NB_SCAN * 4));
    int*    bbase  = (int*)   (ws + alloc((size_t)NB_SCAN * 4));
    int*    srcidx = (int*)   (ws + alloc((size_t)(N_EDGES + 64) * 4));      // +64 pad for predicated idx loads
    uint2*  seg8   = (uint2*) (ws + alloc((size_t)N_NODES * 8));             // packed per-node seg counts
    uint32* xs16   = (uint32*)(ws + alloc((size_t)(N_NODES + 1) * 32 * 4));  // +1 zero pad row
    uint32* a2u    = (uint32*)(ws + alloc((size_t)(N_NODES + 1) * 32 * 4));  // +1 zero pad row
    float*  gsum   = (float*) (ws + alloc((size_t)N_GRAPHS * 64 * 4));
    uint2*  part   = (uint2*) (ws + alloc((size_t)NBUK * BK_CAP * 8));       // 14.5 MB bucket regions
    int*    gcur   = (int*)   (ws + alloc((size_t)NBUK * 4));

    hipMemsetAsync(gsum, 0, (size_t)N_GRAPHS * 64 * 4, stream);

    GCNEncoder_77214922048129_kernel<<<1, 256, 0, stream>>>(x, ei, flags, gcur);
    k_part<<<NPB, 256, 0, stream>>>(ei, part, gcur, flags);
    k_bdeg<<<NBUK, 256, 0, stream>>>(part, gcur, deg, seg8);
    k_bsum<<<NB_SCAN, 256, 0, stream>>>(deg, bsum, dinv);
    k_bscan<<<1, 512, 0, stream>>>(bsum, bbase);
    k_rowptr<<<NB_SCAN, 256, 0, stream>>>(deg, bbase, rowptr);
    k_fill<<<NBUK, 256, 0, stream>>>(part, gcur, rowptr, seg8, srcidx);
    k_scale<<<((N_NODES + 1) * 32 + 255) / 256, 256, 0, stream>>>(x, dinv, xs16, a2u, flags);
    // one 8-node group per wave: 1563 blocks * 8 waves = 12504 waves >= 12500 groups
    k_gather1<<<1563, 64 * G1W, 0, stream>>>(rowptr, srcidx, seg8, xs16, dinv, b1, lnw,
                                             lnb, W1, W2, a2u, flags);
    // 3125 blocks * 4 waves = 12500 waves = 12500 groups (exact)
    k_gather2<<<3125, 256, 0, stream>>>(rowptr, srcidx, seg8, a2u, dinv, b2, d_out, flags);
    k_pool<<<512, 256, 0, stream>>>(d_out, bat, gsum, flags);
    k_gout<<<(N_GRAPHS * 64 + 255) / 256, 256, 0, stream>>>(gsum, bat, d_out, flags);
}

// Round 6
// 353.845 us; speedup vs baseline: 1.8154x; 1.0220x over previous
//
#include <hip/hip_runtime.h>
#include <hip/hip_bf16.h>
#include <hip/hip_fp16.h>
#include <cstdint>

#define N_NODES 100000
#define N_EDGES 1600000
#define N_GRAPHS 64
#define F_IN 64
#define F_MID 128
#define F_OUT 64

typedef unsigned int uint32;

// ---- bucket partition parameters --------------------------------------------------
#define BK_SHIFT 9
#define BK_COLS (1 << BK_SHIFT)                      // 512 cols per bucket
#define NBUK ((N_NODES + BK_COLS - 1) >> BK_SHIFT)   // 196 buckets
#define BK_CAP 9216                                  // mean 8163 + >10 sigma margin
#define EPB 4096                                     // edges per partition block
#define NPB ((N_EDGES + EPB - 1) / EPB)              // 391 blocks

// ---- dtype-agnostic accessors (flags[0]=1 → floats are fp32; flags[1]=1 → ints are int64)
__device__ __forceinline__ float ldF(const void* p, size_t i, int f32) {
    return f32 ? ((const float*)p)[i]
               : __bfloat162float(((const __hip_bfloat16*)p)[i]);
}
__device__ __forceinline__ int ldI(const void* p, size_t i, int i64) {
    return i64 ? (int)((const long long*)p)[i] : ((const int*)p)[i];
}
__device__ __forceinline__ void stF(void* p, size_t i, float v, int f32) {
    if (f32) ((float*)p)[i] = v;
    else     ((__hip_bfloat16*)p)[i] = __float2bfloat16(v);
}

// ---- fp16x2 pack/unpack (SCALAR unions only — arrays of unions spill to scratch!) ----
union H2U { uint32 u; __half2 h; };
__device__ __forceinline__ float2 up16(uint32 u) {
    H2U c; c.u = u;
    return __half22float2(c.h);
}
__device__ __forceinline__ __half2 u2h(uint32 u) {
    H2U c; c.u = u;
    return c.h;
}
__device__ __forceinline__ uint32 pk16(float a, float b) {
    H2U c; c.h = __floats2half2_rn(a, b);
    return c.u;
}
__device__ __forceinline__ unsigned short bfbits(float f) {
    __hip_bfloat16 b = __float2bfloat16(f);
    return *(unsigned short*)&b;
}

// ---- OCTET gather: 8 lanes own one node; lane q owns features 8q..8q+7 (16B) -----
// 16-edge predicated batches: lane holds 2 index slots (q and q+8); 16 shfl + 16
// b128 loads issued before any accum → 256 B in flight per lane, ONE latency
// round-trip per 16 edges. Invalid slots read the zero pad row (L1-resident).
// Next-batch indices prefetched. Octet lanes share n → uniform trip count → shfl
// sources always active.
struct Acc8 { float2 p0, p1, p2, p3; };

__device__ __forceinline__ void accum(Acc8& A, const uint4 d) {
    const float2 f0 = up16(d.x), f1 = up16(d.y), f2 = up16(d.z), f3 = up16(d.w);
    A.p0.x += f0.x; A.p0.y += f0.y;
    A.p1.x += f1.x; A.p1.y += f1.y;
    A.p2.x += f2.x; A.p2.y += f2.y;
    A.p3.x += f3.x; A.p3.y += f3.y;
}

__device__ __forceinline__ void oct_gather(const int* __restrict__ sp,
                                           const uint32* __restrict__ rows,
                                           const int beg, const int end,
                                           const int q, const int obase,
                                           Acc8& A) {
    const uint32 qo = (uint32)(q << 2);
    int ta = sp[beg + q];            // pad-safe (src has +64 pad)
    int tb = sp[beg + 8 + q];
    for (int jj = beg; jj < end; jj += 16) {
        const int rem = end - jj;
        const int ca = (q < rem) ? ta : N_NODES;
        const int cb = (q + 8 < rem) ? tb : N_NODES;
        ta = sp[jj + 16 + q];        // prefetch next batch (pad-safe)
        tb = sp[jj + 24 + q];
        const int i0 = __shfl(ca, obase | 0, 64);
        const int i1 = __shfl(ca, obase | 1, 64);
        const int i2 = __shfl(ca, obase | 2, 64);
        const int i3 = __shfl(ca, obase | 3, 64);
        const int i4 = __shfl(ca, obase | 4, 64);
        const int i5 = __shfl(ca, obase | 5, 64);
        const int i6 = __shfl(ca, obase | 6, 64);
        const int i7 = __shfl(ca, obase | 7, 64);
        const int j0 = __shfl(cb, obase | 0, 64);
        const int j1 = __shfl(cb, obase | 1, 64);
        const int j2 = __shfl(cb, obase | 2, 64);
        const int j3 = __shfl(cb, obase | 3, 64);
        const int j4 = __shfl(cb, obase | 4, 64);
        const int j5 = __shfl(cb, obase | 5, 64);
        const int j6 = __shfl(cb, obase | 6, 64);
        const int j7 = __shfl(cb, obase | 7, 64);
        const uint4 d0 = *(const uint4*)(rows + ((uint32)i0 * 32u + qo));
        const uint4 d1 = *(const uint4*)(rows + ((uint32)i1 * 32u + qo));
        const uint4 d2 = *(const uint4*)(rows + ((uint32)i2 * 32u + qo));
        const uint4 d3 = *(const uint4*)(rows + ((uint32)i3 * 32u + qo));
        const uint4 d4 = *(const uint4*)(rows + ((uint32)i4 * 32u + qo));
        const uint4 d5 = *(const uint4*)(rows + ((uint32)i5 * 32u + qo));
        const uint4 d6 = *(const uint4*)(rows + ((uint32)i6 * 32u + qo));
        const uint4 d7 = *(const uint4*)(rows + ((uint32)i7 * 32u + qo));
        const uint4 e0 = *(const uint4*)(rows + ((uint32)j0 * 32u + qo));
        const uint4 e1 = *(const uint4*)(rows + ((uint32)j1 * 32u + qo));
        const uint4 e2 = *(const uint4*)(rows + ((uint32)j2 * 32u + qo));
        const uint4 e3 = *(const uint4*)(rows + ((uint32)j3 * 32u + qo));
        const uint4 e4 = *(const uint4*)(rows + ((uint32)j4 * 32u + qo));
        const uint4 e5 = *(const uint4*)(rows + ((uint32)j5 * 32u + qo));
        const uint4 e6 = *(const uint4*)(rows + ((uint32)j6 * 32u + qo));
        const uint4 e7 = *(const uint4*)(rows + ((uint32)j7 * 32u + qo));
        accum(A, d0); accum(A, d1); accum(A, d2); accum(A, d3);
        accum(A, d4); accum(A, d5); accum(A, d6); accum(A, d7);
        accum(A, e0); accum(A, e1); accum(A, e2); accum(A, e3);
        accum(A, e4); accum(A, e5); accum(A, e6); accum(A, e7);
    }
}

// ---------------- dtype sniffer + gcur init ----------------------------------------
__global__ void GCNEncoder_77214922048129_kernel(const void* x, const void* ei,
                                                 int* flags, int* gcur) {
    __shared__ int cnt_weird, cnt_zero;
    if (threadIdx.x == 0) { cnt_weird = 0; cnt_zero = 0; }
    if (threadIdx.x < NBUK) gcur[threadIdx.x] = threadIdx.x * BK_CAP;
    __syncthreads();
    const unsigned short* u = (const unsigned short*)x;
    int w = 0;
    for (int i = threadIdx.x; i < 2048; i += 256) {
        int e = (u[i] >> 7) & 0xFF;
        if (e == 0xFF || e >= 159 || (e > 0 && e <= 95)) w++;
    }
    atomicAdd(&cnt_weird, w);
    const int* ii = (const int*)ei;
    int z = 0;
    for (int i = threadIdx.x; i < 128; i += 256) {
        if (ii[2 * i + 1] == 0) z++;
    }
    atomicAdd(&cnt_zero, z);
    __syncthreads();
    if (threadIdx.x == 0) {
        flags[0] = (cnt_weird > 64) ? 1 : 0;  // fp32 floats
        flags[1] = (cnt_zero > 64) ? 1 : 0;   // int64 indices
    }
}

// ---------------- bucket partition: edges → part[bucket regions] -------------------
__global__ __launch_bounds__(256) void k_part(const void* __restrict__ ei,
                                              uint2* __restrict__ part,
                                              int* __restrict__ gcur,
                                              const int* __restrict__ flags) {
    const int i64 = flags[1];
    __shared__ uint2 est[EPB];                 // 32 KB edge stage
    __shared__ int cnt[NBUK], base_[NBUK], cur[NBUK];
    const int t = threadIdx.x;
    const int e0 = blockIdx.x * EPB;
    const int ne = min(EPB, N_EDGES - e0);
    for (int i = t; i < NBUK; i += 256) { cnt[i] = 0; cur[i] = 0; }
    __syncthreads();
    for (int i = t; i < ne; i += 256) {
        const int e = e0 + i;
        const int r = ldI(ei, e, i64);
        const int c = ldI(ei, (size_t)N_EDGES + e, i64);
        est[i] = make_uint2((uint32)r, (uint32)c);
        atomicAdd(&cnt[c >> BK_SHIFT], 1);
    }
    __syncthreads();
    for (int b = t; b < NBUK; b += 256)
        base_[b] = (cnt[b] > 0) ? atomicAdd(&gcur[b], cnt[b]) : 0;
    __syncthreads();
    for (int i = t; i < ne; i += 256) {
        const uint2 rc = est[i];
        const int b = (int)(rc.y >> BK_SHIFT);
        const int off = atomicAdd(&cur[b], 1);
        const int pos = base_[b] + off;
        if (pos < (b + 1) * BK_CAP) part[pos] = rc;  // overflow guard (statistically never)
    }
}

// ---------------- per-bucket degree histogram → sequential deg writes --------------
__global__ __launch_bounds__(256) void k_bdeg(const uint2* __restrict__ part,
                                              const int* __restrict__ gcur,
                                              int* __restrict__ deg) {
    __shared__ int h[BK_COLS];
    const int b = blockIdx.x;
    const int t = threadIdx.x;
    for (int i = t; i < BK_COLS; i += 256) h[i] = 0;
    __syncthreads();
    const int beg = b * BK_CAP;
    const int cnt = min(gcur[b] - beg, BK_CAP);
    for (int i = t; i < cnt; i += 256)
        atomicAdd(&h[part[beg + i].y & (BK_COLS - 1)], 1);
    __syncthreads();
    const int cbase = b << BK_SHIFT;
    for (int i = t; i < BK_COLS; i += 256)
        if (cbase + i < N_NODES) deg[cbase + i] = h[i];
}

// ---------------- per-bucket CSR fill: scatter confined to L2-resident window ------
__global__ __launch_bounds__(256) void k_fill(const uint2* __restrict__ part,
                                              const int* __restrict__ gcur,
                                              const int* __restrict__ rowptr,
                                              int* __restrict__ src) {
    __shared__ int cur[BK_COLS];
    const int b = blockIdx.x;
    const int t = threadIdx.x;
    const int cbase = b << BK_SHIFT;
    for (int i = t; i < BK_COLS; i += 256)
        cur[i] = (cbase + i < N_NODES) ? rowptr[cbase + i] : 0;
    __syncthreads();
    const int beg = b * BK_CAP;
    const int cnt = min(gcur[b] - beg, BK_CAP);
    for (int i = t; i < cnt; i += 256) {
        const uint2 rc = part[beg + i];
        const int pos = atomicAdd(&cur[rc.y & (BK_COLS - 1)], 1);
        src[pos] = (int)rc.x;
    }
}

// ---------------- CSR scan: 3-stage parallel exclusive scan of deg -----------------
#define NB_SCAN ((N_NODES + 255) / 256)  // 391

__global__ __launch_bounds__(256) void k_bsum(const int* __restrict__ deg,
                                              int* __restrict__ bsum,
                                              float* __restrict__ dinv) {
    __shared__ int sh[256];
    int idx = blockIdx.x * 256 + threadIdx.x;
    int d = 0;
    if (idx < N_NODES) {
        d = deg[idx];
        dinv[idx] = rsqrtf((float)d + 1.0f);  // +1 = self-loop
    }
    sh[threadIdx.x] = d;
    __syncthreads();
#pragma unroll
    for (int off = 128; off > 0; off >>= 1) {
        if (threadIdx.x < off) sh[threadIdx.x] += sh[threadIdx.x + off];
        __syncthreads();
    }
    if (threadIdx.x == 0) bsum[blockIdx.x] = sh[0];
}

__global__ __launch_bounds__(512) void k_bscan(const int* __restrict__ bsum,
                                               int* __restrict__ bbase) {
    __shared__ int sh[512];
    const int t = threadIdx.x;
    sh[t] = (t < NB_SCAN) ? bsum[t] : 0;
    __syncthreads();
    for (int off = 1; off < 512; off <<= 1) {
        int v = (t >= off) ? sh[t - off] : 0;
        __syncthreads();
        sh[t] += v;
        __syncthreads();
    }
    if (t < NB_SCAN) bbase[t] = (t == 0) ? 0 : sh[t - 1];
}

__global__ __launch_bounds__(256) void k_rowptr(const int* __restrict__ deg,
                                                const int* __restrict__ bbase,
                                                int* __restrict__ rowptr) {
    __shared__ int sh[256];
    const int t = threadIdx.x;
    const int idx = blockIdx.x * 256 + t;
    const int d = (idx < N_NODES) ? deg[idx] : 0;
    sh[t] = d;
    __syncthreads();
    for (int off = 1; off < 256; off <<= 1) {
        int v = (t >= off) ? sh[t - off] : 0;
        __syncthreads();
        sh[t] += v;
        __syncthreads();
    }
    if (idx < N_NODES) rowptr[idx] = bbase[blockIdx.x] + sh[t] - d;  // exclusive
    if (idx == 0) rowptr[N_NODES] = N_EDGES;
}

// ---------------- xs16[n] = fp16( x[n] * dinv[n] ), packed pairs -------------------
__global__ __launch_bounds__(256) void k_scale(const void* __restrict__ x,
                                               const float* __restrict__ dinv,
                                               uint32* __restrict__ xs16,
                                               uint32* __restrict__ a2u,
                                               const int* __restrict__ flags) {
    const int F32 = flags[0];
    int idx = blockIdx.x * blockDim.x + threadIdx.x;  // feature-pair index
    if (idx < N_NODES * 32) {
        int n = idx >> 5;
        float dv = dinv[n];
        float a = ldF(x, (size_t)idx * 2, F32) * dv;
        float b = ldF(x, (size_t)idx * 2 + 1, F32) * dv;
        xs16[idx] = pk16(a, b);
    } else if (idx < (N_NODES + 1) * 32) {
        xs16[idx] = 0u;  // zero pad row: dummy gather target contributes 0
        a2u[idx] = 0u;
    }
}

// ------ fused layer1: OCTET gather + per-node GEMM1 + LN + ReLU + GEMM2 ------------
#define G1W 8
__global__ __launch_bounds__(64 * G1W) void k_gather1(
    const int* __restrict__ rowptr, const int* __restrict__ src,
    const uint32* __restrict__ xsu, const float* __restrict__ dinv,
    const void* __restrict__ b1, const void* __restrict__ lnw,
    const void* __restrict__ lnb, const void* __restrict__ W1,
    const void* __restrict__ W2, uint32* __restrict__ a2u,
    const int* __restrict__ flags) {
    const int F32 = flags[0];
    __shared__ uint2  w1d[32 * 64];    // 16 KB
    __shared__ uint2  w2q[32 * 64];    // 16 KB
    __shared__ float b1s[F_MID], lnws[F_MID], lnbs[F_MID];
    __shared__ uint32 aggp[G1W][8][32];  // per-wave, per-octet agg k-pairs ; 8 KB
    __shared__ uint32 usp[G1W][64];      // packed u k-pairs per wave ; 2 KB
    for (int i = threadIdx.x; i < 32 * 64; i += 64 * G1W) {
        const int k2 = i >> 6, f = i & 63;
        uint2 w;
        w.x = pk16(ldF(W1, (size_t)(2 * k2) * F_MID + f, F32),
                   ldF(W1, (size_t)(2 * k2 + 1) * F_MID + f, F32));
        w.y = pk16(ldF(W1, (size_t)(2 * k2) * F_MID + f + 64, F32),
                   ldF(W1, (size_t)(2 * k2 + 1) * F_MID + f + 64, F32));
        w1d[i] = w;
    }
    for (int i = threadIdx.x; i < 32 * 64; i += 64 * G1W) {
        const int k4 = i >> 6, f = i & 63;
        uint2 w;
        w.x = pk16(ldF(W2, (size_t)(4 * k4) * F_OUT + f, F32),
                   ldF(W2, (size_t)(4 * k4 + 1) * F_OUT + f, F32));
        w.y = pk16(ldF(W2, (size_t)(4 * k4 + 2) * F_OUT + f, F32),
                   ldF(W2, (size_t)(4 * k4 + 3) * F_OUT + f, F32));
        w2q[i] = w;
    }
    if (threadIdx.x < F_MID) {
        b1s[threadIdx.x] = ldF(b1, threadIdx.x, F32);
        lnws[threadIdx.x] = ldF(lnw, threadIdx.x, F32);
        lnbs[threadIdx.x] = ldF(lnb, threadIdx.x, F32);
    }
    __syncthreads();
    const int wid = threadIdx.x >> 6;
    const int lane = threadIdx.x & 63;
    const int q = lane & 7;       // feature-slice within octet (16B)
    const int oct = lane >> 3;    // node slot within wave
    const int obase = lane & 56;  // octet base lane
    const int gw = (blockIdx.x * (64 * G1W) + threadIdx.x) >> 6;
    const int totw = (gridDim.x * (64 * G1W)) >> 6;
    const __half2 hz = __float2half2_rn(0.f);
    for (int nb = gw * 8; nb < N_NODES; nb += totw * 8) {
        // ---- OCTET gather phase: 8 nodes in parallel ----
        const int n = nb + oct;
        const int nc = (n < N_NODES) ? n : (N_NODES - 1);
        int beg = rowptr[nc], end = rowptr[nc + 1];
        if (n >= N_NODES) { beg = 0; end = 0; }
        const uint32 nself = (n < N_NODES) ? (uint32)n : (uint32)N_NODES;
        const uint4 sd = *(const uint4*)(xsu + (nself * 32u + (uint32)(q << 2)));
        Acc8 A = {{0.f, 0.f}, {0.f, 0.f}, {0.f, 0.f}, {0.f, 0.f}};
        oct_gather(src, xsu, beg, end, q, obase, A);
        accum(A, sd);  // self (already * dinv)
        uint4 pkd;
        pkd.x = pk16(A.p0.x, A.p0.y);
        pkd.y = pk16(A.p1.x, A.p1.y);
        pkd.z = pk16(A.p2.x, A.p2.y);
        pkd.w = pk16(A.p3.x, A.p3.y);
        *(uint4*)&aggp[wid][oct][q * 4] = pkd;  // within-wave RAW (lgkmcnt wait)
        // ---- compute phase: 8 nodes sequentially ----
        for (int c = 0; c < 8; ++c) {
            const int node = nb + c;
            if (node >= N_NODES) break;  // wave-uniform
            const float dv = dinv[node];
            // ---- GEMM1: lane f handles f and f+64; hfma2, promote every 16 k ----
            __half2 hc0 = hz, hc1 = hz;
            float g0 = 0.f, g1 = 0.f;
#pragma unroll
            for (int qq = 0; qq < 8; ++qq) {
                const uint4 aq = ((const uint4*)aggp[wid][c])[qq];  // b128 broadcast
#pragma unroll
                for (int j = 0; j < 4; ++j) {
                    const uint32 av = (j == 0) ? aq.x : (j == 1) ? aq.y : (j == 2) ? aq.z : aq.w;
                    const uint2 wv = w1d[(qq * 4 + j) * 64 + lane];
                    hc0 = __hfma2(u2h(av), u2h(wv.x), hc0);
                    hc1 = __hfma2(u2h(av), u2h(wv.y), hc1);
                }
                if (qq & 1) {
                    float2 p;
                    p = __half22float2(hc0); g0 += p.x + p.y; hc0 = hz;
                    p = __half22float2(hc1); g1 += p.x + p.y; hc1 = hz;
                }
            }
            const float t0 = g0 * dv + b1s[lane];
            const float t1 = g1 * dv + b1s[lane + 64];
            // ---- LayerNorm over 128 ----
            float s = t0 + t1;
#pragma unroll
            for (int off = 32; off > 0; off >>= 1) s += __shfl_xor(s, off, 64);
            const float mu = s * (1.f / 128.f);
            const float d0 = t0 - mu, d1 = t1 - mu;
            float v = d0 * d0 + d1 * d1;
#pragma unroll
            for (int off = 32; off > 0; off >>= 1) v += __shfl_xor(v, off, 64);
            const float rstd = rsqrtf(v * (1.f / 128.f) + 1e-5f);
            const float u0 = fmaxf(d0 * rstd * lnws[lane] + lnbs[lane], 0.f);
            const float u1 = fmaxf(d1 * rstd * lnws[lane + 64] + lnbs[lane + 64], 0.f);
            // repack u into k-pair layout: usp[k2] = (u[2k2], u[2k2+1])
            const int praw = (int)pk16(u0, u1);  // lane m: (u[m], u[m+64])
            const int ia = __shfl(praw, (2 * lane) & 63, 64);
            const int ib = __shfl(praw, (2 * lane + 1) & 63, 64);
            const float2 fa = up16((uint32)ia), fb = up16((uint32)ib);
            const float ux = (lane < 32) ? fa.x : fa.y;  // u[2*lane]
            const float uy = (lane < 32) ? fb.x : fb.y;  // u[2*lane+1]
            usp[wid][lane] = pk16(ux, uy);
            // ---- GEMM2: a2[lane] = (u @ W2)[lane] * dv ----
            __half2 hc = hz;
            float facc = 0.f;
#pragma unroll
            for (int qq = 0; qq < 16; ++qq) {
                const uint4 uq = ((const uint4*)usp[wid])[qq];  // b128 broadcast
                const uint2 wv0 = w2q[(2 * qq) * 64 + lane];
                const uint2 wv1 = w2q[(2 * qq + 1) * 64 + lane];
                hc = __hfma2(u2h(uq.x), u2h(wv0.x), hc);
                hc = __hfma2(u2h(uq.y), u2h(wv0.y), hc);
                hc = __hfma2(u2h(uq.z), u2h(wv1.x), hc);
                hc = __hfma2(u2h(uq.w), u2h(wv1.y), hc);
                if ((qq & 3) == 3) {
                    const float2 p = __half22float2(hc);
                    facc += p.x + p.y;
                    hc = hz;
                }
            }
            const float a2 = facc * dv;
            // ---- store packed fp16 pairs ----
            const float e  = __shfl(a2, (2 * lane) & 63, 64);
            const float f2 = __shfl(a2, (2 * lane + 1) & 63, 64);
            if (lane < 32) a2u[(size_t)node * 32 + lane] = pk16(e, f2);
        }
    }
}

// ------ fused layer2: OCTET gather + self + dinv + b2 → out ------------------------
__global__ __launch_bounds__(256) void k_gather2(
    const int* __restrict__ rowptr, const int* __restrict__ src,
    const uint32* __restrict__ a2u, const float* __restrict__ dinv,
    const void* __restrict__ b2, void* __restrict__ out,
    const int* __restrict__ flags) {
    const int F32 = flags[0];
    const int lane = threadIdx.x & 63;
    const int q = lane & 7;
    const int oct = lane >> 3;
    const int obase = lane & 56;
    // b2 slice into registers (fixed per lane)
    const float bb0 = ldF(b2, q * 8 + 0, F32), bb1 = ldF(b2, q * 8 + 1, F32);
    const float bb2 = ldF(b2, q * 8 + 2, F32), bb3 = ldF(b2, q * 8 + 3, F32);
    const float bb4 = ldF(b2, q * 8 + 4, F32), bb5 = ldF(b2, q * 8 + 5, F32);
    const float bb6 = ldF(b2, q * 8 + 6, F32), bb7 = ldF(b2, q * 8 + 7, F32);
    const int gw = (blockIdx.x * 256 + threadIdx.x) >> 6;
    const int totw = (gridDim.x * 256) >> 6;
    for (int nb = gw * 8; nb < N_NODES; nb += totw * 8) {
        const int n = nb + oct;
        const int nc = (n < N_NODES) ? n : (N_NODES - 1);
        int beg = rowptr[nc], end = rowptr[nc + 1];
        if (n >= N_NODES) { beg = 0; end = 0; }
        const uint32 nself = (n < N_NODES) ? (uint32)n : (uint32)N_NODES;
        const uint4 sd = *(const uint4*)(a2u + (nself * 32u + (uint32)(q << 2)));
        const float dv = dinv[nc];
        Acc8 A = {{0.f, 0.f}, {0.f, 0.f}, {0.f, 0.f}, {0.f, 0.f}};
        oct_gather(src, a2u, beg, end, q, obase, A);
        accum(A, sd);  // self term
        const float r0 = A.p0.x * dv + bb0, r1 = A.p0.y * dv + bb1;
        const float r2 = A.p1.x * dv + bb2, r3 = A.p1.y * dv + bb3;
        const float r4 = A.p2.x * dv + bb4, r5 = A.p2.y * dv + bb5;
        const float r6 = A.p3.x * dv + bb6, r7 = A.p3.y * dv + bb7;
        if (n < N_NODES) {
            if (F32) {
                float4 o0; o0.x = r0; o0.y = r1; o0.z = r2; o0.w = r3;
                float4 o1; o1.x = r4; o1.y = r5; o1.z = r6; o1.w = r7;
                ((float4*)out)[(size_t)n * 16 + (q << 1)]     = o0;
                ((float4*)out)[(size_t)n * 16 + (q << 1) + 1] = o1;
            } else {
                uint4 ub;
                ub.x = ((uint32)bfbits(r1) << 16) | (uint32)bfbits(r0);
                ub.y = ((uint32)bfbits(r3) << 16) | (uint32)bfbits(r2);
                ub.z = ((uint32)bfbits(r5) << 16) | (uint32)bfbits(r4);
                ub.w = ((uint32)bfbits(r7) << 16) | (uint32)bfbits(r6);
                ((uint4*)out)[(size_t)n * 8 + q] = ub;
            }
        }
    }
}

// ---------------- pooling: segmented per-wave reduction (reads d_out h) ------------
__global__ __launch_bounds__(256) void k_pool(const void* __restrict__ hout,
                                              const void* __restrict__ batch,
                                              float* __restrict__ gsum,
                                              const int* __restrict__ flags) {
    const int F32 = flags[0];
    const int i64 = flags[1];
    const int wid = (blockIdx.x * blockDim.x + threadIdx.x) >> 6;
    const int lane = threadIdx.x & 63;
    const int nwaves = (gridDim.x * blockDim.x) >> 6;
    const int per = (N_NODES + nwaves - 1) / nwaves;
    const int start = wid * per;
    const int end = min(start + per, N_NODES);
    if (start >= end) return;
    float acc = 0.f;
    int gcur = ldI(batch, start, i64);
    for (int n = start; n < end; ++n) {
        int g = ldI(batch, n, i64);
        if (g != gcur) {
            atomicAdd(&gsum[gcur * 64 + lane], acc);
            acc = 0.f;
            gcur = g;
        }
        acc += ldF(hout, (size_t)n * 64 + lane, F32);
    }
    atomicAdd(&gsum[gcur * 64 + lane], acc);
}

// ---------------- g-output with inline per-graph count (binary search) -------------
__global__ void k_gout(const float* __restrict__ gsum, const void* __restrict__ batch,
                       void* __restrict__ out, const int* __restrict__ flags) {
    const int F32 = flags[0];
    const int i64 = flags[1];
    int idx = blockIdx.x * blockDim.x + threadIdx.x;
    if (idx < N_GRAPHS * 64) {
        int g = idx >> 6;  // wave-uniform within 64-thread groups
        int lo = 0, hi = N_NODES;
        while (lo < hi) { int m = (lo + hi) >> 1; if (ldI(batch, m, i64) < g) lo = m + 1; else hi = m; }
        int lb = lo;
        lo = 0; hi = N_NODES;
        while (lo < hi) { int m = (lo + hi) >> 1; if (ldI(batch, m, i64) <= g) lo = m + 1; else hi = m; }
        float c = (float)max(lo - lb, 1);
        stF(out, (size_t)N_NODES * F_OUT + idx, gsum[idx] / c, F32);
    }
}

extern "C" void kernel_launch(void* const* d_in, const int* in_sizes, int n_in,
                              void* d_out, int out_size, void* d_ws, size_t ws_size,
                              hipStream_t stream) {
    const void* x   = d_in[0];
    const void* ei  = d_in[1];
    const void* bat = d_in[2];
    const void* W1  = d_in[3];
    const void* b1  = d_in[4];
    const void* lnw = d_in[5];
    const void* lnb = d_in[6];
    const void* W2  = d_in[7];
    const void* b2  = d_in[8];

    char* ws = (char*)d_ws;
    size_t o = 0;
    auto alloc = [&](size_t bytes) { size_t r = o; o += (bytes + 255) & ~(size_t)255; return r; };
    int*    flags  = (int*)   (ws + alloc(2 * 4));
    float*  dinv   = (float*) (ws + alloc((size_t)N_NODES * 4));
    int*    deg    = (int*)   (ws + alloc((size_t)N_NODES * 4));
    int*    rowptr = (int*)   (ws + alloc((size_t)(N_NODES + 1) * 4));
    int*    bsum   = (int*)   (ws + alloc((size_t)NB_SCAN * 4));
    int*    bbase  = (int*)   (ws + alloc((size_t)NB_SCAN * 4));
    int*    srcidx = (int*)   (ws + alloc((size_t)(N_EDGES + 64) * 4));      // +64 pad for predicated idx loads
    uint32* xs16   = (uint32*)(ws + alloc((size_t)(N_NODES + 1) * 32 * 4));  // +1 zero pad row
    uint32* a2u    = (uint32*)(ws + alloc((size_t)(N_NODES + 1) * 32 * 4));  // +1 zero pad row
    float*  gsum   = (float*) (ws + alloc((size_t)N_GRAPHS * 64 * 4));
    uint2*  part   = (uint2*) (ws + alloc((size_t)NBUK * BK_CAP * 8));       // 14.5 MB bucket regions
    int*    gcur   = (int*)   (ws + alloc((size_t)NBUK * 4));

    hipMemsetAsync(gsum, 0, (size_t)N_GRAPHS * 64 * 4, stream);

    GCNEncoder_77214922048129_kernel<<<1, 256, 0, stream>>>(x, ei, flags, gcur);
    k_part<<<NPB, 256, 0, stream>>>(ei, part, gcur, flags);
    k_bdeg<<<NBUK, 256, 0, stream>>>(part, gcur, deg);
    k_bsum<<<NB_SCAN, 256, 0, stream>>>(deg, bsum, dinv);
    k_bscan<<<1, 512, 0, stream>>>(bsum, bbase);
    k_rowptr<<<NB_SCAN, 256, 0, stream>>>(deg, bbase, rowptr);
    k_fill<<<NBUK, 256, 0, stream>>>(part, gcur, rowptr, srcidx);
    k_scale<<<((N_NODES + 1) * 32 + 255) / 256, 256, 0, stream>>>(x, dinv, xs16, a2u, flags);
    // one 8-node group per wave: 1563 blocks * 8 waves = 12504 waves >= 12500 groups
    k_gather1<<<1563, 64 * G1W, 0, stream>>>(rowptr, srcidx, xs16, dinv, b1, lnw, lnb,
                                             W1, W2, a2u, flags);
    // 3125 blocks * 4 waves = 12500 waves = 12500 groups (exact)
    k_gather2<<<3125, 256, 0, stream>>>(rowptr, srcidx, a2u, dinv, b2, d_out, flags);
    k_pool<<<512, 256, 0, stream>>>(d_out, bat, gsum, flags);
    k_gout<<<(N_GRAPHS * 64 + 255) / 256, 256, 0, stream>>>(gsum, bat, d_out, flags);
}

// Round 7
// 349.136 us; speedup vs baseline: 1.8399x; 1.0135x over previous
//
#include <hip/hip_runtime.h>
#include <hip/hip_bf16.h>
#include <hip/hip_fp16.h>
#include <cstdint>

#define N_NODES 100000
#define N_EDGES 1600000
#define N_GRAPHS 64
#define F_IN 64
#define F_MID 128
#define F_OUT 64

typedef unsigned int uint32;

// ---- bucket partition parameters --------------------------------------------------
#define BK_SHIFT 9
#define BK_COLS (1 << BK_SHIFT)                      // 512 cols per bucket
#define NBUK ((N_NODES + BK_COLS - 1) >> BK_SHIFT)   // 196 buckets
#define BK_CAP 9216                                  // mean 8163 + >10 sigma margin
#define EPB 4096                                     // edges per partition block
#define NPB ((N_EDGES + EPB - 1) / EPB)              // 391 blocks

// ---- dtype-agnostic accessors (flags[0]=1 → floats are fp32; flags[1]=1 → ints are int64)
__device__ __forceinline__ float ldF(const void* p, size_t i, int f32) {
    return f32 ? ((const float*)p)[i]
               : __bfloat162float(((const __hip_bfloat16*)p)[i]);
}
__device__ __forceinline__ int ldI(const void* p, size_t i, int i64) {
    return i64 ? (int)((const long long*)p)[i] : ((const int*)p)[i];
}
__device__ __forceinline__ void stF(void* p, size_t i, float v, int f32) {
    if (f32) ((float*)p)[i] = v;
    else     ((__hip_bfloat16*)p)[i] = __float2bfloat16(v);
}

// ---- fp16x2 pack/unpack (SCALAR unions only — arrays of unions spill to scratch!) ----
union H2U { uint32 u; __half2 h; };
__device__ __forceinline__ float2 up16(uint32 u) {
    H2U c; c.u = u;
    return __half22float2(c.h);
}
__device__ __forceinline__ __half2 u2h(uint32 u) {
    H2U c; c.u = u;
    return c.h;
}
__device__ __forceinline__ uint32 pk16(float a, float b) {
    H2U c; c.h = __floats2half2_rn(a, b);
    return c.u;
}
__device__ __forceinline__ unsigned short bfbits(float f) {
    __hip_bfloat16 b = __float2bfloat16(f);
    return *(unsigned short*)&b;
}

// ---- sc0 (L1-bypass) 16B gather load ----------------------------------------------
// Theory: gather throughput is capped by ~16 per-CU L1 miss trackers (84 MB L2-miss
// at ~700 GB/s = ~15 lines/CU outstanding at LLC latency). sc0 reads through L1
// (no L1 allocate, L2 allocate preserved) → returns tracked beyond the L1 MSHRs.
// NOTE: asm loads are invisible to the compiler's vmcnt model — caller MUST drain
// with s_waitcnt vmcnt(0) + sched_barrier(0) before consuming (rule #18 analog).
__device__ __forceinline__ uint4 ld_sc0(const uint32* p) {
    uint4 d;
    asm volatile("global_load_dwordx4 %0, %1, off sc0" : "=v"(d) : "v"(p));
    return d;
}

// ---- OCTET gather: 8 lanes own one node; lane q owns features 8q..8q+7 (16B) -----
// 8-edge predicated batches (R4-proven structure): 1 coalesced index load/lane + 8
// intra-octet shfl; 8 sc0 b128 row loads issued back-to-back, ONE explicit drain,
// then accumulate. Invalid slots read the zero pad row (adds 0). Next-batch index
// prefetched. Octet lanes share n → uniform trip count → shfl sources active.
struct Acc8 { float2 p0, p1, p2, p3; };

__device__ __forceinline__ void accum(Acc8& A, const uint4 d) {
    const float2 f0 = up16(d.x), f1 = up16(d.y), f2 = up16(d.z), f3 = up16(d.w);
    A.p0.x += f0.x; A.p0.y += f0.y;
    A.p1.x += f1.x; A.p1.y += f1.y;
    A.p2.x += f2.x; A.p2.y += f2.y;
    A.p3.x += f3.x; A.p3.y += f3.y;
}

__device__ __forceinline__ void oct_gather(const int* __restrict__ sp,
                                           const uint32* __restrict__ rows,
                                           const int beg, const int end,
                                           const int q, const int obase,
                                           Acc8& A) {
    const uint32 qo = (uint32)(q << 2);
    int pre = sp[beg + q];                       // pad-safe (src has +64 pad)
    int myidx = (beg + q < end) ? pre : N_NODES;
    for (int jj = beg; jj < end; jj += 8) {
        const int cur = myidx;
        const int nx = jj + 8 + q;
        pre = sp[nx];                            // prefetch next batch (pad-safe)
        myidx = (nx < end) ? pre : N_NODES;
        const int i0 = __shfl(cur, obase | 0, 64);
        const int i1 = __shfl(cur, obase | 1, 64);
        const int i2 = __shfl(cur, obase | 2, 64);
        const int i3 = __shfl(cur, obase | 3, 64);
        const int i4 = __shfl(cur, obase | 4, 64);
        const int i5 = __shfl(cur, obase | 5, 64);
        const int i6 = __shfl(cur, obase | 6, 64);
        const int i7 = __shfl(cur, obase | 7, 64);
        const uint4 d0 = ld_sc0(rows + ((uint32)i0 * 32u + qo));
        const uint4 d1 = ld_sc0(rows + ((uint32)i1 * 32u + qo));
        const uint4 d2 = ld_sc0(rows + ((uint32)i2 * 32u + qo));
        const uint4 d3 = ld_sc0(rows + ((uint32)i3 * 32u + qo));
        const uint4 d4 = ld_sc0(rows + ((uint32)i4 * 32u + qo));
        const uint4 d5 = ld_sc0(rows + ((uint32)i5 * 32u + qo));
        const uint4 d6 = ld_sc0(rows + ((uint32)i6 * 32u + qo));
        const uint4 d7 = ld_sc0(rows + ((uint32)i7 * 32u + qo));
        asm volatile("s_waitcnt vmcnt(0)" ::: "memory");
        __builtin_amdgcn_sched_barrier(0);       // keep accums AFTER the drain
        accum(A, d0); accum(A, d1); accum(A, d2); accum(A, d3);
        accum(A, d4); accum(A, d5); accum(A, d6); accum(A, d7);
    }
}

// ---------------- dtype sniffer + gcur init ----------------------------------------
__global__ void GCNEncoder_77214922048129_kernel(const void* x, const void* ei,
                                                 int* flags, int* gcur) {
    __shared__ int cnt_weird, cnt_zero;
    if (threadIdx.x == 0) { cnt_weird = 0; cnt_zero = 0; }
    if (threadIdx.x < NBUK) gcur[threadIdx.x] = threadIdx.x * BK_CAP;
    __syncthreads();
    const unsigned short* u = (const unsigned short*)x;
    int w = 0;
    for (int i = threadIdx.x; i < 2048; i += 256) {
        int e = (u[i] >> 7) & 0xFF;
        if (e == 0xFF || e >= 159 || (e > 0 && e <= 95)) w++;
    }
    atomicAdd(&cnt_weird, w);
    const int* ii = (const int*)ei;
    int z = 0;
    for (int i = threadIdx.x; i < 128; i += 256) {
        if (ii[2 * i + 1] == 0) z++;
    }
    atomicAdd(&cnt_zero, z);
    __syncthreads();
    if (threadIdx.x == 0) {
        flags[0] = (cnt_weird > 64) ? 1 : 0;  // fp32 floats
        flags[1] = (cnt_zero > 64) ? 1 : 0;   // int64 indices
    }
}

// ---------------- bucket partition: edges → part[bucket regions] -------------------
__global__ __launch_bounds__(256) void k_part(const void* __restrict__ ei,
                                              uint2* __restrict__ part,
                                              int* __restrict__ gcur,
                                              const int* __restrict__ flags) {
    const int i64 = flags[1];
    __shared__ uint2 est[EPB];                 // 32 KB edge stage
    __shared__ int cnt[NBUK], base_[NBUK], cur[NBUK];
    const int t = threadIdx.x;
    const int e0 = blockIdx.x * EPB;
    const int ne = min(EPB, N_EDGES - e0);
    for (int i = t; i < NBUK; i += 256) { cnt[i] = 0; cur[i] = 0; }
    __syncthreads();
    for (int i = t; i < ne; i += 256) {
        const int e = e0 + i;
        const int r = ldI(ei, e, i64);
        const int c = ldI(ei, (size_t)N_EDGES + e, i64);
        est[i] = make_uint2((uint32)r, (uint32)c);
        atomicAdd(&cnt[c >> BK_SHIFT], 1);
    }
    __syncthreads();
    for (int b = t; b < NBUK; b += 256)
        base_[b] = (cnt[b] > 0) ? atomicAdd(&gcur[b], cnt[b]) : 0;
    __syncthreads();
    for (int i = t; i < ne; i += 256) {
        const uint2 rc = est[i];
        const int b = (int)(rc.y >> BK_SHIFT);
        const int off = atomicAdd(&cur[b], 1);
        const int pos = base_[b] + off;
        if (pos < (b + 1) * BK_CAP) part[pos] = rc;  // overflow guard (statistically never)
    }
}

// ---------------- per-bucket degree histogram → sequential deg writes --------------
__global__ __launch_bounds__(256) void k_bdeg(const uint2* __restrict__ part,
                                              const int* __restrict__ gcur,
                                              int* __restrict__ deg) {
    __shared__ int h[BK_COLS];
    const int b = blockIdx.x;
    const int t = threadIdx.x;
    for (int i = t; i < BK_COLS; i += 256) h[i] = 0;
    __syncthreads();
    const int beg = b * BK_CAP;
    const int cnt = min(gcur[b] - beg, BK_CAP);
    for (int i = t; i < cnt; i += 256)
        atomicAdd(&h[part[beg + i].y & (BK_COLS - 1)], 1);
    __syncthreads();
    const int cbase = b << BK_SHIFT;
    for (int i = t; i < BK_COLS; i += 256)
        if (cbase + i < N_NODES) deg[cbase + i] = h[i];
}

// ---------------- per-bucket CSR fill: scatter confined to L2-resident window ------
__global__ __launch_bounds__(256) void k_fill(const uint2* __restrict__ part,
                                              const int* __restrict__ gcur,
                                              const int* __restrict__ rowptr,
                                              int* __restrict__ src) {
    __shared__ int cur[BK_COLS];
    const int b = blockIdx.x;
    const int t = threadIdx.x;
    const int cbase = b << BK_SHIFT;
    for (int i = t; i < BK_COLS; i += 256)
        cur[i] = (cbase + i < N_NODES) ? rowptr[cbase + i] : 0;
    __syncthreads();
    const int beg = b * BK_CAP;
    const int cnt = min(gcur[b] - beg, BK_CAP);
    for (int i = t; i < cnt; i += 256) {
        const uint2 rc = part[beg + i];
        const int pos = atomicAdd(&cur[rc.y & (BK_COLS - 1)], 1);
        src[pos] = (int)rc.x;
    }
}

// ---------------- CSR scan: 3-stage parallel exclusive scan of deg -----------------
#define NB_SCAN ((N_NODES + 255) / 256)  // 391

__global__ __launch_bounds__(256) void k_bsum(const int* __restrict__ deg,
                                              int* __restrict__ bsum,
                                              float* __restrict__ dinv) {
    __shared__ int sh[256];
    int idx = blockIdx.x * 256 + threadIdx.x;
    int d = 0;
    if (idx < N_NODES) {
        d = deg[idx];
        dinv[idx] = rsqrtf((float)d + 1.0f);  // +1 = self-loop
    }
    sh[threadIdx.x] = d;
    __syncthreads();
#pragma unroll
    for (int off = 128; off > 0; off >>= 1) {
        if (threadIdx.x < off) sh[threadIdx.x] += sh[threadIdx.x + off];
        __syncthreads();
    }
    if (threadIdx.x == 0) bsum[blockIdx.x] = sh[0];
}

__global__ __launch_bounds__(512) void k_bscan(const int* __restrict__ bsum,
                                               int* __restrict__ bbase) {
    __shared__ int sh[512];
    const int t = threadIdx.x;
    sh[t] = (t < NB_SCAN) ? bsum[t] : 0;
    __syncthreads();
    for (int off = 1; off < 512; off <<= 1) {
        int v = (t >= off) ? sh[t - off] : 0;
        __syncthreads();
        sh[t] += v;
        __syncthreads();
    }
    if (t < NB_SCAN) bbase[t] = (t == 0) ? 0 : sh[t - 1];
}

__global__ __launch_bounds__(256) void k_rowptr(const int* __restrict__ deg,
                                                const int* __restrict__ bbase,
                                                int* __restrict__ rowptr) {
    __shared__ int sh[256];
    const int t = threadIdx.x;
    const int idx = blockIdx.x * 256 + t;
    const int d = (idx < N_NODES) ? deg[idx] : 0;
    sh[t] = d;
    __syncthreads();
    for (int off = 1; off < 256; off <<= 1) {
        int v = (t >= off) ? sh[t - off] : 0;
        __syncthreads();
        sh[t] += v;
        __syncthreads();
    }
    if (idx < N_NODES) rowptr[idx] = bbase[blockIdx.x] + sh[t] - d;  // exclusive
    if (idx == 0) rowptr[N_NODES] = N_EDGES;
}

// ---------------- xs16[n] = fp16( x[n] * dinv[n] ), packed pairs -------------------
__global__ __launch_bounds__(256) void k_scale(const void* __restrict__ x,
                                               const float* __restrict__ dinv,
                                               uint32* __restrict__ xs16,
                                               uint32* __restrict__ a2u,
                                               const int* __restrict__ flags) {
    const int F32 = flags[0];
    int idx = blockIdx.x * blockDim.x + threadIdx.x;  // feature-pair index
    if (idx < N_NODES * 32) {
        int n = idx >> 5;
        float dv = dinv[n];
        float a = ldF(x, (size_t)idx * 2, F32) * dv;
        float b = ldF(x, (size_t)idx * 2 + 1, F32) * dv;
        xs16[idx] = pk16(a, b);
    } else if (idx < (N_NODES + 1) * 32) {
        xs16[idx] = 0u;  // zero pad row: dummy gather target contributes 0
        a2u[idx] = 0u;
    }
}

// ------ fused layer1: OCTET gather + per-node GEMM1 + LN + ReLU + GEMM2 ------------
#define G1W 8
__global__ __launch_bounds__(64 * G1W) void k_gather1(
    const int* __restrict__ rowptr, const int* __restrict__ src,
    const uint32* __restrict__ xsu, const float* __restrict__ dinv,
    const void* __restrict__ b1, const void* __restrict__ lnw,
    const void* __restrict__ lnb, const void* __restrict__ W1,
    const void* __restrict__ W2, uint32* __restrict__ a2u,
    const int* __restrict__ flags) {
    const int F32 = flags[0];
    __shared__ uint2  w1d[32 * 64];    // 16 KB
    __shared__ uint2  w2q[32 * 64];    // 16 KB
    __shared__ float b1s[F_MID], lnws[F_MID], lnbs[F_MID];
    __shared__ uint32 aggp[G1W][8][32];  // per-wave, per-octet agg k-pairs ; 8 KB
    __shared__ uint32 usp[G1W][64];      // packed u k-pairs per wave ; 2 KB
    for (int i = threadIdx.x; i < 32 * 64; i += 64 * G1W) {
        const int k2 = i >> 6, f = i & 63;
        uint2 w;
        w.x = pk16(ldF(W1, (size_t)(2 * k2) * F_MID + f, F32),
                   ldF(W1, (size_t)(2 * k2 + 1) * F_MID + f, F32));
        w.y = pk16(ldF(W1, (size_t)(2 * k2) * F_MID + f + 64, F32),
                   ldF(W1, (size_t)(2 * k2 + 1) * F_MID + f + 64, F32));
        w1d[i] = w;
    }
    for (int i = threadIdx.x; i < 32 * 64; i += 64 * G1W) {
        const int k4 = i >> 6, f = i & 63;
        uint2 w;
        w.x = pk16(ldF(W2, (size_t)(4 * k4) * F_OUT + f, F32),
                   ldF(W2, (size_t)(4 * k4 + 1) * F_OUT + f, F32));
        w.y = pk16(ldF(W2, (size_t)(4 * k4 + 2) * F_OUT + f, F32),
                   ldF(W2, (size_t)(4 * k4 + 3) * F_OUT + f, F32));
        w2q[i] = w;
    }
    if (threadIdx.x < F_MID) {
        b1s[threadIdx.x] = ldF(b1, threadIdx.x, F32);
        lnws[threadIdx.x] = ldF(lnw, threadIdx.x, F32);
        lnbs[threadIdx.x] = ldF(lnb, threadIdx.x, F32);
    }
    __syncthreads();
    const int wid = threadIdx.x >> 6;
    const int lane = threadIdx.x & 63;
    const int q = lane & 7;       // feature-slice within octet (16B)
    const int oct = lane >> 3;    // node slot within wave
    const int obase = lane & 56;  // octet base lane
    const int gw = (blockIdx.x * (64 * G1W) + threadIdx.x) >> 6;
    const int totw = (gridDim.x * (64 * G1W)) >> 6;
    const __half2 hz = __float2half2_rn(0.f);
    for (int nb = gw * 8; nb < N_NODES; nb += totw * 8) {
        // ---- OCTET gather phase: 8 nodes in parallel ----
        const int n = nb + oct;
        const int nc = (n < N_NODES) ? n : (N_NODES - 1);
        int beg = rowptr[nc], end = rowptr[nc + 1];
        if (n >= N_NODES) { beg = 0; end = 0; }
        const uint32 nself = (n < N_NODES) ? (uint32)n : (uint32)N_NODES;
        const uint4 sd = *(const uint4*)(xsu + (nself * 32u + (uint32)(q << 2)));
        Acc8 A = {{0.f, 0.f}, {0.f, 0.f}, {0.f, 0.f}, {0.f, 0.f}};
        oct_gather(src, xsu, beg, end, q, obase, A);
        accum(A, sd);  // self (already * dinv)
        uint4 pkd;
        pkd.x = pk16(A.p0.x, A.p0.y);
        pkd.y = pk16(A.p1.x, A.p1.y);
        pkd.z = pk16(A.p2.x, A.p2.y);
        pkd.w = pk16(A.p3.x, A.p3.y);
        *(uint4*)&aggp[wid][oct][q * 4] = pkd;  // within-wave RAW (lgkmcnt wait)
        // ---- compute phase: 8 nodes sequentially ----
        for (int c = 0; c < 8; ++c) {
            const int node = nb + c;
            if (node >= N_NODES) break;  // wave-uniform
            const float dv = dinv[node];
            // ---- GEMM1: lane f handles f and f+64; hfma2, promote every 16 k ----
            __half2 hc0 = hz, hc1 = hz;
            float g0 = 0.f, g1 = 0.f;
#pragma unroll
            for (int qq = 0; qq < 8; ++qq) {
                const uint4 aq = ((const uint4*)aggp[wid][c])[qq];  // b128 broadcast
#pragma unroll
                for (int j = 0; j < 4; ++j) {
                    const uint32 av = (j == 0) ? aq.x : (j == 1) ? aq.y : (j == 2) ? aq.z : aq.w;
                    const uint2 wv = w1d[(qq * 4 + j) * 64 + lane];
                    hc0 = __hfma2(u2h(av), u2h(wv.x), hc0);
                    hc1 = __hfma2(u2h(av), u2h(wv.y), hc1);
                }
                if (qq & 1) {
                    float2 p;
                    p = __half22float2(hc0); g0 += p.x + p.y; hc0 = hz;
                    p = __half22float2(hc1); g1 += p.x + p.y; hc1 = hz;
                }
            }
            const float t0 = g0 * dv + b1s[lane];
            const float t1 = g1 * dv + b1s[lane + 64];
            // ---- LayerNorm over 128 ----
            float s = t0 + t1;
#pragma unroll
            for (int off = 32; off > 0; off >>= 1) s += __shfl_xor(s, off, 64);
            const float mu = s * (1.f / 128.f);
            const float d0 = t0 - mu, d1 = t1 - mu;
            float v = d0 * d0 + d1 * d1;
#pragma unroll
            for (int off = 32; off > 0; off >>= 1) v += __shfl_xor(v, off, 64);
            const float rstd = rsqrtf(v * (1.f / 128.f) + 1e-5f);
            const float u0 = fmaxf(d0 * rstd * lnws[lane] + lnbs[lane], 0.f);
            const float u1 = fmaxf(d1 * rstd * lnws[lane + 64] + lnbs[lane + 64], 0.f);
            // repack u into k-pair layout: usp[k2] = (u[2k2], u[2k2+1])
            const int praw = (int)pk16(u0, u1);  // lane m: (u[m], u[m+64])
            const int ia = __shfl(praw, (2 * lane) & 63, 64);
            const int ib = __shfl(praw, (2 * lane + 1) & 63, 64);
            const float2 fa = up16((uint32)ia), fb = up16((uint32)ib);
            const float ux = (lane < 32) ? fa.x : fa.y;  // u[2*lane]
            const float uy = (lane < 32) ? fb.x : fb.y;  // u[2*lane+1]
            usp[wid][lane] = pk16(ux, uy);
            // ---- GEMM2: a2[lane] = (u @ W2)[lane] * dv ----
            __half2 hc = hz;
            float facc = 0.f;
#pragma unroll
            for (int qq = 0; qq < 16; ++qq) {
                const uint4 uq = ((const uint4*)usp[wid])[qq];  // b128 broadcast
                const uint2 wv0 = w2q[(2 * qq) * 64 + lane];
                const uint2 wv1 = w2q[(2 * qq + 1) * 64 + lane];
                hc = __hfma2(u2h(uq.x), u2h(wv0.x), hc);
                hc = __hfma2(u2h(uq.y), u2h(wv0.y), hc);
                hc = __hfma2(u2h(uq.z), u2h(wv1.x), hc);
                hc = __hfma2(u2h(uq.w), u2h(wv1.y), hc);
                if ((qq & 3) == 3) {
                    const float2 p = __half22float2(hc);
                    facc += p.x + p.y;
                    hc = hz;
                }
            }
            const float a2 = facc * dv;
            // ---- store packed fp16 pairs ----
            const float e  = __shfl(a2, (2 * lane) & 63, 64);
            const float f2 = __shfl(a2, (2 * lane + 1) & 63, 64);
            if (lane < 32) a2u[(size_t)node * 32 + lane] = pk16(e, f2);
        }
    }
}

// ------ fused layer2: OCTET gather + self + dinv + b2 → out ------------------------
__global__ __launch_bounds__(256) void k_gather2(
    const int* __restrict__ rowptr, const int* __restrict__ src,
    const uint32* __restrict__ a2u, const float* __restrict__ dinv,
    const void* __restrict__ b2, void* __restrict__ out,
    const int* __restrict__ flags) {
    const int F32 = flags[0];
    const int lane = threadIdx.x & 63;
    const int q = lane & 7;
    const int oct = lane >> 3;
    const int obase = lane & 56;
    // b2 slice into registers (fixed per lane)
    const float bb0 = ldF(b2, q * 8 + 0, F32), bb1 = ldF(b2, q * 8 + 1, F32);
    const float bb2 = ldF(b2, q * 8 + 2, F32), bb3 = ldF(b2, q * 8 + 3, F32);
    const float bb4 = ldF(b2, q * 8 + 4, F32), bb5 = ldF(b2, q * 8 + 5, F32);
    const float bb6 = ldF(b2, q * 8 + 6, F32), bb7 = ldF(b2, q * 8 + 7, F32);
    const int gw = (blockIdx.x * 256 + threadIdx.x) >> 6;
    const int totw = (gridDim.x * 256) >> 6;
    for (int nb = gw * 8; nb < N_NODES; nb += totw * 8) {
        const int n = nb + oct;
        const int nc = (n < N_NODES) ? n : (N_NODES - 1);
        int beg = rowptr[nc], end = rowptr[nc + 1];
        if (n >= N_NODES) { beg = 0; end = 0; }
        const uint32 nself = (n < N_NODES) ? (uint32)n : (uint32)N_NODES;
        const uint4 sd = *(const uint4*)(a2u + (nself * 32u + (uint32)(q << 2)));
        const float dv = dinv[nc];
        Acc8 A = {{0.f, 0.f}, {0.f, 0.f}, {0.f, 0.f}, {0.f, 0.f}};
        oct_gather(src, a2u, beg, end, q, obase, A);
        accum(A, sd);  // self term
        const float r0 = A.p0.x * dv + bb0, r1 = A.p0.y * dv + bb1;
        const float r2 = A.p1.x * dv + bb2, r3 = A.p1.y * dv + bb3;
        const float r4 = A.p2.x * dv + bb4, r5 = A.p2.y * dv + bb5;
        const float r6 = A.p3.x * dv + bb6, r7 = A.p3.y * dv + bb7;
        if (n < N_NODES) {
            if (F32) {
                float4 o0; o0.x = r0; o0.y = r1; o0.z = r2; o0.w = r3;
                float4 o1; o1.x = r4; o1.y = r5; o1.z = r6; o1.w = r7;
                ((float4*)out)[(size_t)n * 16 + (q << 1)]     = o0;
                ((float4*)out)[(size_t)n * 16 + (q << 1) + 1] = o1;
            } else {
                uint4 ub;
                ub.x = ((uint32)bfbits(r1) << 16) | (uint32)bfbits(r0);
                ub.y = ((uint32)bfbits(r3) << 16) | (uint32)bfbits(r2);
                ub.z = ((uint32)bfbits(r5) << 16) | (uint32)bfbits(r4);
                ub.w = ((uint32)bfbits(r7) << 16) | (uint32)bfbits(r6);
                ((uint4*)out)[(size_t)n * 8 + q] = ub;
            }
        }
    }
}

// ---------------- pooling: segmented per-wave reduction (reads d_out h) ------------
__global__ __launch_bounds__(256) void k_pool(const void* __restrict__ hout,
                                              const void* __restrict__ batch,
                                              float* __restrict__ gsum,
                                              const int* __restrict__ flags) {
    const int F32 = flags[0];
    const int i64 = flags[1];
    const int wid = (blockIdx.x * blockDim.x + threadIdx.x) >> 6;
    const int lane = threadIdx.x & 63;
    const int nwaves = (gridDim.x * blockDim.x) >> 6;
    const int per = (N_NODES + nwaves - 1) / nwaves;
    const int start = wid * per;
    const int end = min(start + per, N_NODES);
    if (start >= end) return;
    float acc = 0.f;
    int gcur = ldI(batch, start, i64);
    for (int n = start; n < end; ++n) {
        int g = ldI(batch, n, i64);
        if (g != gcur) {
            atomicAdd(&gsum[gcur * 64 + lane], acc);
            acc = 0.f;
            gcur = g;
        }
        acc += ldF(hout, (size_t)n * 64 + lane, F32);
    }
    atomicAdd(&gsum[gcur * 64 + lane], acc);
}

// ---------------- g-output with inline per-graph count (binary search) -------------
__global__ void k_gout(const float* __restrict__ gsum, const void* __restrict__ batch,
                       void* __restrict__ out, const int* __restrict__ flags) {
    const int F32 = flags[0];
    const int i64 = flags[1];
    int idx = blockIdx.x * blockDim.x + threadIdx.x;
    if (idx < N_GRAPHS * 64) {
        int g = idx >> 6;  // wave-uniform within 64-thread groups
        int lo = 0, hi = N_NODES;
        while (lo < hi) { int m = (lo + hi) >> 1; if (ldI(batch, m, i64) < g) lo = m + 1; else hi = m; }
        int lb = lo;
        lo = 0; hi = N_NODES;
        while (lo < hi) { int m = (lo + hi) >> 1; if (ldI(batch, m, i64) <= g) lo = m + 1; else hi = m; }
        float c = (float)max(lo - lb, 1);
        stF(out, (size_t)N_NODES * F_OUT + idx, gsum[idx] / c, F32);
    }
}

extern "C" void kernel_launch(void* const* d_in, const int* in_sizes, int n_in,
                              void* d_out, int out_size, void* d_ws, size_t ws_size,
                              hipStream_t stream) {
    const void* x   = d_in[0];
    const void* ei  = d_in[1];
    const void* bat = d_in[2];
    const void* W1  = d_in[3];
    const void* b1  = d_in[4];
    const void* lnw = d_in[5];
    const void* lnb = d_in[6];
    const void* W2  = d_in[7];
    const void* b2  = d_in[8];

    char* ws = (char*)d_ws;
    size_t o = 0;
    auto alloc = [&](size_t bytes) { size_t r = o; o += (bytes + 255) & ~(size_t)255; return r; };
    int*    flags  = (int*)   (ws + alloc(2 * 4));
    float*  dinv   = (float*) (ws + alloc((size_t)N_NODES * 4));
    int*    deg    = (int*)   (ws + alloc((size_t)N_NODES * 4));
    int*    rowptr = (int*)   (ws + alloc((size_t)(N_NODES + 1) * 4));
    int*    bsum   = (int*)   (ws + alloc((size_t)NB_SCAN * 4));
    int*    bbase  = (int*)   (ws + alloc((size_t)NB_SCAN * 4));
    int*    srcidx = (int*)   (ws + alloc((size_t)(N_EDGES + 64) * 4));      // +64 pad for predicated idx loads
    uint32* xs16   = (uint32*)(ws + alloc((size_t)(N_NODES + 1) * 32 * 4));  // +1 zero pad row
    uint32* a2u    = (uint32*)(ws + alloc((size_t)(N_NODES + 1) * 32 * 4));  // +1 zero pad row
    float*  gsum   = (float*) (ws + alloc((size_t)N_GRAPHS * 64 * 4));
    uint2*  part   = (uint2*) (ws + alloc((size_t)NBUK * BK_CAP * 8));       // 14.5 MB bucket regions
    int*    gcur   = (int*)   (ws + alloc((size_t)NBUK * 4));

    hipMemsetAsync(gsum, 0, (size_t)N_GRAPHS * 64 * 4, stream);

    GCNEncoder_77214922048129_kernel<<<1, 256, 0, stream>>>(x, ei, flags, gcur);
    k_part<<<NPB, 256, 0, stream>>>(ei, part, gcur, flags);
    k_bdeg<<<NBUK, 256, 0, stream>>>(part, gcur, deg);
    k_bsum<<<NB_SCAN, 256, 0, stream>>>(deg, bsum, dinv);
    k_bscan<<<1, 512, 0, stream>>>(bsum, bbase);
    k_rowptr<<<NB_SCAN, 256, 0, stream>>>(deg, bbase, rowptr);
    k_fill<<<NBUK, 256, 0, stream>>>(part, gcur, rowptr, srcidx);
    k_scale<<<((N_NODES + 1) * 32 + 255) / 256, 256, 0, stream>>>(x, dinv, xs16, a2u, flags);
    // one 8-node group per wave: 1563 blocks * 8 waves = 12504 waves >= 12500 groups
    k_gather1<<<1563, 64 * G1W, 0, stream>>>(rowptr, srcidx, xs16, dinv, b1, lnw, lnb,
                                             W1, W2, a2u, flags);
    // 3125 blocks * 4 waves = 12500 waves = 12500 groups (exact)
    k_gather2<<<3125, 256, 0, stream>>>(rowptr, srcidx, a2u, dinv, b2, d_out, flags);
    k_pool<<<512, 256, 0, stream>>>(d_out, bat, gsum, flags);
    k_gout<<<(N_GRAPHS * 64 + 255) / 256, 256, 0, stream>>>(gsum, bat, d_out, flags);
}